// Round 1
// baseline (1604.088 us; speedup 1.0000x reference)
//
#include <hip/hip_runtime.h>

// ---------------- constants ----------------
// N = 32768 (derived at runtime), C = 64, K = 16, CS = 8, SHARE = 8

// const-area offsets (floats) inside workspace
enum {
  S_BN1_SUM = 0,    S_BN1_SQ = 64,
  S_LP_SUM = 128,   S_LP_SQ = 132,
  S_M2B1_SUM = 136, S_M2B1_SQ = 200,
  S_M2B2_SUM = 264, S_M2B2_SQ = 272,
  S_BN2_SUM = 280,  S_BN2_SQ = 344,
  S_BN3_SUM = 408,  S_BN3_SQ = 472,
  S_SC1 = 536,  S_SH1 = 600,
  S_LPSC = 664, S_LPSH = 668,
  S_M2S1 = 672, S_M2H1 = 736,
  S_M2S2 = 800, S_M2H2 = 808,
  S_SC2 = 816,  S_SH2 = 880,
  S_SC3 = 944,  S_SH3 = 1008,
  S_LPW2S = 1072, S_LPB2S = 1120,
  S_QW = 1136, S_QB = 1148,
  CONST_FLOATS = 1280
};

__device__ __forceinline__ unsigned int fkey(float f) {
  unsigned int u = __float_as_uint(f);
  return (u & 0x80000000u) ? ~u : (u | 0x80000000u);
}
__device__ __forceinline__ float funkey(unsigned int k) {
  unsigned int u = (k & 0x80000000u) ? (k & 0x7fffffffu) : ~k;
  return __uint_as_float(u);
}

// ---------------- generic 64x64 GEMM (row per lane-column) ----------------
// out[row, lane] = (opt-normrelu(in[row,:])) @ w[:, lane] (+ bias[lane]); optional per-channel stats.
__global__ __launch_bounds__(256) void k_gemm64(
    const float* __restrict__ in, const float* __restrict__ w,
    const float* __restrict__ bias,
    const float* __restrict__ sc, const float* __restrict__ sh,
    float* __restrict__ out,
    float* __restrict__ stat_sum, float* __restrict__ stat_sq,
    int n)
{
  __shared__ float scsh[64], shsh[64];
  __shared__ float bsum[64], bsq[64];
  const int tid = threadIdx.x;
  const int lane = tid & 63;
  const int wave = tid >> 6;
  if (sc != nullptr && tid < 64) { scsh[tid] = sc[tid]; shsh[tid] = sh[tid]; }
  if (tid < 64) { bsum[tid] = 0.f; bsq[tid] = 0.f; }
  __syncthreads();

  float wreg[64];
  #pragma unroll
  for (int k = 0; k < 64; ++k) wreg[k] = w[k * 64 + lane];
  const float bz = bias ? bias[lane] : 0.f;

  float lsum = 0.f, lsq = 0.f;
  const int row0 = (blockIdx.x * 4 + wave) * 16;
  for (int r = 0; r < 16; ++r) {
    const int row = row0 + r;
    const float* xr = in + (size_t)row * 64;
    float acc = bz;
    if (sc != nullptr) {
      #pragma unroll
      for (int k = 0; k < 64; k += 4) {
        float4 xv = *(const float4*)(xr + k);
        float x0 = fmaxf(fmaf(xv.x, scsh[k + 0], shsh[k + 0]), 0.f);
        float x1 = fmaxf(fmaf(xv.y, scsh[k + 1], shsh[k + 1]), 0.f);
        float x2 = fmaxf(fmaf(xv.z, scsh[k + 2], shsh[k + 2]), 0.f);
        float x3 = fmaxf(fmaf(xv.w, scsh[k + 3], shsh[k + 3]), 0.f);
        acc = fmaf(x0, wreg[k + 0], acc);
        acc = fmaf(x1, wreg[k + 1], acc);
        acc = fmaf(x2, wreg[k + 2], acc);
        acc = fmaf(x3, wreg[k + 3], acc);
      }
    } else {
      #pragma unroll
      for (int k = 0; k < 64; k += 4) {
        float4 xv = *(const float4*)(xr + k);
        acc = fmaf(xv.x, wreg[k + 0], acc);
        acc = fmaf(xv.y, wreg[k + 1], acc);
        acc = fmaf(xv.z, wreg[k + 2], acc);
        acc = fmaf(xv.w, wreg[k + 3], acc);
      }
    }
    out[(size_t)row * 64 + lane] = acc;
    lsum += acc;
    lsq = fmaf(acc, acc, lsq);
  }
  if (stat_sum != nullptr) {
    atomicAdd(&bsum[lane], lsum);
    atomicAdd(&bsq[lane], lsq);
    __syncthreads();
    if (tid < 64) {
      atomicAdd(&stat_sum[tid], bsum[tid]);
      atomicAdd(&stat_sq[tid], bsq[tid]);
    }
  }
}

// ---------------- BN finalize ----------------
__global__ void k_finalize_bn(const float* __restrict__ ssum, const float* __restrict__ ssq,
                              const float* __restrict__ g, const float* __restrict__ b,
                              float* __restrict__ scale, float* __restrict__ shift,
                              float inv_count, int nch)
{
  int i = threadIdx.x;
  if (i < nch) {
    float m = ssum[i] * inv_count;
    float v = ssq[i] * inv_count - m * m;
    float rs = rsqrtf(v + 1e-5f);
    float s = g[i] * rs;
    scale[i] = s;
    shift[i] = fmaf(-m, s, b[i]);
  }
}

// ---------------- lp finalize + weight folding ----------------
__global__ void k_f2_lp(const float* __restrict__ lpg, const float* __restrict__ lpbt,
                        const float* __restrict__ lpw1, const float* __restrict__ lpb1,
                        const float* __restrict__ lpw2, const float* __restrict__ lpb2,
                        float* __restrict__ cst, float inv_count)
{
  int t = threadIdx.x;
  if (t < 3) {
    float m = cst[S_LP_SUM + t] * inv_count;
    float v = cst[S_LP_SQ + t] * inv_count - m * m;
    float rs = rsqrtf(v + 1e-5f);
    float s = lpg[t] * rs;
    cst[S_LPSC + t] = s;
    cst[S_LPSH + t] = fmaf(-m, s, lpbt[t]);
  }
  __syncthreads();
  if (t < 9)  cst[S_QW + t] = lpw1[t] * cst[S_LPSC + (t % 3)];
  if (t < 3)  cst[S_QB + t] = fmaf(lpb1[t], cst[S_LPSC + t], cst[S_LPSH + t]);
  if (t < 16) {
    float b = 0.f;
    for (int c2 = 0; c2 < 4; ++c2) b += lpb2[c2 * 16 + t];
    cst[S_LPB2S + t] = b;
    for (int r = 0; r < 3; ++r) {
      float w = 0.f;
      for (int c2 = 0; c2 < 4; ++c2) w += lpw2[r * 64 + c2 * 16 + t];
      cst[S_LPW2S + r * 16 + t] = w;
    }
  }
}

// ---------------- K2: p_r, energy, lp stats ----------------
__global__ __launch_bounds__(256) void k_energy(
    const float* __restrict__ p, const float* __restrict__ y1,
    const int* __restrict__ knn,
    const float* __restrict__ m1w1, const float* __restrict__ m1b1,
    const float* __restrict__ m1w2, const float* __restrict__ m1b2,
    const float* __restrict__ lpw1, const float* __restrict__ lpb1,
    const float* __restrict__ sc1, const float* __restrict__ sh1,
    float* __restrict__ p_r, float* __restrict__ energy,
    float* __restrict__ lp_stats)
{
  __shared__ float w1sh[67 * 16];
  __shared__ float w2sh[256];
  __shared__ float b1sh[16], b2sh[16];
  __shared__ float scsh[64], shsh[64];
  __shared__ float lpw1sh[9], lpb1sh[3];
  const int tid = threadIdx.x;
  for (int i = tid; i < 67 * 16; i += 256) w1sh[i] = m1w1[i];
  w2sh[tid] = m1w2[tid];
  if (tid < 16) { b1sh[tid] = m1b1[tid]; b2sh[tid] = m1b2[tid]; }
  if (tid < 64) { scsh[tid] = sc1[tid]; shsh[tid] = sh1[tid]; }
  if (tid < 9) lpw1sh[tid] = lpw1[tid];
  if (tid < 3) lpb1sh[tid] = lpb1[tid];
  __syncthreads();

  const size_t g = (size_t)blockIdx.x * 256 + tid;
  const int i = (int)(g >> 4);
  const int j = knn[g];
  const float pr0 = p[j * 3 + 0] - p[i * 3 + 0];
  const float pr1 = p[j * 3 + 1] - p[i * 3 + 1];
  const float pr2 = p[j * 3 + 2] - p[i * 3 + 2];
  p_r[g * 3 + 0] = pr0; p_r[g * 3 + 1] = pr1; p_r[g * 3 + 2] = pr2;

  float acc1[16];
  #pragma unroll
  for (int t4 = 0; t4 < 16; t4 += 4) {
    float4 w0 = *(const float4*)(w1sh + 0 * 16 + t4);
    float4 w1v = *(const float4*)(w1sh + 1 * 16 + t4);
    float4 w2v = *(const float4*)(w1sh + 2 * 16 + t4);
    float4 bb = *(const float4*)(b1sh + t4);
    acc1[t4 + 0] = fmaf(pr2, w2v.x, fmaf(pr1, w1v.x, fmaf(pr0, w0.x, bb.x)));
    acc1[t4 + 1] = fmaf(pr2, w2v.y, fmaf(pr1, w1v.y, fmaf(pr0, w0.y, bb.y)));
    acc1[t4 + 2] = fmaf(pr2, w2v.z, fmaf(pr1, w1v.z, fmaf(pr0, w0.z, bb.z)));
    acc1[t4 + 3] = fmaf(pr2, w2v.w, fmaf(pr1, w1v.w, fmaf(pr0, w0.w, bb.w)));
  }
  const float* yr = y1 + (size_t)j * 64;
  for (int c = 0; c < 64; c += 4) {
    float4 yv = *(const float4*)(yr + c);
    float xx0 = fmaxf(fmaf(yv.x, scsh[c + 0], shsh[c + 0]), 0.f);
    float xx1 = fmaxf(fmaf(yv.y, scsh[c + 1], shsh[c + 1]), 0.f);
    float xx2 = fmaxf(fmaf(yv.z, scsh[c + 2], shsh[c + 2]), 0.f);
    float xx3 = fmaxf(fmaf(yv.w, scsh[c + 3], shsh[c + 3]), 0.f);
    float xx[4] = {xx0, xx1, xx2, xx3};
    #pragma unroll
    for (int d = 0; d < 4; ++d) {
      const float* wrow = w1sh + (3 + c + d) * 16;
      const float x = xx[d];
      #pragma unroll
      for (int t4 = 0; t4 < 16; t4 += 4) {
        float4 wv = *(const float4*)(wrow + t4);
        acc1[t4 + 0] = fmaf(x, wv.x, acc1[t4 + 0]);
        acc1[t4 + 1] = fmaf(x, wv.y, acc1[t4 + 1]);
        acc1[t4 + 2] = fmaf(x, wv.z, acc1[t4 + 2]);
        acc1[t4 + 3] = fmaf(x, wv.w, acc1[t4 + 3]);
      }
    }
  }
  float acc2[16];
  #pragma unroll
  for (int t4 = 0; t4 < 16; t4 += 4) {
    float4 bb = *(const float4*)(b2sh + t4);
    acc2[t4 + 0] = bb.x; acc2[t4 + 1] = bb.y; acc2[t4 + 2] = bb.z; acc2[t4 + 3] = bb.w;
  }
  #pragma unroll
  for (int t = 0; t < 16; ++t) {
    float a = fmaxf(acc1[t], 0.f);
    const float* wrow = w2sh + t * 16;
    #pragma unroll
    for (int t4 = 0; t4 < 16; t4 += 4) {
      float4 wv = *(const float4*)(wrow + t4);
      acc2[t4 + 0] = fmaf(a, wv.x, acc2[t4 + 0]);
      acc2[t4 + 1] = fmaf(a, wv.y, acc2[t4 + 1]);
      acc2[t4 + 2] = fmaf(a, wv.z, acc2[t4 + 2]);
      acc2[t4 + 3] = fmaf(a, wv.w, acc2[t4 + 3]);
    }
  }
  #pragma unroll
  for (int t = 0; t < 16; t += 4)
    *(float4*)(energy + g * 16 + t) = make_float4(acc2[t], acc2[t + 1], acc2[t + 2], acc2[t + 3]);

  // lp stats (3 channels over n*k)
  float q0 = fmaf(pr2, lpw1sh[6], fmaf(pr1, lpw1sh[3], fmaf(pr0, lpw1sh[0], lpb1sh[0])));
  float q1 = fmaf(pr2, lpw1sh[7], fmaf(pr1, lpw1sh[4], fmaf(pr0, lpw1sh[1], lpb1sh[1])));
  float q2 = fmaf(pr2, lpw1sh[8], fmaf(pr1, lpw1sh[5], fmaf(pr0, lpw1sh[2], lpb1sh[2])));
  float s0 = q0, s1 = q1, s2 = q2, qq0 = q0 * q0, qq1 = q1 * q1, qq2 = q2 * q2;
  #pragma unroll
  for (int m = 1; m < 64; m <<= 1) {
    s0 += __shfl_xor(s0, m); s1 += __shfl_xor(s1, m); s2 += __shfl_xor(s2, m);
    qq0 += __shfl_xor(qq0, m); qq1 += __shfl_xor(qq1, m); qq2 += __shfl_xor(qq2, m);
  }
  if ((tid & 63) == 0) {
    atomicAdd(&lp_stats[0], s0); atomicAdd(&lp_stats[1], s1); atomicAdd(&lp_stats[2], s2);
    atomicAdd(&lp_stats[4], qq0); atomicAdd(&lp_stats[5], qq1); atomicAdd(&lp_stats[6], qq2);
  }
}

// ---------------- e-vector recompute helper ----------------
__device__ __forceinline__ void load_e(const float* __restrict__ energy,
                                       const float* __restrict__ p_r,
                                       const float* __restrict__ cst,
                                       size_t g, float* e)
{
  float4 t0 = *(const float4*)(energy + g * 16);
  float4 t1 = *(const float4*)(energy + g * 16 + 4);
  float4 t2 = *(const float4*)(energy + g * 16 + 8);
  float4 t3 = *(const float4*)(energy + g * 16 + 12);
  e[0] = t0.x; e[1] = t0.y; e[2] = t0.z; e[3] = t0.w;
  e[4] = t1.x; e[5] = t1.y; e[6] = t1.z; e[7] = t1.w;
  e[8] = t2.x; e[9] = t2.y; e[10] = t2.z; e[11] = t2.w;
  e[12] = t3.x; e[13] = t3.y; e[14] = t3.z; e[15] = t3.w;
  float pr0 = p_r[g * 3 + 0], pr1 = p_r[g * 3 + 1], pr2 = p_r[g * 3 + 2];
  float qn0 = fmaxf(fmaf(pr2, cst[S_QW + 6], fmaf(pr1, cst[S_QW + 3], fmaf(pr0, cst[S_QW + 0], cst[S_QB + 0]))), 0.f);
  float qn1 = fmaxf(fmaf(pr2, cst[S_QW + 7], fmaf(pr1, cst[S_QW + 4], fmaf(pr0, cst[S_QW + 1], cst[S_QB + 1]))), 0.f);
  float qn2 = fmaxf(fmaf(pr2, cst[S_QW + 8], fmaf(pr1, cst[S_QW + 5], fmaf(pr0, cst[S_QW + 2], cst[S_QB + 2]))), 0.f);
  #pragma unroll
  for (int t = 0; t < 16; ++t)
    e[16 + t] = fmaf(qn2, cst[S_LPW2S + 32 + t],
                fmaf(qn1, cst[S_LPW2S + 16 + t],
                fmaf(qn0, cst[S_LPW2S + t], cst[S_LPB2S + t])));
}

// ---------------- K3: stats of h1 = e @ m2w1 ----------------
__global__ __launch_bounds__(256) void k_m2b1_stats(
    const float* __restrict__ energy, const float* __restrict__ p_r,
    const float* __restrict__ cst, const float* __restrict__ m2w1,
    float* __restrict__ stat_sum, float* __restrict__ stat_sq)
{
  __shared__ float esh[32 * 260];
  __shared__ float lsum[64], lsq[64];
  const int tid = threadIdx.x;
  const int lane = tid & 63;
  const int wave = tid >> 6;
  if (tid < 64) { lsum[tid] = 0.f; lsq[tid] = 0.f; }
  float wreg[32];
  #pragma unroll
  for (int k = 0; k < 32; ++k) wreg[k] = m2w1[k * 64 + lane];

  const size_t g = (size_t)blockIdx.x * 256 + tid;
  float e[32];
  load_e(energy, p_r, cst, g, e);
  #pragma unroll
  for (int k = 0; k < 32; ++k) esh[k * 260 + tid] = e[k];
  __syncthreads();

  float ls = 0.f, lq = 0.f;
  for (int g4 = wave * 64; g4 < wave * 64 + 64; g4 += 4) {
    float h0 = 0.f, h1 = 0.f, h2 = 0.f, h3 = 0.f;
    #pragma unroll
    for (int k = 0; k < 32; ++k) {
      float4 ev = *(const float4*)(esh + k * 260 + g4);
      h0 = fmaf(ev.x, wreg[k], h0);
      h1 = fmaf(ev.y, wreg[k], h1);
      h2 = fmaf(ev.z, wreg[k], h2);
      h3 = fmaf(ev.w, wreg[k], h3);
    }
    ls += h0 + h1 + h2 + h3;
    lq += h0 * h0 + h1 * h1 + h2 * h2 + h3 * h3;
  }
  atomicAdd(&lsum[lane], ls);
  atomicAdd(&lsq[lane], lq);
  __syncthreads();
  if (tid < 64) { atomicAdd(&stat_sum[tid], lsum[tid]); atomicAdd(&stat_sq[tid], lsq[tid]); }
}

// ---------------- K4: h2 = relu(bn(h1)) @ m2w2, + stats ----------------
__global__ __launch_bounds__(256) void k_h2(
    const float* __restrict__ energy, const float* __restrict__ p_r,
    const float* __restrict__ cst, const float* __restrict__ m2w1, const float* __restrict__ m2w2,
    float* __restrict__ h2out,
    float* __restrict__ stat_sum, float* __restrict__ stat_sq)
{
  __shared__ float wT[64 * 36];
  __shared__ float w2sh[512];
  __shared__ float scsh[64], shsh[64];
  __shared__ float bsum[8], bsq[8];
  const int tid = threadIdx.x;
  for (int idx = tid; idx < 2048; idx += 256) { int k = idx >> 6, c = idx & 63; wT[c * 36 + k] = m2w1[idx]; }
  for (int idx = tid; idx < 512; idx += 256) w2sh[idx] = m2w2[idx];
  if (tid < 64) { scsh[tid] = cst[S_M2S1 + tid]; shsh[tid] = cst[S_M2H1 + tid]; }
  if (tid < 8) { bsum[tid] = 0.f; bsq[tid] = 0.f; }
  __syncthreads();

  const size_t g0 = ((size_t)blockIdx.x * 256 + tid) * 2;
  float e0[32], e1[32];
  load_e(energy, p_r, cst, g0 + 0, e0);
  load_e(energy, p_r, cst, g0 + 1, e1);
  float a0[8], a1[8];
  #pragma unroll
  for (int t = 0; t < 8; ++t) { a0[t] = 0.f; a1[t] = 0.f; }
  for (int c = 0; c < 64; ++c) {
    const float* wc = wT + c * 36;
    float h0 = 0.f, h1 = 0.f;
    #pragma unroll
    for (int k = 0; k < 32; k += 4) {
      float4 wv = *(const float4*)(wc + k);
      h0 = fmaf(e0[k + 3], wv.w, fmaf(e0[k + 2], wv.z, fmaf(e0[k + 1], wv.y, fmaf(e0[k + 0], wv.x, h0))));
      h1 = fmaf(e1[k + 3], wv.w, fmaf(e1[k + 2], wv.z, fmaf(e1[k + 1], wv.y, fmaf(e1[k + 0], wv.x, h1))));
    }
    float x0 = fmaxf(fmaf(h0, scsh[c], shsh[c]), 0.f);
    float x1 = fmaxf(fmaf(h1, scsh[c], shsh[c]), 0.f);
    float4 wa = *(const float4*)(w2sh + c * 8);
    float4 wb = *(const float4*)(w2sh + c * 8 + 4);
    a0[0] = fmaf(x0, wa.x, a0[0]); a0[1] = fmaf(x0, wa.y, a0[1]); a0[2] = fmaf(x0, wa.z, a0[2]); a0[3] = fmaf(x0, wa.w, a0[3]);
    a0[4] = fmaf(x0, wb.x, a0[4]); a0[5] = fmaf(x0, wb.y, a0[5]); a0[6] = fmaf(x0, wb.z, a0[6]); a0[7] = fmaf(x0, wb.w, a0[7]);
    a1[0] = fmaf(x1, wa.x, a1[0]); a1[1] = fmaf(x1, wa.y, a1[1]); a1[2] = fmaf(x1, wa.z, a1[2]); a1[3] = fmaf(x1, wa.w, a1[3]);
    a1[4] = fmaf(x1, wb.x, a1[4]); a1[5] = fmaf(x1, wb.y, a1[5]); a1[6] = fmaf(x1, wb.z, a1[6]); a1[7] = fmaf(x1, wb.w, a1[7]);
  }
  *(float4*)(h2out + g0 * 8)      = make_float4(a0[0], a0[1], a0[2], a0[3]);
  *(float4*)(h2out + g0 * 8 + 4)  = make_float4(a0[4], a0[5], a0[6], a0[7]);
  *(float4*)(h2out + g0 * 8 + 8)  = make_float4(a1[0], a1[1], a1[2], a1[3]);
  *(float4*)(h2out + g0 * 8 + 12) = make_float4(a1[4], a1[5], a1[6], a1[7]);
  #pragma unroll
  for (int t = 0; t < 8; ++t) {
    atomicAdd(&bsum[t], a0[t] + a1[t]);
    atomicAdd(&bsq[t], fmaf(a0[t], a0[t], a1[t] * a1[t]));
  }
  __syncthreads();
  if (tid < 8) { atomicAdd(&stat_sum[tid], bsum[tid]); atomicAdd(&stat_sq[tid], bsq[tid]); }
}

// ---------------- K5a: softmax over k ----------------
__global__ __launch_bounds__(256) void k_softmax(
    const float* __restrict__ h2, const float* __restrict__ cst,
    const float* __restrict__ m2w3, const float* __restrict__ m2b3,
    float* __restrict__ wout)
{
  __shared__ float w3sh[64];
  __shared__ float b3sh[8], s2sh[8], h2sh[8];
  const int tid = threadIdx.x;
  if (tid < 64) w3sh[tid] = m2w3[tid];
  if (tid < 8) { b3sh[tid] = m2b3[tid]; s2sh[tid] = cst[S_M2S2 + tid]; h2sh[tid] = cst[S_M2H2 + tid]; }
  __syncthreads();
  const size_t g = (size_t)blockIdx.x * 256 + tid;
  float4 ha = *(const float4*)(h2 + g * 8);
  float4 hb = *(const float4*)(h2 + g * 8 + 4);
  float hn[8];
  hn[0] = fmaxf(fmaf(ha.x, s2sh[0], h2sh[0]), 0.f);
  hn[1] = fmaxf(fmaf(ha.y, s2sh[1], h2sh[1]), 0.f);
  hn[2] = fmaxf(fmaf(ha.z, s2sh[2], h2sh[2]), 0.f);
  hn[3] = fmaxf(fmaf(ha.w, s2sh[3], h2sh[3]), 0.f);
  hn[4] = fmaxf(fmaf(hb.x, s2sh[4], h2sh[4]), 0.f);
  hn[5] = fmaxf(fmaf(hb.y, s2sh[5], h2sh[5]), 0.f);
  hn[6] = fmaxf(fmaf(hb.z, s2sh[6], h2sh[6]), 0.f);
  hn[7] = fmaxf(fmaf(hb.w, s2sh[7], h2sh[7]), 0.f);
  float lg[8];
  #pragma unroll
  for (int t = 0; t < 8; ++t) {
    float a = b3sh[t];
    #pragma unroll
    for (int u = 0; u < 8; ++u) a = fmaf(hn[u], w3sh[u * 8 + t], a);
    lg[t] = a;
  }
  #pragma unroll
  for (int t = 0; t < 8; ++t) {
    float m = lg[t];
    m = fmaxf(m, __shfl_xor(m, 1));
    m = fmaxf(m, __shfl_xor(m, 2));
    m = fmaxf(m, __shfl_xor(m, 4));
    m = fmaxf(m, __shfl_xor(m, 8));
    float ex = __expf(lg[t] - m);
    float s = ex;
    s += __shfl_xor(s, 1);
    s += __shfl_xor(s, 2);
    s += __shfl_xor(s, 4);
    s += __shfl_xor(s, 8);
    lg[t] = ex / s;
  }
  *(float4*)(wout + g * 8)     = make_float4(lg[0], lg[1], lg[2], lg[3]);
  *(float4*)(wout + g * 8 + 4) = make_float4(lg[4], lg[5], lg[6], lg[7]);
}

// ---------------- K5b: xk, x_intra, s, v, segment-max ----------------
__global__ __launch_bounds__(128) void k_intra(
    const float* __restrict__ z, const float* __restrict__ p_r,
    const int* __restrict__ knn, const float* __restrict__ cst,
    const float* __restrict__ lpw2, const float* __restrict__ lpb2,
    const float* __restrict__ iw, const float* __restrict__ ib,
    const float* __restrict__ ixw, const float* __restrict__ ixb,
    const float* __restrict__ wsoft,
    float* __restrict__ x_intra, float* __restrict__ sbuf, float* __restrict__ vbuf,
    unsigned int* __restrict__ smax)
{
  __shared__ float xksh[128][65];
  __shared__ float lpw2sh[192], lpb2sh[64];
  __shared__ float iwsh[512], ixwsh[512];
  __shared__ float ibsh[8], ixbsh[8];
  const int tid = threadIdx.x;
  for (int idx = tid; idx < 192; idx += 128) lpw2sh[idx] = lpw2[idx];
  if (tid < 64) lpb2sh[tid] = lpb2[tid];
  for (int idx = tid; idx < 512; idx += 128) { iwsh[idx] = iw[idx]; ixwsh[idx] = ixw[idx]; }
  if (tid < 8) { ibsh[tid] = ib[tid]; ixbsh[tid] = ixb[tid]; }
  __syncthreads();

  const size_t g = (size_t)blockIdx.x * 128 + tid;
  const int j = knn[g];
  const float pr0 = p_r[g * 3 + 0], pr1 = p_r[g * 3 + 1], pr2 = p_r[g * 3 + 2];
  const float qn0 = fmaxf(fmaf(pr2, cst[S_QW + 6], fmaf(pr1, cst[S_QW + 3], fmaf(pr0, cst[S_QW + 0], cst[S_QB + 0]))), 0.f);
  const float qn1 = fmaxf(fmaf(pr2, cst[S_QW + 7], fmaf(pr1, cst[S_QW + 4], fmaf(pr0, cst[S_QW + 1], cst[S_QB + 1]))), 0.f);
  const float qn2 = fmaxf(fmaf(pr2, cst[S_QW + 8], fmaf(pr1, cst[S_QW + 5], fmaf(pr0, cst[S_QW + 2], cst[S_QB + 2]))), 0.f);
  float4 wka = *(const float4*)(wsoft + g * 8);
  float4 wkb = *(const float4*)(wsoft + g * 8 + 4);
  float wk[8] = {wka.x, wka.y, wka.z, wka.w, wkb.x, wkb.y, wkb.z, wkb.w};
  float sacc[8], vacc[8];
  #pragma unroll
  for (int t = 0; t < 8; ++t) { sacc[t] = ibsh[t]; vacc[t] = ixbsh[t]; }
  const float* zr = z + (size_t)j * 64;
  for (int c = 0; c < 64; c += 4) {
    float4 zv = *(const float4*)(zr + c);
    float4 l0 = *(const float4*)(lpw2sh + c);
    float4 l1 = *(const float4*)(lpw2sh + 64 + c);
    float4 l2 = *(const float4*)(lpw2sh + 128 + c);
    float4 lb = *(const float4*)(lpb2sh + c);
    float xkv[4];
    xkv[0] = (zv.x + fmaf(qn2, l2.x, fmaf(qn1, l1.x, fmaf(qn0, l0.x, lb.x)))) * wk[(c + 0) & 7];
    xkv[1] = (zv.y + fmaf(qn2, l2.y, fmaf(qn1, l1.y, fmaf(qn0, l0.y, lb.y)))) * wk[(c + 1) & 7];
    xkv[2] = (zv.z + fmaf(qn2, l2.z, fmaf(qn1, l1.z, fmaf(qn0, l0.z, lb.z)))) * wk[(c + 2) & 7];
    xkv[3] = (zv.w + fmaf(qn2, l2.w, fmaf(qn1, l1.w, fmaf(qn0, l0.w, lb.w)))) * wk[(c + 3) & 7];
    xksh[tid][c + 0] = xkv[0];
    xksh[tid][c + 1] = xkv[1];
    xksh[tid][c + 2] = xkv[2];
    xksh[tid][c + 3] = xkv[3];
    #pragma unroll
    for (int d = 0; d < 4; ++d) {
      const float xk = xkv[d];
      const float* iwc = iwsh + (c + d) * 8;
      const float* ixwc = ixwsh + (c + d) * 8;
      float4 a0 = *(const float4*)(iwc);
      float4 a1 = *(const float4*)(iwc + 4);
      float4 b0 = *(const float4*)(ixwc);
      float4 b1 = *(const float4*)(ixwc + 4);
      sacc[0] = fmaf(xk, a0.x, sacc[0]); sacc[1] = fmaf(xk, a0.y, sacc[1]); sacc[2] = fmaf(xk, a0.z, sacc[2]); sacc[3] = fmaf(xk, a0.w, sacc[3]);
      sacc[4] = fmaf(xk, a1.x, sacc[4]); sacc[5] = fmaf(xk, a1.y, sacc[5]); sacc[6] = fmaf(xk, a1.z, sacc[6]); sacc[7] = fmaf(xk, a1.w, sacc[7]);
      vacc[0] = fmaf(xk, b0.x, vacc[0]); vacc[1] = fmaf(xk, b0.y, vacc[1]); vacc[2] = fmaf(xk, b0.z, vacc[2]); vacc[3] = fmaf(xk, b0.w, vacc[3]);
      vacc[4] = fmaf(xk, b1.x, vacc[4]); vacc[5] = fmaf(xk, b1.y, vacc[5]); vacc[6] = fmaf(xk, b1.z, vacc[6]); vacc[7] = fmaf(xk, b1.w, vacc[7]);
    }
  }
  *(float4*)(sbuf + g * 8)     = make_float4(sacc[0], sacc[1], sacc[2], sacc[3]);
  *(float4*)(sbuf + g * 8 + 4) = make_float4(sacc[4], sacc[5], sacc[6], sacc[7]);
  *(float4*)(vbuf + g * 8)     = make_float4(vacc[0], vacc[1], vacc[2], vacc[3]);
  *(float4*)(vbuf + g * 8 + 4) = make_float4(vacc[4], vacc[5], vacc[6], vacc[7]);
  #pragma unroll
  for (int t = 0; t < 8; ++t) atomicMax(&smax[(size_t)j * 8 + t], fkey(sacc[t]));
  __syncthreads();
  const int nl = tid >> 4;
  const int cb = (tid & 15) * 4;
  float o0 = 0.f, o1 = 0.f, o2 = 0.f, o3 = 0.f;
  #pragma unroll
  for (int k = 0; k < 16; ++k) {
    const float* xr = &xksh[nl * 16 + k][cb];
    o0 += xr[0]; o1 += xr[1]; o2 += xr[2]; o3 += xr[3];
  }
  const size_t nrow = (size_t)blockIdx.x * 8 + nl;
  *(float4*)(x_intra + nrow * 64 + cb) = make_float4(o0, o1, o2, o3);
}

// ---------------- K6: exp + segment sum ----------------
__global__ __launch_bounds__(256) void k_scatter1(
    const int* __restrict__ knn, const unsigned int* __restrict__ smax,
    float* __restrict__ sbuf, float* __restrict__ ssum)
{
  const size_t g = (size_t)blockIdx.x * 256 + threadIdx.x;
  const int j = knn[g];
  float4 a = *(const float4*)(sbuf + g * 8);
  float4 b = *(const float4*)(sbuf + g * 8 + 4);
  float sv[8] = {a.x, a.y, a.z, a.w, b.x, b.y, b.z, b.w};
  float ex[8];
  #pragma unroll
  for (int t = 0; t < 8; ++t) {
    float sm = funkey(smax[(size_t)j * 8 + t]);
    ex[t] = __expf(sv[t] - sm);
    atomicAdd(&ssum[(size_t)j * 8 + t], ex[t]);
  }
  *(float4*)(sbuf + g * 8)     = make_float4(ex[0], ex[1], ex[2], ex[3]);
  *(float4*)(sbuf + g * 8 + 4) = make_float4(ex[4], ex[5], ex[6], ex[7]);
}

// ---------------- K7: residual scatter ----------------
__global__ __launch_bounds__(256) void k_scatter2(
    const int* __restrict__ knn, const float* __restrict__ sbuf,
    const float* __restrict__ ssum, const float* __restrict__ vbuf,
    float* __restrict__ resid)
{
  const size_t g = (size_t)blockIdx.x * 256 + threadIdx.x;
  const int j = knn[g];
  float4 ea = *(const float4*)(sbuf + g * 8);
  float4 eb = *(const float4*)(sbuf + g * 8 + 4);
  float4 va = *(const float4*)(vbuf + g * 8);
  float4 vb = *(const float4*)(vbuf + g * 8 + 4);
  float ex[8] = {ea.x, ea.y, ea.z, ea.w, eb.x, eb.y, eb.z, eb.w};
  float vv[8] = {va.x, va.y, va.z, va.w, vb.x, vb.y, vb.z, vb.w};
  #pragma unroll
  for (int t = 0; t < 8; ++t) {
    float prob = ex[t] / ssum[(size_t)j * 8 + t];
    atomicAdd(&resid[(size_t)j * 8 + t], vv[t] * prob);
  }
}

// ---------------- K8: x2 = x_intra + tile(resid), bn2 stats ----------------
__global__ __launch_bounds__(256) void k_x2_stats(
    float* __restrict__ xi, const float* __restrict__ resid,
    float* __restrict__ stat_sum, float* __restrict__ stat_sq, int n)
{
  __shared__ float bsum[64], bsq[64];
  const int tid = threadIdx.x;
  const int lane = tid & 63;
  const int wave = tid >> 6;
  if (tid < 64) { bsum[tid] = 0.f; bsq[tid] = 0.f; }
  __syncthreads();
  float ls = 0.f, lq = 0.f;
  const int row0 = (blockIdx.x * 4 + wave) * 16;
  for (int r = 0; r < 16; ++r) {
    const int row = row0 + r;
    float v = xi[(size_t)row * 64 + lane] + resid[(size_t)row * 8 + (lane & 7)];
    xi[(size_t)row * 64 + lane] = v;
    ls += v;
    lq = fmaf(v, v, lq);
  }
  atomicAdd(&bsum[lane], ls);
  atomicAdd(&bsq[lane], lq);
  __syncthreads();
  if (tid < 64) { atomicAdd(&stat_sum[tid], bsum[tid]); atomicAdd(&stat_sq[tid], bsq[tid]); }
}

// ---------------- K10: final bn3 + residual + relu ----------------
__global__ __launch_bounds__(256) void k_out(
    const float* __restrict__ y3, const float* __restrict__ x0,
    const float* __restrict__ cst, float* __restrict__ out)
{
  __shared__ float scsh[64], shsh[64];
  const int tid = threadIdx.x;
  if (tid < 64) { scsh[tid] = cst[S_SC3 + tid]; shsh[tid] = cst[S_SH3 + tid]; }
  __syncthreads();
  const size_t i = ((size_t)blockIdx.x * 256 + tid) * 4;
  float4 y = *(const float4*)(y3 + i);
  float4 x = *(const float4*)(x0 + i);
  const int c = (int)(i & 63);
  float4 o;
  o.x = fmaxf(fmaf(y.x, scsh[c + 0], shsh[c + 0]) + x.x, 0.f);
  o.y = fmaxf(fmaf(y.y, scsh[c + 1], shsh[c + 1]) + x.y, 0.f);
  o.z = fmaxf(fmaf(y.z, scsh[c + 2], shsh[c + 2]) + x.z, 0.f);
  o.w = fmaxf(fmaf(y.w, scsh[c + 3], shsh[c + 3]) + x.w, 0.f);
  *(float4*)(out + i) = o;
}

// ---------------- launch ----------------
extern "C" void kernel_launch(void* const* d_in, const int* in_sizes, int n_in,
                              void* d_out, int out_size, void* d_ws, size_t ws_size,
                              hipStream_t stream)
{
  (void)n_in; (void)out_size; (void)ws_size;
  const float* p    = (const float*)d_in[0];
  const float* x    = (const float*)d_in[1];
  const int*   knn  = (const int*)d_in[2];
  const float* w1   = (const float*)d_in[3];
  const float* g1   = (const float*)d_in[4];
  const float* b1   = (const float*)d_in[5];
  const float* m1w1 = (const float*)d_in[6];
  const float* m1b1 = (const float*)d_in[7];
  const float* m1w2 = (const float*)d_in[8];
  const float* m1b2 = (const float*)d_in[9];
  const float* lpw1 = (const float*)d_in[10];
  const float* lpb1 = (const float*)d_in[11];
  const float* lpg  = (const float*)d_in[12];
  const float* lpbt = (const float*)d_in[13];
  const float* lpw2 = (const float*)d_in[14];
  const float* lpb2 = (const float*)d_in[15];
  const float* m2w1 = (const float*)d_in[16];
  const float* m2g1 = (const float*)d_in[17];
  const float* m2bt1= (const float*)d_in[18];
  const float* m2w2 = (const float*)d_in[19];
  const float* m2g2 = (const float*)d_in[20];
  const float* m2bt2= (const float*)d_in[21];
  const float* m2w3 = (const float*)d_in[22];
  const float* m2b3 = (const float*)d_in[23];
  const float* m3w  = (const float*)d_in[24];
  const float* m3b  = (const float*)d_in[25];
  const float* iw   = (const float*)d_in[26];
  const float* ib   = (const float*)d_in[27];
  const float* ixw  = (const float*)d_in[28];
  const float* ixb  = (const float*)d_in[29];
  const float* g2   = (const float*)d_in[30];
  const float* b2   = (const float*)d_in[31];
  const float* w3   = (const float*)d_in[32];
  const float* g3   = (const float*)d_in[33];
  const float* b3   = (const float*)d_in[34];
  float* out = (float*)d_out;
  float* ws  = (float*)d_ws;

  const int n = in_sizes[1] / 64;                // 32768
  const long long nk = (long long)n * 16;        // 524288

  float* cst = ws;
  unsigned int* smax = (unsigned int*)(ws + CONST_FLOATS);
  float* ssumseg = ws + CONST_FLOATS + 8LL * n;
  float* resid   = ws + CONST_FLOATS + 16LL * n;
  float* y1 = ws + CONST_FLOATS + 24LL * n;     // N*64, reused as y3
  float* z  = y1 + 64LL * n;                    // N*64
  float* xi = z + 64LL * n;                     // N*64 (x_intra -> x2)
  float* pr = xi + 64LL * n;                    // N*K*3
  float* en = pr + 48LL * n;                    // N*K*16
  float* h2 = en + 256LL * n;                   // N*K*8
  float* wsm = h2 + 128LL * n;                  // N*K*8
  float* sb = wsm + 128LL * n;                  // N*K*8
  float* vb = sb + 128LL * n;                   // N*K*8

  const int gB   = n / 64;            // 512
  const int nkB  = (int)(nk / 256);   // 2048
  const int nkB2 = (int)(nk / 512);   // 1024
  const int nkBi = (int)(nk / 128);   // 4096

  // zero stats + smax + ssum + resid
  hipMemsetAsync(d_ws, 0, (size_t)(CONST_FLOATS + 24LL * n) * sizeof(float), stream);

  // 1) y1 = x @ w1, bn1 stats
  k_gemm64<<<gB, 256, 0, stream>>>(x, w1, nullptr, nullptr, nullptr, y1,
                                   cst + S_BN1_SUM, cst + S_BN1_SQ, n);
  k_finalize_bn<<<1, 64, 0, stream>>>(cst + S_BN1_SUM, cst + S_BN1_SQ, g1, b1,
                                      cst + S_SC1, cst + S_SH1, 1.f / (float)n, 64);
  // 2) z = relu(bn1(y1)) @ m3w + m3b
  k_gemm64<<<gB, 256, 0, stream>>>(y1, m3w, m3b, cst + S_SC1, cst + S_SH1, z,
                                   nullptr, nullptr, n);
  // 3) p_r, energy, lp stats
  k_energy<<<nkB, 256, 0, stream>>>(p, y1, knn, m1w1, m1b1, m1w2, m1b2, lpw1, lpb1,
                                    cst + S_SC1, cst + S_SH1, pr, en, cst + S_LP_SUM);
  k_f2_lp<<<1, 64, 0, stream>>>(lpg, lpbt, lpw1, lpb1, lpw2, lpb2, cst, 1.f / (float)nk);
  // 4) h1 stats
  k_m2b1_stats<<<nkB, 256, 0, stream>>>(en, pr, cst, m2w1, cst + S_M2B1_SUM, cst + S_M2B1_SQ);
  k_finalize_bn<<<1, 64, 0, stream>>>(cst + S_M2B1_SUM, cst + S_M2B1_SQ, m2g1, m2bt1,
                                      cst + S_M2S1, cst + S_M2H1, 1.f / (float)nk, 64);
  // 5) h2 + stats
  k_h2<<<nkB2, 256, 0, stream>>>(en, pr, cst, m2w1, m2w2, h2, cst + S_M2B2_SUM, cst + S_M2B2_SQ);
  k_finalize_bn<<<1, 64, 0, stream>>>(cst + S_M2B2_SUM, cst + S_M2B2_SQ, m2g2, m2bt2,
                                      cst + S_M2S2, cst + S_M2H2, 1.f / (float)nk, 8);
  // 6) softmax weights
  k_softmax<<<nkB, 256, 0, stream>>>(h2, cst, m2w3, m2b3, wsm);
  // 7) xk, x_intra, s, v, segment max
  k_intra<<<nkBi, 128, 0, stream>>>(z, pr, knn, cst, lpw2, lpb2, iw, ib, ixw, ixb, wsm,
                                    xi, sb, vb, smax);
  // 8) scatter softmax
  k_scatter1<<<nkB, 256, 0, stream>>>(knn, smax, sb, ssumseg);
  k_scatter2<<<nkB, 256, 0, stream>>>(knn, sb, ssumseg, vb, resid);
  // 9) x2 = x_intra + tile(resid), bn2 stats
  k_x2_stats<<<gB, 256, 0, stream>>>(xi, resid, cst + S_BN2_SUM, cst + S_BN2_SQ, n);
  k_finalize_bn<<<1, 64, 0, stream>>>(cst + S_BN2_SUM, cst + S_BN2_SQ, g2, b2,
                                      cst + S_SC2, cst + S_SH2, 1.f / (float)n, 64);
  // 10) y3 = relu(bn2(x2)) @ w3, bn3 stats
  k_gemm64<<<gB, 256, 0, stream>>>(xi, w3, nullptr, cst + S_SC2, cst + S_SH2, y1,
                                   cst + S_BN3_SUM, cst + S_BN3_SQ, n);
  k_finalize_bn<<<1, 64, 0, stream>>>(cst + S_BN3_SUM, cst + S_BN3_SQ, g3, b3,
                                      cst + S_SC3, cst + S_SH3, 1.f / (float)n, 64);
  // 11) out = relu(bn3(y3) + x)
  k_out<<<(int)((long long)n * 64 / 1024), 256, 0, stream>>>(y1, x, cst, out);
}

// Round 2
// 928.113 us; speedup vs baseline: 1.7283x; 1.7283x over previous
//
#include <hip/hip_runtime.h>

// N = 32768 (runtime), C = 64, K = 16, CS = 8, SHARE = 8

enum {
  S_BN1_SUM = 0,    S_BN1_SQ = 64,
  S_LP_SUM = 128,   S_LP_SQ = 132,
  S_M2B1_SUM = 136, S_M2B1_SQ = 200,
  S_M2B2_SUM = 264, S_M2B2_SQ = 272,
  S_BN2_SUM = 280,  S_BN2_SQ = 344,
  S_BN3_SUM = 408,  S_BN3_SQ = 472,
  S_SC1 = 536,  S_SH1 = 600,
  S_LPSC = 664, S_LPSH = 668,
  S_M2S1 = 672, S_M2H1 = 736,
  S_M2S2 = 800, S_M2H2 = 808,
  S_SC2 = 816,  S_SH2 = 880,
  S_SC3 = 944,  S_SH3 = 1008,
  S_LPW2S = 1072, S_LPB2S = 1120,
  S_QW = 1136, S_QB = 1148,
  CONST_FLOATS = 1280
};

__device__ __forceinline__ unsigned int fkey(float f) {
  unsigned int u = __float_as_uint(f);
  return (u & 0x80000000u) ? ~u : (u | 0x80000000u);
}
__device__ __forceinline__ float funkey(unsigned int k) {
  unsigned int u = (k & 0x80000000u) ? (k & 0x7fffffffu) : ~k;
  return __uint_as_float(u);
}

// ---------------- partial-sum reduce: one block per channel ----------------
__global__ __launch_bounds__(256) void k_reduce(
    const float* __restrict__ partial, float* __restrict__ outbuf, int nblocks)
{
  const int tid = threadIdx.x;
  const float* src = partial + (size_t)blockIdx.x * nblocks;
  float s = 0.f;
  for (int t = tid; t < nblocks; t += 256) s += src[t];
  #pragma unroll
  for (int m = 1; m < 64; m <<= 1) s += __shfl_xor(s, m);
  __shared__ float wsum[4];
  if ((tid & 63) == 0) wsum[tid >> 6] = s;
  __syncthreads();
  if (tid == 0) outbuf[blockIdx.x] = wsum[0] + wsum[1] + wsum[2] + wsum[3];
}

// ---------------- generic 64x64 GEMM ----------------
__global__ __launch_bounds__(256) void k_gemm64(
    const float* __restrict__ in, const float* __restrict__ w,
    const float* __restrict__ bias,
    const float* __restrict__ sc, const float* __restrict__ sh,
    float* __restrict__ out,
    float* __restrict__ partial,   // [128 * gridDim.x] channel-major, or null
    int n)
{
  __shared__ float scsh[64], shsh[64];
  __shared__ float bsum[64], bsq[64];
  const int tid = threadIdx.x;
  const int lane = tid & 63;
  const int wave = tid >> 6;
  if (sc != nullptr && tid < 64) { scsh[tid] = sc[tid]; shsh[tid] = sh[tid]; }
  if (tid < 64) { bsum[tid] = 0.f; bsq[tid] = 0.f; }
  __syncthreads();

  float wreg[64];
  #pragma unroll
  for (int k = 0; k < 64; ++k) wreg[k] = w[k * 64 + lane];
  const float bz = bias ? bias[lane] : 0.f;

  float lsum = 0.f, lsq = 0.f;
  const int row0 = (blockIdx.x * 4 + wave) * 16;
  for (int r = 0; r < 16; ++r) {
    const int row = row0 + r;
    const float* xr = in + (size_t)row * 64;
    float acc = bz;
    if (sc != nullptr) {
      #pragma unroll
      for (int k = 0; k < 64; k += 4) {
        float4 xv = *(const float4*)(xr + k);
        float x0 = fmaxf(fmaf(xv.x, scsh[k + 0], shsh[k + 0]), 0.f);
        float x1 = fmaxf(fmaf(xv.y, scsh[k + 1], shsh[k + 1]), 0.f);
        float x2 = fmaxf(fmaf(xv.z, scsh[k + 2], shsh[k + 2]), 0.f);
        float x3 = fmaxf(fmaf(xv.w, scsh[k + 3], shsh[k + 3]), 0.f);
        acc = fmaf(x0, wreg[k + 0], acc);
        acc = fmaf(x1, wreg[k + 1], acc);
        acc = fmaf(x2, wreg[k + 2], acc);
        acc = fmaf(x3, wreg[k + 3], acc);
      }
    } else {
      #pragma unroll
      for (int k = 0; k < 64; k += 4) {
        float4 xv = *(const float4*)(xr + k);
        acc = fmaf(xv.x, wreg[k + 0], acc);
        acc = fmaf(xv.y, wreg[k + 1], acc);
        acc = fmaf(xv.z, wreg[k + 2], acc);
        acc = fmaf(xv.w, wreg[k + 3], acc);
      }
    }
    out[(size_t)row * 64 + lane] = acc;
    lsum += acc;
    lsq = fmaf(acc, acc, lsq);
  }
  if (partial != nullptr) {
    atomicAdd(&bsum[lane], lsum);
    atomicAdd(&bsq[lane], lsq);
    __syncthreads();
    if (tid < 64) {
      partial[(size_t)tid * gridDim.x + blockIdx.x] = bsum[tid];
      partial[(size_t)(tid + 64) * gridDim.x + blockIdx.x] = bsq[tid];
    }
  }
}

// ---------------- BN finalize ----------------
__global__ void k_finalize_bn(const float* __restrict__ ssum, const float* __restrict__ ssq,
                              const float* __restrict__ g, const float* __restrict__ b,
                              float* __restrict__ scale, float* __restrict__ shift,
                              float inv_count, int nch)
{
  int i = threadIdx.x;
  if (i < nch) {
    float m = ssum[i] * inv_count;
    float v = ssq[i] * inv_count - m * m;
    float rs = rsqrtf(v + 1e-5f);
    float s = g[i] * rs;
    scale[i] = s;
    shift[i] = fmaf(-m, s, b[i]);
  }
}

// ---------------- lp finalize + weight folding ----------------
__global__ void k_f2_lp(const float* __restrict__ lpg, const float* __restrict__ lpbt,
                        const float* __restrict__ lpw1, const float* __restrict__ lpb1,
                        const float* __restrict__ lpw2, const float* __restrict__ lpb2,
                        float* __restrict__ cst, float inv_count)
{
  int t = threadIdx.x;
  if (t < 3) {
    float m = cst[S_LP_SUM + t] * inv_count;
    float v = cst[S_LP_SQ + t] * inv_count - m * m;
    float rs = rsqrtf(v + 1e-5f);
    float s = lpg[t] * rs;
    cst[S_LPSC + t] = s;
    cst[S_LPSH + t] = fmaf(-m, s, lpbt[t]);
  }
  __syncthreads();
  if (t < 9)  cst[S_QW + t] = lpw1[t] * cst[S_LPSC + (t % 3)];
  if (t < 3)  cst[S_QB + t] = fmaf(lpb1[t], cst[S_LPSC + t], cst[S_LPSH + t]);
  if (t < 16) {
    float b = 0.f;
    for (int c2 = 0; c2 < 4; ++c2) b += lpb2[c2 * 16 + t];
    cst[S_LPB2S + t] = b;
    for (int r = 0; r < 3; ++r) {
      float w = 0.f;
      for (int c2 = 0; c2 < 4; ++c2) w += lpw2[r * 64 + c2 * 16 + t];
      cst[S_LPW2S + r * 16 + t] = w;
    }
  }
}

// ---------------- K2: p_r, energy, lp partials ----------------
__global__ __launch_bounds__(256) void k_energy(
    const float* __restrict__ p, const float* __restrict__ y1,
    const int* __restrict__ knn,
    const float* __restrict__ m1w1, const float* __restrict__ m1b1,
    const float* __restrict__ m1w2, const float* __restrict__ m1b2,
    const float* __restrict__ lpw1, const float* __restrict__ lpb1,
    const float* __restrict__ sc1, const float* __restrict__ sh1,
    float* __restrict__ p_r, float* __restrict__ energy,
    float* __restrict__ plp)    // [8 * gridDim.x] channel-major
{
  __shared__ float w1sh[67 * 16];
  __shared__ float w2sh[256];
  __shared__ float b1sh[16], b2sh[16];
  __shared__ float scsh[64], shsh[64];
  __shared__ float lpw1sh[9], lpb1sh[3];
  __shared__ float lpsh[4][8];
  const int tid = threadIdx.x;
  for (int i = tid; i < 67 * 16; i += 256) w1sh[i] = m1w1[i];
  w2sh[tid] = m1w2[tid];
  if (tid < 16) { b1sh[tid] = m1b1[tid]; b2sh[tid] = m1b2[tid]; }
  if (tid < 64) { scsh[tid] = sc1[tid]; shsh[tid] = sh1[tid]; }
  if (tid < 9) lpw1sh[tid] = lpw1[tid];
  if (tid < 3) lpb1sh[tid] = lpb1[tid];
  __syncthreads();

  const size_t g = (size_t)blockIdx.x * 256 + tid;
  const int i = (int)(g >> 4);
  const int j = knn[g];
  const float pr0 = p[j * 3 + 0] - p[i * 3 + 0];
  const float pr1 = p[j * 3 + 1] - p[i * 3 + 1];
  const float pr2 = p[j * 3 + 2] - p[i * 3 + 2];
  p_r[g * 3 + 0] = pr0; p_r[g * 3 + 1] = pr1; p_r[g * 3 + 2] = pr2;

  float acc1[16];
  #pragma unroll
  for (int t4 = 0; t4 < 16; t4 += 4) {
    float4 w0 = *(const float4*)(w1sh + 0 * 16 + t4);
    float4 w1v = *(const float4*)(w1sh + 1 * 16 + t4);
    float4 w2v = *(const float4*)(w1sh + 2 * 16 + t4);
    float4 bb = *(const float4*)(b1sh + t4);
    acc1[t4 + 0] = fmaf(pr2, w2v.x, fmaf(pr1, w1v.x, fmaf(pr0, w0.x, bb.x)));
    acc1[t4 + 1] = fmaf(pr2, w2v.y, fmaf(pr1, w1v.y, fmaf(pr0, w0.y, bb.y)));
    acc1[t4 + 2] = fmaf(pr2, w2v.z, fmaf(pr1, w1v.z, fmaf(pr0, w0.z, bb.z)));
    acc1[t4 + 3] = fmaf(pr2, w2v.w, fmaf(pr1, w1v.w, fmaf(pr0, w0.w, bb.w)));
  }
  const float* yr = y1 + (size_t)j * 64;
  for (int c = 0; c < 64; c += 4) {
    float4 yv = *(const float4*)(yr + c);
    float xx0 = fmaxf(fmaf(yv.x, scsh[c + 0], shsh[c + 0]), 0.f);
    float xx1 = fmaxf(fmaf(yv.y, scsh[c + 1], shsh[c + 1]), 0.f);
    float xx2 = fmaxf(fmaf(yv.z, scsh[c + 2], shsh[c + 2]), 0.f);
    float xx3 = fmaxf(fmaf(yv.w, scsh[c + 3], shsh[c + 3]), 0.f);
    float xx[4] = {xx0, xx1, xx2, xx3};
    #pragma unroll
    for (int d = 0; d < 4; ++d) {
      const float* wrow = w1sh + (3 + c + d) * 16;
      const float x = xx[d];
      #pragma unroll
      for (int t4 = 0; t4 < 16; t4 += 4) {
        float4 wv = *(const float4*)(wrow + t4);
        acc1[t4 + 0] = fmaf(x, wv.x, acc1[t4 + 0]);
        acc1[t4 + 1] = fmaf(x, wv.y, acc1[t4 + 1]);
        acc1[t4 + 2] = fmaf(x, wv.z, acc1[t4 + 2]);
        acc1[t4 + 3] = fmaf(x, wv.w, acc1[t4 + 3]);
      }
    }
  }
  float acc2[16];
  #pragma unroll
  for (int t4 = 0; t4 < 16; t4 += 4) {
    float4 bb = *(const float4*)(b2sh + t4);
    acc2[t4 + 0] = bb.x; acc2[t4 + 1] = bb.y; acc2[t4 + 2] = bb.z; acc2[t4 + 3] = bb.w;
  }
  #pragma unroll
  for (int t = 0; t < 16; ++t) {
    float a = fmaxf(acc1[t], 0.f);
    const float* wrow = w2sh + t * 16;
    #pragma unroll
    for (int t4 = 0; t4 < 16; t4 += 4) {
      float4 wv = *(const float4*)(wrow + t4);
      acc2[t4 + 0] = fmaf(a, wv.x, acc2[t4 + 0]);
      acc2[t4 + 1] = fmaf(a, wv.y, acc2[t4 + 1]);
      acc2[t4 + 2] = fmaf(a, wv.z, acc2[t4 + 2]);
      acc2[t4 + 3] = fmaf(a, wv.w, acc2[t4 + 3]);
    }
  }
  #pragma unroll
  for (int t = 0; t < 16; t += 4)
    *(float4*)(energy + g * 16 + t) = make_float4(acc2[t], acc2[t + 1], acc2[t + 2], acc2[t + 3]);

  // lp stats partials
  float q0 = fmaf(pr2, lpw1sh[6], fmaf(pr1, lpw1sh[3], fmaf(pr0, lpw1sh[0], lpb1sh[0])));
  float q1 = fmaf(pr2, lpw1sh[7], fmaf(pr1, lpw1sh[4], fmaf(pr0, lpw1sh[1], lpb1sh[1])));
  float q2 = fmaf(pr2, lpw1sh[8], fmaf(pr1, lpw1sh[5], fmaf(pr0, lpw1sh[2], lpb1sh[2])));
  float s0 = q0, s1 = q1, s2 = q2, qq0 = q0 * q0, qq1 = q1 * q1, qq2 = q2 * q2;
  #pragma unroll
  for (int m = 1; m < 64; m <<= 1) {
    s0 += __shfl_xor(s0, m); s1 += __shfl_xor(s1, m); s2 += __shfl_xor(s2, m);
    qq0 += __shfl_xor(qq0, m); qq1 += __shfl_xor(qq1, m); qq2 += __shfl_xor(qq2, m);
  }
  if ((tid & 63) == 0) {
    const int w = tid >> 6;
    lpsh[w][0] = s0; lpsh[w][1] = s1; lpsh[w][2] = s2; lpsh[w][3] = 0.f;
    lpsh[w][4] = qq0; lpsh[w][5] = qq1; lpsh[w][6] = qq2; lpsh[w][7] = 0.f;
  }
  __syncthreads();
  if (tid < 8) {
    float v = lpsh[0][tid] + lpsh[1][tid] + lpsh[2][tid] + lpsh[3][tid];
    plp[(size_t)tid * gridDim.x + blockIdx.x] = v;
  }
}

// ---------------- e-vector recompute helper ----------------
__device__ __forceinline__ void load_e(const float* __restrict__ energy,
                                       const float* __restrict__ p_r,
                                       const float* __restrict__ cst,
                                       size_t g, float* e)
{
  float4 t0 = *(const float4*)(energy + g * 16);
  float4 t1 = *(const float4*)(energy + g * 16 + 4);
  float4 t2 = *(const float4*)(energy + g * 16 + 8);
  float4 t3 = *(const float4*)(energy + g * 16 + 12);
  e[0] = t0.x; e[1] = t0.y; e[2] = t0.z; e[3] = t0.w;
  e[4] = t1.x; e[5] = t1.y; e[6] = t1.z; e[7] = t1.w;
  e[8] = t2.x; e[9] = t2.y; e[10] = t2.z; e[11] = t2.w;
  e[12] = t3.x; e[13] = t3.y; e[14] = t3.z; e[15] = t3.w;
  float pr0 = p_r[g * 3 + 0], pr1 = p_r[g * 3 + 1], pr2 = p_r[g * 3 + 2];
  float qn0 = fmaxf(fmaf(pr2, cst[S_QW + 6], fmaf(pr1, cst[S_QW + 3], fmaf(pr0, cst[S_QW + 0], cst[S_QB + 0]))), 0.f);
  float qn1 = fmaxf(fmaf(pr2, cst[S_QW + 7], fmaf(pr1, cst[S_QW + 4], fmaf(pr0, cst[S_QW + 1], cst[S_QB + 1]))), 0.f);
  float qn2 = fmaxf(fmaf(pr2, cst[S_QW + 8], fmaf(pr1, cst[S_QW + 5], fmaf(pr0, cst[S_QW + 2], cst[S_QB + 2]))), 0.f);
  #pragma unroll
  for (int t = 0; t < 16; ++t)
    e[16 + t] = fmaf(qn2, cst[S_LPW2S + 32 + t],
                fmaf(qn1, cst[S_LPW2S + 16 + t],
                fmaf(qn0, cst[S_LPW2S + t], cst[S_LPB2S + t])));
}

// ---------------- K3: stats of h1 = e @ m2w1 ----------------
__global__ __launch_bounds__(256) void k_m2b1_stats(
    const float* __restrict__ energy, const float* __restrict__ p_r,
    const float* __restrict__ cst, const float* __restrict__ m2w1,
    float* __restrict__ partial)   // [128 * gridDim.x]
{
  __shared__ float esh[32 * 260];
  __shared__ float lsum[64], lsq[64];
  const int tid = threadIdx.x;
  const int lane = tid & 63;
  const int wave = tid >> 6;
  if (tid < 64) { lsum[tid] = 0.f; lsq[tid] = 0.f; }
  float wreg[32];
  #pragma unroll
  for (int k = 0; k < 32; ++k) wreg[k] = m2w1[k * 64 + lane];

  const size_t g = (size_t)blockIdx.x * 256 + tid;
  float e[32];
  load_e(energy, p_r, cst, g, e);
  #pragma unroll
  for (int k = 0; k < 32; ++k) esh[k * 260 + tid] = e[k];
  __syncthreads();

  float ls = 0.f, lq = 0.f;
  for (int g4 = wave * 64; g4 < wave * 64 + 64; g4 += 4) {
    float h0 = 0.f, h1 = 0.f, h2 = 0.f, h3 = 0.f;
    #pragma unroll
    for (int k = 0; k < 32; ++k) {
      float4 ev = *(const float4*)(esh + k * 260 + g4);
      h0 = fmaf(ev.x, wreg[k], h0);
      h1 = fmaf(ev.y, wreg[k], h1);
      h2 = fmaf(ev.z, wreg[k], h2);
      h3 = fmaf(ev.w, wreg[k], h3);
    }
    ls += h0 + h1 + h2 + h3;
    lq += h0 * h0 + h1 * h1 + h2 * h2 + h3 * h3;
  }
  atomicAdd(&lsum[lane], ls);
  atomicAdd(&lsq[lane], lq);
  __syncthreads();
  if (tid < 64) {
    partial[(size_t)tid * gridDim.x + blockIdx.x] = lsum[tid];
    partial[(size_t)(tid + 64) * gridDim.x + blockIdx.x] = lsq[tid];
  }
}

// ---------------- K4: h2 = relu(bn(h1)) @ m2w2, + partials ----------------
__global__ __launch_bounds__(256) void k_h2(
    const float* __restrict__ energy, const float* __restrict__ p_r,
    const float* __restrict__ cst, const float* __restrict__ m2w1, const float* __restrict__ m2w2,
    float* __restrict__ h2out,
    float* __restrict__ partial)   // [16 * gridDim.x]
{
  __shared__ float wT[64 * 36];
  __shared__ float w2sh[512];
  __shared__ float scsh[64], shsh[64];
  __shared__ float redsh[4][16];
  const int tid = threadIdx.x;
  for (int idx = tid; idx < 2048; idx += 256) { int k = idx >> 6, c = idx & 63; wT[c * 36 + k] = m2w1[idx]; }
  for (int idx = tid; idx < 512; idx += 256) w2sh[idx] = m2w2[idx];
  if (tid < 64) { scsh[tid] = cst[S_M2S1 + tid]; shsh[tid] = cst[S_M2H1 + tid]; }
  __syncthreads();

  const size_t g0 = ((size_t)blockIdx.x * 256 + tid) * 2;
  float e0[32], e1[32];
  load_e(energy, p_r, cst, g0 + 0, e0);
  load_e(energy, p_r, cst, g0 + 1, e1);
  float a0[8], a1[8];
  #pragma unroll
  for (int t = 0; t < 8; ++t) { a0[t] = 0.f; a1[t] = 0.f; }
  for (int c = 0; c < 64; ++c) {
    const float* wc = wT + c * 36;
    float h0 = 0.f, h1 = 0.f;
    #pragma unroll
    for (int k = 0; k < 32; k += 4) {
      float4 wv = *(const float4*)(wc + k);
      h0 = fmaf(e0[k + 3], wv.w, fmaf(e0[k + 2], wv.z, fmaf(e0[k + 1], wv.y, fmaf(e0[k + 0], wv.x, h0))));
      h1 = fmaf(e1[k + 3], wv.w, fmaf(e1[k + 2], wv.z, fmaf(e1[k + 1], wv.y, fmaf(e1[k + 0], wv.x, h1))));
    }
    float x0 = fmaxf(fmaf(h0, scsh[c], shsh[c]), 0.f);
    float x1 = fmaxf(fmaf(h1, scsh[c], shsh[c]), 0.f);
    float4 wa = *(const float4*)(w2sh + c * 8);
    float4 wb = *(const float4*)(w2sh + c * 8 + 4);
    a0[0] = fmaf(x0, wa.x, a0[0]); a0[1] = fmaf(x0, wa.y, a0[1]); a0[2] = fmaf(x0, wa.z, a0[2]); a0[3] = fmaf(x0, wa.w, a0[3]);
    a0[4] = fmaf(x0, wb.x, a0[4]); a0[5] = fmaf(x0, wb.y, a0[5]); a0[6] = fmaf(x0, wb.z, a0[6]); a0[7] = fmaf(x0, wb.w, a0[7]);
    a1[0] = fmaf(x1, wa.x, a1[0]); a1[1] = fmaf(x1, wa.y, a1[1]); a1[2] = fmaf(x1, wa.z, a1[2]); a1[3] = fmaf(x1, wa.w, a1[3]);
    a1[4] = fmaf(x1, wb.x, a1[4]); a1[5] = fmaf(x1, wb.y, a1[5]); a1[6] = fmaf(x1, wb.z, a1[6]); a1[7] = fmaf(x1, wb.w, a1[7]);
  }
  *(float4*)(h2out + g0 * 8)      = make_float4(a0[0], a0[1], a0[2], a0[3]);
  *(float4*)(h2out + g0 * 8 + 4)  = make_float4(a0[4], a0[5], a0[6], a0[7]);
  *(float4*)(h2out + g0 * 8 + 8)  = make_float4(a1[0], a1[1], a1[2], a1[3]);
  *(float4*)(h2out + g0 * 8 + 12) = make_float4(a1[4], a1[5], a1[6], a1[7]);

  // per-wave shuffle reduce of 8 sums + 8 sqs, then cross-wave via LDS
  float st[8], sq[8];
  #pragma unroll
  for (int t = 0; t < 8; ++t) {
    st[t] = a0[t] + a1[t];
    sq[t] = fmaf(a0[t], a0[t], a1[t] * a1[t]);
  }
  #pragma unroll
  for (int m = 1; m < 64; m <<= 1) {
    #pragma unroll
    for (int t = 0; t < 8; ++t) { st[t] += __shfl_xor(st[t], m); sq[t] += __shfl_xor(sq[t], m); }
  }
  if ((tid & 63) == 0) {
    const int w = tid >> 6;
    #pragma unroll
    for (int t = 0; t < 8; ++t) { redsh[w][t] = st[t]; redsh[w][8 + t] = sq[t]; }
  }
  __syncthreads();
  if (tid < 16) {
    float v = redsh[0][tid] + redsh[1][tid] + redsh[2][tid] + redsh[3][tid];
    partial[(size_t)tid * gridDim.x + blockIdx.x] = v;
  }
}

// ---------------- K5a: softmax over k ----------------
__global__ __launch_bounds__(256) void k_softmax(
    const float* __restrict__ h2, const float* __restrict__ cst,
    const float* __restrict__ m2w3, const float* __restrict__ m2b3,
    float* __restrict__ wout)
{
  __shared__ float w3sh[64];
  __shared__ float b3sh[8], s2sh[8], h2sh[8];
  const int tid = threadIdx.x;
  if (tid < 64) w3sh[tid] = m2w3[tid];
  if (tid < 8) { b3sh[tid] = m2b3[tid]; s2sh[tid] = cst[S_M2S2 + tid]; h2sh[tid] = cst[S_M2H2 + tid]; }
  __syncthreads();
  const size_t g = (size_t)blockIdx.x * 256 + tid;
  float4 ha = *(const float4*)(h2 + g * 8);
  float4 hb = *(const float4*)(h2 + g * 8 + 4);
  float hn[8];
  hn[0] = fmaxf(fmaf(ha.x, s2sh[0], h2sh[0]), 0.f);
  hn[1] = fmaxf(fmaf(ha.y, s2sh[1], h2sh[1]), 0.f);
  hn[2] = fmaxf(fmaf(ha.z, s2sh[2], h2sh[2]), 0.f);
  hn[3] = fmaxf(fmaf(ha.w, s2sh[3], h2sh[3]), 0.f);
  hn[4] = fmaxf(fmaf(hb.x, s2sh[4], h2sh[4]), 0.f);
  hn[5] = fmaxf(fmaf(hb.y, s2sh[5], h2sh[5]), 0.f);
  hn[6] = fmaxf(fmaf(hb.z, s2sh[6], h2sh[6]), 0.f);
  hn[7] = fmaxf(fmaf(hb.w, s2sh[7], h2sh[7]), 0.f);
  float lg[8];
  #pragma unroll
  for (int t = 0; t < 8; ++t) {
    float a = b3sh[t];
    #pragma unroll
    for (int u = 0; u < 8; ++u) a = fmaf(hn[u], w3sh[u * 8 + t], a);
    lg[t] = a;
  }
  #pragma unroll
  for (int t = 0; t < 8; ++t) {
    float m = lg[t];
    m = fmaxf(m, __shfl_xor(m, 1));
    m = fmaxf(m, __shfl_xor(m, 2));
    m = fmaxf(m, __shfl_xor(m, 4));
    m = fmaxf(m, __shfl_xor(m, 8));
    float ex = __expf(lg[t] - m);
    float s = ex;
    s += __shfl_xor(s, 1);
    s += __shfl_xor(s, 2);
    s += __shfl_xor(s, 4);
    s += __shfl_xor(s, 8);
    lg[t] = ex / s;
  }
  *(float4*)(wout + g * 8)     = make_float4(lg[0], lg[1], lg[2], lg[3]);
  *(float4*)(wout + g * 8 + 4) = make_float4(lg[4], lg[5], lg[6], lg[7]);
}

// ---------------- K5b: xk, x_intra, s, v, segment-max ----------------
__global__ __launch_bounds__(128) void k_intra(
    const float* __restrict__ z, const float* __restrict__ p_r,
    const int* __restrict__ knn, const float* __restrict__ cst,
    const float* __restrict__ lpw2, const float* __restrict__ lpb2,
    const float* __restrict__ iw, const float* __restrict__ ib,
    const float* __restrict__ ixw, const float* __restrict__ ixb,
    const float* __restrict__ wsoft,
    float* __restrict__ x_intra, float* __restrict__ sbuf, float* __restrict__ vbuf,
    unsigned int* __restrict__ smax)
{
  __shared__ float xksh[128][65];
  __shared__ float lpw2sh[192], lpb2sh[64];
  __shared__ float iwsh[512], ixwsh[512];
  __shared__ float ibsh[8], ixbsh[8];
  const int tid = threadIdx.x;
  for (int idx = tid; idx < 192; idx += 128) lpw2sh[idx] = lpw2[idx];
  if (tid < 64) lpb2sh[tid] = lpb2[tid];
  for (int idx = tid; idx < 512; idx += 128) { iwsh[idx] = iw[idx]; ixwsh[idx] = ixw[idx]; }
  if (tid < 8) { ibsh[tid] = ib[tid]; ixbsh[tid] = ixb[tid]; }
  __syncthreads();

  const size_t g = (size_t)blockIdx.x * 128 + tid;
  const int j = knn[g];
  const float pr0 = p_r[g * 3 + 0], pr1 = p_r[g * 3 + 1], pr2 = p_r[g * 3 + 2];
  const float qn0 = fmaxf(fmaf(pr2, cst[S_QW + 6], fmaf(pr1, cst[S_QW + 3], fmaf(pr0, cst[S_QW + 0], cst[S_QB + 0]))), 0.f);
  const float qn1 = fmaxf(fmaf(pr2, cst[S_QW + 7], fmaf(pr1, cst[S_QW + 4], fmaf(pr0, cst[S_QW + 1], cst[S_QB + 1]))), 0.f);
  const float qn2 = fmaxf(fmaf(pr2, cst[S_QW + 8], fmaf(pr1, cst[S_QW + 5], fmaf(pr0, cst[S_QW + 2], cst[S_QB + 2]))), 0.f);
  float4 wka = *(const float4*)(wsoft + g * 8);
  float4 wkb = *(const float4*)(wsoft + g * 8 + 4);
  float wk[8] = {wka.x, wka.y, wka.z, wka.w, wkb.x, wkb.y, wkb.z, wkb.w};
  float sacc[8], vacc[8];
  #pragma unroll
  for (int t = 0; t < 8; ++t) { sacc[t] = ibsh[t]; vacc[t] = ixbsh[t]; }
  const float* zr = z + (size_t)j * 64;
  for (int c = 0; c < 64; c += 4) {
    float4 zv = *(const float4*)(zr + c);
    float4 l0 = *(const float4*)(lpw2sh + c);
    float4 l1 = *(const float4*)(lpw2sh + 64 + c);
    float4 l2 = *(const float4*)(lpw2sh + 128 + c);
    float4 lb = *(const float4*)(lpb2sh + c);
    float xkv[4];
    xkv[0] = (zv.x + fmaf(qn2, l2.x, fmaf(qn1, l1.x, fmaf(qn0, l0.x, lb.x)))) * wk[(c + 0) & 7];
    xkv[1] = (zv.y + fmaf(qn2, l2.y, fmaf(qn1, l1.y, fmaf(qn0, l0.y, lb.y)))) * wk[(c + 1) & 7];
    xkv[2] = (zv.z + fmaf(qn2, l2.z, fmaf(qn1, l1.z, fmaf(qn0, l0.z, lb.z)))) * wk[(c + 2) & 7];
    xkv[3] = (zv.w + fmaf(qn2, l2.w, fmaf(qn1, l1.w, fmaf(qn0, l0.w, lb.w)))) * wk[(c + 3) & 7];
    xksh[tid][c + 0] = xkv[0];
    xksh[tid][c + 1] = xkv[1];
    xksh[tid][c + 2] = xkv[2];
    xksh[tid][c + 3] = xkv[3];
    #pragma unroll
    for (int d = 0; d < 4; ++d) {
      const float xk = xkv[d];
      const float* iwc = iwsh + (c + d) * 8;
      const float* ixwc = ixwsh + (c + d) * 8;
      float4 a0 = *(const float4*)(iwc);
      float4 a1 = *(const float4*)(iwc + 4);
      float4 b0 = *(const float4*)(ixwc);
      float4 b1 = *(const float4*)(ixwc + 4);
      sacc[0] = fmaf(xk, a0.x, sacc[0]); sacc[1] = fmaf(xk, a0.y, sacc[1]); sacc[2] = fmaf(xk, a0.z, sacc[2]); sacc[3] = fmaf(xk, a0.w, sacc[3]);
      sacc[4] = fmaf(xk, a1.x, sacc[4]); sacc[5] = fmaf(xk, a1.y, sacc[5]); sacc[6] = fmaf(xk, a1.z, sacc[6]); sacc[7] = fmaf(xk, a1.w, sacc[7]);
      vacc[0] = fmaf(xk, b0.x, vacc[0]); vacc[1] = fmaf(xk, b0.y, vacc[1]); vacc[2] = fmaf(xk, b0.z, vacc[2]); vacc[3] = fmaf(xk, b0.w, vacc[3]);
      vacc[4] = fmaf(xk, b1.x, vacc[4]); vacc[5] = fmaf(xk, b1.y, vacc[5]); vacc[6] = fmaf(xk, b1.z, vacc[6]); vacc[7] = fmaf(xk, b1.w, vacc[7]);
    }
  }
  *(float4*)(sbuf + g * 8)     = make_float4(sacc[0], sacc[1], sacc[2], sacc[3]);
  *(float4*)(sbuf + g * 8 + 4) = make_float4(sacc[4], sacc[5], sacc[6], sacc[7]);
  *(float4*)(vbuf + g * 8)     = make_float4(vacc[0], vacc[1], vacc[2], vacc[3]);
  *(float4*)(vbuf + g * 8 + 4) = make_float4(vacc[4], vacc[5], vacc[6], vacc[7]);
  #pragma unroll
  for (int t = 0; t < 8; ++t) atomicMax(&smax[(size_t)j * 8 + t], fkey(sacc[t]));
  __syncthreads();
  const int nl = tid >> 4;
  const int cb = (tid & 15) * 4;
  float o0 = 0.f, o1 = 0.f, o2 = 0.f, o3 = 0.f;
  #pragma unroll
  for (int k = 0; k < 16; ++k) {
    const float* xr = &xksh[nl * 16 + k][cb];
    o0 += xr[0]; o1 += xr[1]; o2 += xr[2]; o3 += xr[3];
  }
  const size_t nrow = (size_t)blockIdx.x * 8 + nl;
  *(float4*)(x_intra + nrow * 64 + cb) = make_float4(o0, o1, o2, o3);
}

// ---------------- K6: exp + segment sum ----------------
__global__ __launch_bounds__(256) void k_scatter1(
    const int* __restrict__ knn, const unsigned int* __restrict__ smax,
    float* __restrict__ sbuf, float* __restrict__ ssum)
{
  const size_t g = (size_t)blockIdx.x * 256 + threadIdx.x;
  const int j = knn[g];
  float4 a = *(const float4*)(sbuf + g * 8);
  float4 b = *(const float4*)(sbuf + g * 8 + 4);
  float sv[8] = {a.x, a.y, a.z, a.w, b.x, b.y, b.z, b.w};
  float ex[8];
  #pragma unroll
  for (int t = 0; t < 8; ++t) {
    float sm = funkey(smax[(size_t)j * 8 + t]);
    ex[t] = __expf(sv[t] - sm);
    atomicAdd(&ssum[(size_t)j * 8 + t], ex[t]);
  }
  *(float4*)(sbuf + g * 8)     = make_float4(ex[0], ex[1], ex[2], ex[3]);
  *(float4*)(sbuf + g * 8 + 4) = make_float4(ex[4], ex[5], ex[6], ex[7]);
}

// ---------------- K7: residual scatter ----------------
__global__ __launch_bounds__(256) void k_scatter2(
    const int* __restrict__ knn, const float* __restrict__ sbuf,
    const float* __restrict__ ssum, const float* __restrict__ vbuf,
    float* __restrict__ resid)
{
  const size_t g = (size_t)blockIdx.x * 256 + threadIdx.x;
  const int j = knn[g];
  float4 ea = *(const float4*)(sbuf + g * 8);
  float4 eb = *(const float4*)(sbuf + g * 8 + 4);
  float4 va = *(const float4*)(vbuf + g * 8);
  float4 vb = *(const float4*)(vbuf + g * 8 + 4);
  float ex[8] = {ea.x, ea.y, ea.z, ea.w, eb.x, eb.y, eb.z, eb.w};
  float vv[8] = {va.x, va.y, va.z, va.w, vb.x, vb.y, vb.z, vb.w};
  #pragma unroll
  for (int t = 0; t < 8; ++t) {
    float prob = ex[t] / ssum[(size_t)j * 8 + t];
    atomicAdd(&resid[(size_t)j * 8 + t], vv[t] * prob);
  }
}

// ---------------- K8: x2 = x_intra + tile(resid), bn2 partials ----------------
__global__ __launch_bounds__(256) void k_x2_stats(
    float* __restrict__ xi, const float* __restrict__ resid,
    float* __restrict__ partial, int n)
{
  __shared__ float bsum[64], bsq[64];
  const int tid = threadIdx.x;
  const int lane = tid & 63;
  const int wave = tid >> 6;
  if (tid < 64) { bsum[tid] = 0.f; bsq[tid] = 0.f; }
  __syncthreads();
  float ls = 0.f, lq = 0.f;
  const int row0 = (blockIdx.x * 4 + wave) * 16;
  for (int r = 0; r < 16; ++r) {
    const int row = row0 + r;
    float v = xi[(size_t)row * 64 + lane] + resid[(size_t)row * 8 + (lane & 7)];
    xi[(size_t)row * 64 + lane] = v;
    ls += v;
    lq = fmaf(v, v, lq);
  }
  atomicAdd(&bsum[lane], ls);
  atomicAdd(&bsq[lane], lq);
  __syncthreads();
  if (tid < 64) {
    partial[(size_t)tid * gridDim.x + blockIdx.x] = bsum[tid];
    partial[(size_t)(tid + 64) * gridDim.x + blockIdx.x] = bsq[tid];
  }
}

// ---------------- K10: final bn3 + residual + relu ----------------
__global__ __launch_bounds__(256) void k_out(
    const float* __restrict__ y3, const float* __restrict__ x0,
    const float* __restrict__ cst, float* __restrict__ out)
{
  __shared__ float scsh[64], shsh[64];
  const int tid = threadIdx.x;
  if (tid < 64) { scsh[tid] = cst[S_SC3 + tid]; shsh[tid] = cst[S_SH3 + tid]; }
  __syncthreads();
  const size_t i = ((size_t)blockIdx.x * 256 + tid) * 4;
  float4 y = *(const float4*)(y3 + i);
  float4 x = *(const float4*)(x0 + i);
  const int c = (int)(i & 63);
  float4 o;
  o.x = fmaxf(fmaf(y.x, scsh[c + 0], shsh[c + 0]) + x.x, 0.f);
  o.y = fmaxf(fmaf(y.y, scsh[c + 1], shsh[c + 1]) + x.y, 0.f);
  o.z = fmaxf(fmaf(y.z, scsh[c + 2], shsh[c + 2]) + x.z, 0.f);
  o.w = fmaxf(fmaf(y.w, scsh[c + 3], shsh[c + 3]) + x.w, 0.f);
  *(float4*)(out + i) = o;
}

// ---------------- launch ----------------
extern "C" void kernel_launch(void* const* d_in, const int* in_sizes, int n_in,
                              void* d_out, int out_size, void* d_ws, size_t ws_size,
                              hipStream_t stream)
{
  (void)n_in; (void)out_size; (void)ws_size;
  const float* p    = (const float*)d_in[0];
  const float* x    = (const float*)d_in[1];
  const int*   knn  = (const int*)d_in[2];
  const float* w1   = (const float*)d_in[3];
  const float* g1   = (const float*)d_in[4];
  const float* b1   = (const float*)d_in[5];
  const float* m1w1 = (const float*)d_in[6];
  const float* m1b1 = (const float*)d_in[7];
  const float* m1w2 = (const float*)d_in[8];
  const float* m1b2 = (const float*)d_in[9];
  const float* lpw1 = (const float*)d_in[10];
  const float* lpb1 = (const float*)d_in[11];
  const float* lpg  = (const float*)d_in[12];
  const float* lpbt = (const float*)d_in[13];
  const float* lpw2 = (const float*)d_in[14];
  const float* lpb2 = (const float*)d_in[15];
  const float* m2w1 = (const float*)d_in[16];
  const float* m2g1 = (const float*)d_in[17];
  const float* m2bt1= (const float*)d_in[18];
  const float* m2w2 = (const float*)d_in[19];
  const float* m2g2 = (const float*)d_in[20];
  const float* m2bt2= (const float*)d_in[21];
  const float* m2w3 = (const float*)d_in[22];
  const float* m2b3 = (const float*)d_in[23];
  const float* m3w  = (const float*)d_in[24];
  const float* m3b  = (const float*)d_in[25];
  const float* iw   = (const float*)d_in[26];
  const float* ib   = (const float*)d_in[27];
  const float* ixw  = (const float*)d_in[28];
  const float* ixb  = (const float*)d_in[29];
  const float* g2   = (const float*)d_in[30];
  const float* b2   = (const float*)d_in[31];
  const float* w3   = (const float*)d_in[32];
  const float* g3   = (const float*)d_in[33];
  const float* b3   = (const float*)d_in[34];
  float* out = (float*)d_out;
  float* ws  = (float*)d_ws;

  const int n = in_sizes[1] / 64;                // 32768
  const long long nk = (long long)n * 16;        // 524288

  float* cst = ws;
  unsigned int* smax = (unsigned int*)(ws + CONST_FLOATS);
  float* ssumseg = ws + CONST_FLOATS + 8LL * n;
  float* resid   = ws + CONST_FLOATS + 16LL * n;
  float* y1 = ws + CONST_FLOATS + 24LL * n;     // N*64, reused as y3
  float* z  = y1 + 64LL * n;                    // N*64
  float* xi = z + 64LL * n;                     // N*64 (x_intra -> x2)
  float* pr = xi + 64LL * n;                    // N*K*3
  float* en = pr + 48LL * n;                    // N*K*16
  float* h2 = en + 256LL * n;                   // N*K*8
  float* wsm = h2 + 128LL * n;                  // N*K*8
  float* sb = wsm + 128LL * n;                  // N*K*8
  float* vb = sb + 128LL * n;                   // N*K*8

  const int gB   = n / 64;            // 512
  const int nkB  = (int)(nk / 256);   // 2048
  const int nkB2 = (int)(nk / 512);   // 1024
  const int nkBi = (int)(nk / 128);   // 4096

  // partial-sum scratch (channel-major)
  float* pbn1  = vb + 128LL * n;                 // 128 * gB
  float* plp   = pbn1 + 128LL * gB;              // 8 * nkB
  float* pm2b1 = plp + 8LL * nkB;                // 128 * nkB
  float* pm2b2 = pm2b1 + 128LL * nkB;            // 16 * nkB2
  float* pbn2  = pm2b2 + 16LL * nkB2;            // 128 * gB
  float* pbn3  = pbn2 + 128LL * gB;              // 128 * gB

  // zero smax + ssum + resid (+ const area)
  hipMemsetAsync(d_ws, 0, (size_t)(CONST_FLOATS + 24LL * n) * sizeof(float), stream);

  // 1) y1 = x @ w1, bn1 partials
  k_gemm64<<<gB, 256, 0, stream>>>(x, w1, nullptr, nullptr, nullptr, y1, pbn1, n);
  k_reduce<<<128, 256, 0, stream>>>(pbn1, cst + S_BN1_SUM, gB);
  k_finalize_bn<<<1, 64, 0, stream>>>(cst + S_BN1_SUM, cst + S_BN1_SQ, g1, b1,
                                      cst + S_SC1, cst + S_SH1, 1.f / (float)n, 64);
  // 2) z = relu(bn1(y1)) @ m3w + m3b
  k_gemm64<<<gB, 256, 0, stream>>>(y1, m3w, m3b, cst + S_SC1, cst + S_SH1, z, nullptr, n);
  // 3) p_r, energy, lp partials
  k_energy<<<nkB, 256, 0, stream>>>(p, y1, knn, m1w1, m1b1, m1w2, m1b2, lpw1, lpb1,
                                    cst + S_SC1, cst + S_SH1, pr, en, plp);
  k_reduce<<<8, 256, 0, stream>>>(plp, cst + S_LP_SUM, nkB);
  k_f2_lp<<<1, 64, 0, stream>>>(lpg, lpbt, lpw1, lpb1, lpw2, lpb2, cst, 1.f / (float)nk);
  // 4) h1 stats
  k_m2b1_stats<<<nkB, 256, 0, stream>>>(en, pr, cst, m2w1, pm2b1);
  k_reduce<<<128, 256, 0, stream>>>(pm2b1, cst + S_M2B1_SUM, nkB);
  k_finalize_bn<<<1, 64, 0, stream>>>(cst + S_M2B1_SUM, cst + S_M2B1_SQ, m2g1, m2bt1,
                                      cst + S_M2S1, cst + S_M2H1, 1.f / (float)nk, 64);
  // 5) h2 + stats
  k_h2<<<nkB2, 256, 0, stream>>>(en, pr, cst, m2w1, m2w2, h2, pm2b2);
  k_reduce<<<16, 256, 0, stream>>>(pm2b2, cst + S_M2B2_SUM, nkB2);
  k_finalize_bn<<<1, 64, 0, stream>>>(cst + S_M2B2_SUM, cst + S_M2B2_SQ, m2g2, m2bt2,
                                      cst + S_M2S2, cst + S_M2H2, 1.f / (float)nk, 8);
  // 6) softmax weights
  k_softmax<<<nkB, 256, 0, stream>>>(h2, cst, m2w3, m2b3, wsm);
  // 7) xk, x_intra, s, v, segment max
  k_intra<<<nkBi, 128, 0, stream>>>(z, pr, knn, cst, lpw2, lpb2, iw, ib, ixw, ixb, wsm,
                                    xi, sb, vb, smax);
  // 8) scatter softmax
  k_scatter1<<<nkB, 256, 0, stream>>>(knn, smax, sb, ssumseg);
  k_scatter2<<<nkB, 256, 0, stream>>>(knn, sb, ssumseg, vb, resid);
  // 9) x2 = x_intra + tile(resid), bn2 partials
  k_x2_stats<<<gB, 256, 0, stream>>>(xi, resid, pbn2, n);
  k_reduce<<<128, 256, 0, stream>>>(pbn2, cst + S_BN2_SUM, gB);
  k_finalize_bn<<<1, 64, 0, stream>>>(cst + S_BN2_SUM, cst + S_BN2_SQ, g2, b2,
                                      cst + S_SC2, cst + S_SH2, 1.f / (float)n, 64);
  // 10) y3 = relu(bn2(x2)) @ w3, bn3 partials
  k_gemm64<<<gB, 256, 0, stream>>>(xi, w3, nullptr, cst + S_SC2, cst + S_SH2, y1, pbn3, n);
  k_reduce<<<128, 256, 0, stream>>>(pbn3, cst + S_BN3_SUM, gB);
  k_finalize_bn<<<1, 64, 0, stream>>>(cst + S_BN3_SUM, cst + S_BN3_SQ, g3, b3,
                                      cst + S_SC3, cst + S_SH3, 1.f / (float)n, 64);
  // 11) out = relu(bn3(y3) + x)
  k_out<<<(int)((long long)n * 64 / 1024), 256, 0, stream>>>(y1, x, cst, out);
}

// Round 3
// 766.510 us; speedup vs baseline: 2.0927x; 1.2108x over previous
//
#include <hip/hip_runtime.h>

// N = 32768 (runtime), C = 64, K = 16, CS = 8, SHARE = 8

enum {
  S_BN1_SUM = 0,    S_BN1_SQ = 64,
  S_LP_SUM = 128,   S_LP_SQ = 132,
  S_M2B1_SUM = 136, S_M2B1_SQ = 200,
  S_M2B2_SUM = 264, S_M2B2_SQ = 272,
  S_BN2_SUM = 280,  S_BN2_SQ = 344,
  S_BN3_SUM = 408,  S_BN3_SQ = 472,
  S_SC1 = 536,  S_SH1 = 600,
  S_LPSC = 664, S_LPSH = 668,
  S_M2S1 = 672, S_M2H1 = 736,
  S_M2S2 = 800, S_M2H2 = 808,
  S_SC2 = 816,  S_SH2 = 880,
  S_SC3 = 944,  S_SH3 = 1008,
  S_LPW2S = 1072, S_LPB2S = 1120,
  S_QW = 1136, S_QB = 1148,
  CONST_FLOATS = 1280
};

// ---------------- partial-sum reduce: one block per channel ----------------
__global__ __launch_bounds__(256) void k_reduce(
    const float* __restrict__ partial, float* __restrict__ outbuf, int nblocks)
{
  const int tid = threadIdx.x;
  const float* src = partial + (size_t)blockIdx.x * nblocks;
  float s = 0.f;
  for (int t = tid; t < nblocks; t += 256) s += src[t];
  #pragma unroll
  for (int m = 1; m < 64; m <<= 1) s += __shfl_xor(s, m);
  __shared__ float wsum[4];
  if ((tid & 63) == 0) wsum[tid >> 6] = s;
  __syncthreads();
  if (tid == 0) outbuf[blockIdx.x] = wsum[0] + wsum[1] + wsum[2] + wsum[3];
}

// ---------------- generic 64x64 GEMM ----------------
__global__ __launch_bounds__(256) void k_gemm64(
    const float* __restrict__ in, const float* __restrict__ w,
    const float* __restrict__ bias,
    const float* __restrict__ sc, const float* __restrict__ sh,
    float* __restrict__ out,
    float* __restrict__ partial,   // [128 * gridDim.x] channel-major, or null
    int n)
{
  __shared__ float scsh[64], shsh[64];
  __shared__ float bsum[64], bsq[64];
  const int tid = threadIdx.x;
  const int lane = tid & 63;
  const int wave = tid >> 6;
  if (sc != nullptr && tid < 64) { scsh[tid] = sc[tid]; shsh[tid] = sh[tid]; }
  if (tid < 64) { bsum[tid] = 0.f; bsq[tid] = 0.f; }
  __syncthreads();

  float wreg[64];
  #pragma unroll
  for (int k = 0; k < 64; ++k) wreg[k] = w[k * 64 + lane];
  const float bz = bias ? bias[lane] : 0.f;

  float lsum = 0.f, lsq = 0.f;
  const int row0 = (blockIdx.x * 4 + wave) * 16;
  for (int r = 0; r < 16; ++r) {
    const int row = row0 + r;
    const float* xr = in + (size_t)row * 64;
    float acc = bz;
    if (sc != nullptr) {
      #pragma unroll
      for (int k = 0; k < 64; k += 4) {
        float4 xv = *(const float4*)(xr + k);
        float x0 = fmaxf(fmaf(xv.x, scsh[k + 0], shsh[k + 0]), 0.f);
        float x1 = fmaxf(fmaf(xv.y, scsh[k + 1], shsh[k + 1]), 0.f);
        float x2 = fmaxf(fmaf(xv.z, scsh[k + 2], shsh[k + 2]), 0.f);
        float x3 = fmaxf(fmaf(xv.w, scsh[k + 3], shsh[k + 3]), 0.f);
        acc = fmaf(x0, wreg[k + 0], acc);
        acc = fmaf(x1, wreg[k + 1], acc);
        acc = fmaf(x2, wreg[k + 2], acc);
        acc = fmaf(x3, wreg[k + 3], acc);
      }
    } else {
      #pragma unroll
      for (int k = 0; k < 64; k += 4) {
        float4 xv = *(const float4*)(xr + k);
        acc = fmaf(xv.x, wreg[k + 0], acc);
        acc = fmaf(xv.y, wreg[k + 1], acc);
        acc = fmaf(xv.z, wreg[k + 2], acc);
        acc = fmaf(xv.w, wreg[k + 3], acc);
      }
    }
    out[(size_t)row * 64 + lane] = acc;
    lsum += acc;
    lsq = fmaf(acc, acc, lsq);
  }
  if (partial != nullptr) {
    atomicAdd(&bsum[lane], lsum);
    atomicAdd(&bsq[lane], lsq);
    __syncthreads();
    if (tid < 64) {
      partial[(size_t)tid * gridDim.x + blockIdx.x] = bsum[tid];
      partial[(size_t)(tid + 64) * gridDim.x + blockIdx.x] = bsq[tid];
    }
  }
}

// ---------------- BN finalize ----------------
__global__ void k_finalize_bn(const float* __restrict__ ssum, const float* __restrict__ ssq,
                              const float* __restrict__ g, const float* __restrict__ b,
                              float* __restrict__ scale, float* __restrict__ shift,
                              float inv_count, int nch)
{
  int i = threadIdx.x;
  if (i < nch) {
    float m = ssum[i] * inv_count;
    float v = ssq[i] * inv_count - m * m;
    float rs = rsqrtf(v + 1e-5f);
    float s = g[i] * rs;
    scale[i] = s;
    shift[i] = fmaf(-m, s, b[i]);
  }
}

// ---------------- lp finalize + weight folding ----------------
__global__ void k_f2_lp(const float* __restrict__ lpg, const float* __restrict__ lpbt,
                        const float* __restrict__ lpw1, const float* __restrict__ lpb1,
                        const float* __restrict__ lpw2, const float* __restrict__ lpb2,
                        float* __restrict__ cst, float inv_count)
{
  int t = threadIdx.x;
  if (t < 3) {
    float m = cst[S_LP_SUM + t] * inv_count;
    float v = cst[S_LP_SQ + t] * inv_count - m * m;
    float rs = rsqrtf(v + 1e-5f);
    float s = lpg[t] * rs;
    cst[S_LPSC + t] = s;
    cst[S_LPSH + t] = fmaf(-m, s, lpbt[t]);
  }
  __syncthreads();
  if (t < 9)  cst[S_QW + t] = lpw1[t] * cst[S_LPSC + (t % 3)];
  if (t < 3)  cst[S_QB + t] = fmaf(lpb1[t], cst[S_LPSC + t], cst[S_LPSH + t]);
  if (t < 16) {
    float b = 0.f;
    for (int c2 = 0; c2 < 4; ++c2) b += lpb2[c2 * 16 + t];
    cst[S_LPB2S + t] = b;
    for (int r = 0; r < 3; ++r) {
      float w = 0.f;
      for (int c2 = 0; c2 < 4; ++c2) w += lpw2[r * 64 + c2 * 16 + t];
      cst[S_LPW2S + r * 16 + t] = w;
    }
  }
}

// ---------------- K2: p_r, energy, lp partials ----------------
__global__ __launch_bounds__(256) void k_energy(
    const float* __restrict__ p, const float* __restrict__ y1,
    const int* __restrict__ knn,
    const float* __restrict__ m1w1, const float* __restrict__ m1b1,
    const float* __restrict__ m1w2, const float* __restrict__ m1b2,
    const float* __restrict__ lpw1, const float* __restrict__ lpb1,
    const float* __restrict__ sc1, const float* __restrict__ sh1,
    float* __restrict__ p_r, float* __restrict__ energy,
    float* __restrict__ plp)    // [8 * gridDim.x] channel-major
{
  __shared__ float w1sh[67 * 16];
  __shared__ float w2sh[256];
  __shared__ float b1sh[16], b2sh[16];
  __shared__ float scsh[64], shsh[64];
  __shared__ float lpw1sh[9], lpb1sh[3];
  __shared__ float lpsh[4][8];
  const int tid = threadIdx.x;
  for (int i = tid; i < 67 * 16; i += 256) w1sh[i] = m1w1[i];
  w2sh[tid] = m1w2[tid];
  if (tid < 16) { b1sh[tid] = m1b1[tid]; b2sh[tid] = m1b2[tid]; }
  if (tid < 64) { scsh[tid] = sc1[tid]; shsh[tid] = sh1[tid]; }
  if (tid < 9) lpw1sh[tid] = lpw1[tid];
  if (tid < 3) lpb1sh[tid] = lpb1[tid];
  __syncthreads();

  const size_t g = (size_t)blockIdx.x * 256 + tid;
  const int i = (int)(g >> 4);
  const int j = knn[g];
  const float pr0 = p[j * 3 + 0] - p[i * 3 + 0];
  const float pr1 = p[j * 3 + 1] - p[i * 3 + 1];
  const float pr2 = p[j * 3 + 2] - p[i * 3 + 2];
  p_r[g * 3 + 0] = pr0; p_r[g * 3 + 1] = pr1; p_r[g * 3 + 2] = pr2;

  float acc1[16];
  #pragma unroll
  for (int t4 = 0; t4 < 16; t4 += 4) {
    float4 w0 = *(const float4*)(w1sh + 0 * 16 + t4);
    float4 w1v = *(const float4*)(w1sh + 1 * 16 + t4);
    float4 w2v = *(const float4*)(w1sh + 2 * 16 + t4);
    float4 bb = *(const float4*)(b1sh + t4);
    acc1[t4 + 0] = fmaf(pr2, w2v.x, fmaf(pr1, w1v.x, fmaf(pr0, w0.x, bb.x)));
    acc1[t4 + 1] = fmaf(pr2, w2v.y, fmaf(pr1, w1v.y, fmaf(pr0, w0.y, bb.y)));
    acc1[t4 + 2] = fmaf(pr2, w2v.z, fmaf(pr1, w1v.z, fmaf(pr0, w0.z, bb.z)));
    acc1[t4 + 3] = fmaf(pr2, w2v.w, fmaf(pr1, w1v.w, fmaf(pr0, w0.w, bb.w)));
  }
  const float* yr = y1 + (size_t)j * 64;
  for (int c = 0; c < 64; c += 4) {
    float4 yv = *(const float4*)(yr + c);
    float xx0 = fmaxf(fmaf(yv.x, scsh[c + 0], shsh[c + 0]), 0.f);
    float xx1 = fmaxf(fmaf(yv.y, scsh[c + 1], shsh[c + 1]), 0.f);
    float xx2 = fmaxf(fmaf(yv.z, scsh[c + 2], shsh[c + 2]), 0.f);
    float xx3 = fmaxf(fmaf(yv.w, scsh[c + 3], shsh[c + 3]), 0.f);
    float xx[4] = {xx0, xx1, xx2, xx3};
    #pragma unroll
    for (int d = 0; d < 4; ++d) {
      const float* wrow = w1sh + (3 + c + d) * 16;
      const float x = xx[d];
      #pragma unroll
      for (int t4 = 0; t4 < 16; t4 += 4) {
        float4 wv = *(const float4*)(wrow + t4);
        acc1[t4 + 0] = fmaf(x, wv.x, acc1[t4 + 0]);
        acc1[t4 + 1] = fmaf(x, wv.y, acc1[t4 + 1]);
        acc1[t4 + 2] = fmaf(x, wv.z, acc1[t4 + 2]);
        acc1[t4 + 3] = fmaf(x, wv.w, acc1[t4 + 3]);
      }
    }
  }
  float acc2[16];
  #pragma unroll
  for (int t4 = 0; t4 < 16; t4 += 4) {
    float4 bb = *(const float4*)(b2sh + t4);
    acc2[t4 + 0] = bb.x; acc2[t4 + 1] = bb.y; acc2[t4 + 2] = bb.z; acc2[t4 + 3] = bb.w;
  }
  #pragma unroll
  for (int t = 0; t < 16; ++t) {
    float a = fmaxf(acc1[t], 0.f);
    const float* wrow = w2sh + t * 16;
    #pragma unroll
    for (int t4 = 0; t4 < 16; t4 += 4) {
      float4 wv = *(const float4*)(wrow + t4);
      acc2[t4 + 0] = fmaf(a, wv.x, acc2[t4 + 0]);
      acc2[t4 + 1] = fmaf(a, wv.y, acc2[t4 + 1]);
      acc2[t4 + 2] = fmaf(a, wv.z, acc2[t4 + 2]);
      acc2[t4 + 3] = fmaf(a, wv.w, acc2[t4 + 3]);
    }
  }
  #pragma unroll
  for (int t = 0; t < 16; t += 4)
    *(float4*)(energy + g * 16 + t) = make_float4(acc2[t], acc2[t + 1], acc2[t + 2], acc2[t + 3]);

  // lp stats partials
  float q0 = fmaf(pr2, lpw1sh[6], fmaf(pr1, lpw1sh[3], fmaf(pr0, lpw1sh[0], lpb1sh[0])));
  float q1 = fmaf(pr2, lpw1sh[7], fmaf(pr1, lpw1sh[4], fmaf(pr0, lpw1sh[1], lpb1sh[1])));
  float q2 = fmaf(pr2, lpw1sh[8], fmaf(pr1, lpw1sh[5], fmaf(pr0, lpw1sh[2], lpb1sh[2])));
  float s0 = q0, s1 = q1, s2 = q2, qq0 = q0 * q0, qq1 = q1 * q1, qq2 = q2 * q2;
  #pragma unroll
  for (int m = 1; m < 64; m <<= 1) {
    s0 += __shfl_xor(s0, m); s1 += __shfl_xor(s1, m); s2 += __shfl_xor(s2, m);
    qq0 += __shfl_xor(qq0, m); qq1 += __shfl_xor(qq1, m); qq2 += __shfl_xor(qq2, m);
  }
  if ((tid & 63) == 0) {
    const int w = tid >> 6;
    lpsh[w][0] = s0; lpsh[w][1] = s1; lpsh[w][2] = s2; lpsh[w][3] = 0.f;
    lpsh[w][4] = qq0; lpsh[w][5] = qq1; lpsh[w][6] = qq2; lpsh[w][7] = 0.f;
  }
  __syncthreads();
  if (tid < 8) {
    float v = lpsh[0][tid] + lpsh[1][tid] + lpsh[2][tid] + lpsh[3][tid];
    plp[(size_t)tid * gridDim.x + blockIdx.x] = v;
  }
}

// ---------------- e-vector recompute helper ----------------
__device__ __forceinline__ void load_e(const float* __restrict__ energy,
                                       const float* __restrict__ p_r,
                                       const float* __restrict__ cst,
                                       size_t g, float* e)
{
  float4 t0 = *(const float4*)(energy + g * 16);
  float4 t1 = *(const float4*)(energy + g * 16 + 4);
  float4 t2 = *(const float4*)(energy + g * 16 + 8);
  float4 t3 = *(const float4*)(energy + g * 16 + 12);
  e[0] = t0.x; e[1] = t0.y; e[2] = t0.z; e[3] = t0.w;
  e[4] = t1.x; e[5] = t1.y; e[6] = t1.z; e[7] = t1.w;
  e[8] = t2.x; e[9] = t2.y; e[10] = t2.z; e[11] = t2.w;
  e[12] = t3.x; e[13] = t3.y; e[14] = t3.z; e[15] = t3.w;
  float pr0 = p_r[g * 3 + 0], pr1 = p_r[g * 3 + 1], pr2 = p_r[g * 3 + 2];
  float qn0 = fmaxf(fmaf(pr2, cst[S_QW + 6], fmaf(pr1, cst[S_QW + 3], fmaf(pr0, cst[S_QW + 0], cst[S_QB + 0]))), 0.f);
  float qn1 = fmaxf(fmaf(pr2, cst[S_QW + 7], fmaf(pr1, cst[S_QW + 4], fmaf(pr0, cst[S_QW + 1], cst[S_QB + 1]))), 0.f);
  float qn2 = fmaxf(fmaf(pr2, cst[S_QW + 8], fmaf(pr1, cst[S_QW + 5], fmaf(pr0, cst[S_QW + 2], cst[S_QB + 2]))), 0.f);
  #pragma unroll
  for (int t = 0; t < 16; ++t)
    e[16 + t] = fmaf(qn2, cst[S_LPW2S + 32 + t],
                fmaf(qn1, cst[S_LPW2S + 16 + t],
                fmaf(qn0, cst[S_LPW2S + t], cst[S_LPB2S + t])));
}

// ---------------- K3: stats of h1 = e @ m2w1 ----------------
__global__ __launch_bounds__(256) void k_m2b1_stats(
    const float* __restrict__ energy, const float* __restrict__ p_r,
    const float* __restrict__ cst, const float* __restrict__ m2w1,
    float* __restrict__ partial)   // [128 * gridDim.x]
{
  __shared__ float esh[32 * 260];
  __shared__ float lsum[64], lsq[64];
  const int tid = threadIdx.x;
  const int lane = tid & 63;
  const int wave = tid >> 6;
  if (tid < 64) { lsum[tid] = 0.f; lsq[tid] = 0.f; }
  float wreg[32];
  #pragma unroll
  for (int k = 0; k < 32; ++k) wreg[k] = m2w1[k * 64 + lane];

  const size_t g = (size_t)blockIdx.x * 256 + tid;
  float e[32];
  load_e(energy, p_r, cst, g, e);
  #pragma unroll
  for (int k = 0; k < 32; ++k) esh[k * 260 + tid] = e[k];
  __syncthreads();

  float ls = 0.f, lq = 0.f;
  for (int g4 = wave * 64; g4 < wave * 64 + 64; g4 += 4) {
    float h0 = 0.f, h1 = 0.f, h2 = 0.f, h3 = 0.f;
    #pragma unroll
    for (int k = 0; k < 32; ++k) {
      float4 ev = *(const float4*)(esh + k * 260 + g4);
      h0 = fmaf(ev.x, wreg[k], h0);
      h1 = fmaf(ev.y, wreg[k], h1);
      h2 = fmaf(ev.z, wreg[k], h2);
      h3 = fmaf(ev.w, wreg[k], h3);
    }
    ls += h0 + h1 + h2 + h3;
    lq += h0 * h0 + h1 * h1 + h2 * h2 + h3 * h3;
  }
  atomicAdd(&lsum[lane], ls);
  atomicAdd(&lsq[lane], lq);
  __syncthreads();
  if (tid < 64) {
    partial[(size_t)tid * gridDim.x + blockIdx.x] = lsum[tid];
    partial[(size_t)(tid + 64) * gridDim.x + blockIdx.x] = lsq[tid];
  }
}

// ---------------- K4: h2 = relu(bn(h1)) @ m2w2, + partials ----------------
__global__ __launch_bounds__(256) void k_h2(
    const float* __restrict__ energy, const float* __restrict__ p_r,
    const float* __restrict__ cst, const float* __restrict__ m2w1, const float* __restrict__ m2w2,
    float* __restrict__ h2out,
    float* __restrict__ partial)   // [16 * gridDim.x]
{
  __shared__ float wT[64 * 36];
  __shared__ float w2sh[512];
  __shared__ float scsh[64], shsh[64];
  __shared__ float redsh[4][16];
  const int tid = threadIdx.x;
  for (int idx = tid; idx < 2048; idx += 256) { int k = idx >> 6, c = idx & 63; wT[c * 36 + k] = m2w1[idx]; }
  for (int idx = tid; idx < 512; idx += 256) w2sh[idx] = m2w2[idx];
  if (tid < 64) { scsh[tid] = cst[S_M2S1 + tid]; shsh[tid] = cst[S_M2H1 + tid]; }
  __syncthreads();

  const size_t g0 = ((size_t)blockIdx.x * 256 + tid) * 2;
  float e0[32], e1[32];
  load_e(energy, p_r, cst, g0 + 0, e0);
  load_e(energy, p_r, cst, g0 + 1, e1);
  float a0[8], a1[8];
  #pragma unroll
  for (int t = 0; t < 8; ++t) { a0[t] = 0.f; a1[t] = 0.f; }
  for (int c = 0; c < 64; ++c) {
    const float* wc = wT + c * 36;
    float h0 = 0.f, h1 = 0.f;
    #pragma unroll
    for (int k = 0; k < 32; k += 4) {
      float4 wv = *(const float4*)(wc + k);
      h0 = fmaf(e0[k + 3], wv.w, fmaf(e0[k + 2], wv.z, fmaf(e0[k + 1], wv.y, fmaf(e0[k + 0], wv.x, h0))));
      h1 = fmaf(e1[k + 3], wv.w, fmaf(e1[k + 2], wv.z, fmaf(e1[k + 1], wv.y, fmaf(e1[k + 0], wv.x, h1))));
    }
    float x0 = fmaxf(fmaf(h0, scsh[c], shsh[c]), 0.f);
    float x1 = fmaxf(fmaf(h1, scsh[c], shsh[c]), 0.f);
    float4 wa = *(const float4*)(w2sh + c * 8);
    float4 wb = *(const float4*)(w2sh + c * 8 + 4);
    a0[0] = fmaf(x0, wa.x, a0[0]); a0[1] = fmaf(x0, wa.y, a0[1]); a0[2] = fmaf(x0, wa.z, a0[2]); a0[3] = fmaf(x0, wa.w, a0[3]);
    a0[4] = fmaf(x0, wb.x, a0[4]); a0[5] = fmaf(x0, wb.y, a0[5]); a0[6] = fmaf(x0, wb.z, a0[6]); a0[7] = fmaf(x0, wb.w, a0[7]);
    a1[0] = fmaf(x1, wa.x, a1[0]); a1[1] = fmaf(x1, wa.y, a1[1]); a1[2] = fmaf(x1, wa.z, a1[2]); a1[3] = fmaf(x1, wa.w, a1[3]);
    a1[4] = fmaf(x1, wb.x, a1[4]); a1[5] = fmaf(x1, wb.y, a1[5]); a1[6] = fmaf(x1, wb.z, a1[6]); a1[7] = fmaf(x1, wb.w, a1[7]);
  }
  *(float4*)(h2out + g0 * 8)      = make_float4(a0[0], a0[1], a0[2], a0[3]);
  *(float4*)(h2out + g0 * 8 + 4)  = make_float4(a0[4], a0[5], a0[6], a0[7]);
  *(float4*)(h2out + g0 * 8 + 8)  = make_float4(a1[0], a1[1], a1[2], a1[3]);
  *(float4*)(h2out + g0 * 8 + 12) = make_float4(a1[4], a1[5], a1[6], a1[7]);

  float st[8], sq[8];
  #pragma unroll
  for (int t = 0; t < 8; ++t) {
    st[t] = a0[t] + a1[t];
    sq[t] = fmaf(a0[t], a0[t], a1[t] * a1[t]);
  }
  #pragma unroll
  for (int m = 1; m < 64; m <<= 1) {
    #pragma unroll
    for (int t = 0; t < 8; ++t) { st[t] += __shfl_xor(st[t], m); sq[t] += __shfl_xor(sq[t], m); }
  }
  if ((tid & 63) == 0) {
    const int w = tid >> 6;
    #pragma unroll
    for (int t = 0; t < 8; ++t) { redsh[w][t] = st[t]; redsh[w][8 + t] = sq[t]; }
  }
  __syncthreads();
  if (tid < 16) {
    float v = redsh[0][tid] + redsh[1][tid] + redsh[2][tid] + redsh[3][tid];
    partial[(size_t)tid * gridDim.x + blockIdx.x] = v;
  }
}

// ---------------- K5a: softmax over k ----------------
__global__ __launch_bounds__(256) void k_softmax(
    const float* __restrict__ h2, const float* __restrict__ cst,
    const float* __restrict__ m2w3, const float* __restrict__ m2b3,
    float* __restrict__ wout)
{
  __shared__ float w3sh[64];
  __shared__ float b3sh[8], s2sh[8], h2sh[8];
  const int tid = threadIdx.x;
  if (tid < 64) w3sh[tid] = m2w3[tid];
  if (tid < 8) { b3sh[tid] = m2b3[tid]; s2sh[tid] = cst[S_M2S2 + tid]; h2sh[tid] = cst[S_M2H2 + tid]; }
  __syncthreads();
  const size_t g = (size_t)blockIdx.x * 256 + tid;
  float4 ha = *(const float4*)(h2 + g * 8);
  float4 hb = *(const float4*)(h2 + g * 8 + 4);
  float hn[8];
  hn[0] = fmaxf(fmaf(ha.x, s2sh[0], h2sh[0]), 0.f);
  hn[1] = fmaxf(fmaf(ha.y, s2sh[1], h2sh[1]), 0.f);
  hn[2] = fmaxf(fmaf(ha.z, s2sh[2], h2sh[2]), 0.f);
  hn[3] = fmaxf(fmaf(ha.w, s2sh[3], h2sh[3]), 0.f);
  hn[4] = fmaxf(fmaf(hb.x, s2sh[4], h2sh[4]), 0.f);
  hn[5] = fmaxf(fmaf(hb.y, s2sh[5], h2sh[5]), 0.f);
  hn[6] = fmaxf(fmaf(hb.z, s2sh[6], h2sh[6]), 0.f);
  hn[7] = fmaxf(fmaf(hb.w, s2sh[7], h2sh[7]), 0.f);
  float lg[8];
  #pragma unroll
  for (int t = 0; t < 8; ++t) {
    float a = b3sh[t];
    #pragma unroll
    for (int u = 0; u < 8; ++u) a = fmaf(hn[u], w3sh[u * 8 + t], a);
    lg[t] = a;
  }
  #pragma unroll
  for (int t = 0; t < 8; ++t) {
    float m = lg[t];
    m = fmaxf(m, __shfl_xor(m, 1));
    m = fmaxf(m, __shfl_xor(m, 2));
    m = fmaxf(m, __shfl_xor(m, 4));
    m = fmaxf(m, __shfl_xor(m, 8));
    float ex = __expf(lg[t] - m);
    float s = ex;
    s += __shfl_xor(s, 1);
    s += __shfl_xor(s, 2);
    s += __shfl_xor(s, 4);
    s += __shfl_xor(s, 8);
    lg[t] = ex / s;
  }
  *(float4*)(wout + g * 8)     = make_float4(lg[0], lg[1], lg[2], lg[3]);
  *(float4*)(wout + g * 8 + 4) = make_float4(lg[4], lg[5], lg[6], lg[7]);
}

// ---------------- K5b: xk, x_intra, fused exp+segment-sum (XCD-local) ----------------
__global__ __launch_bounds__(128) void k_intra(
    const float* __restrict__ z, const float* __restrict__ p_r,
    const int* __restrict__ knn, const float* __restrict__ cst,
    const float* __restrict__ lpw2, const float* __restrict__ lpb2,
    const float* __restrict__ iw, const float* __restrict__ ib,
    const float* __restrict__ ixw, const float* __restrict__ ixb,
    const float* __restrict__ wsoft,
    float* __restrict__ x_intra,
    float* __restrict__ seg8,   // 8 XCD-local copies of [n][16] accumulators
    long long nseg)             // n * 16
{
  __shared__ float xksh[128][65];
  __shared__ float lpw2sh[192], lpb2sh[64];
  __shared__ float iwsh[512], ixwsh[512];
  __shared__ float ibsh[8], ixbsh[8];
  const int tid = threadIdx.x;
  for (int idx = tid; idx < 192; idx += 128) lpw2sh[idx] = lpw2[idx];
  if (tid < 64) lpb2sh[tid] = lpb2[tid];
  for (int idx = tid; idx < 512; idx += 128) { iwsh[idx] = iw[idx]; ixwsh[idx] = ixw[idx]; }
  if (tid < 8) { ibsh[tid] = ib[tid]; ixbsh[tid] = ixb[tid]; }
  __syncthreads();

  unsigned int xcd;
  asm volatile("s_getreg_b32 %0, hwreg(HW_REG_XCC_ID)" : "=s"(xcd));
  float* segc = seg8 + (size_t)(xcd & 7) * nseg;

  const size_t g = (size_t)blockIdx.x * 128 + tid;
  const int j = knn[g];
  const float pr0 = p_r[g * 3 + 0], pr1 = p_r[g * 3 + 1], pr2 = p_r[g * 3 + 2];
  const float qn0 = fmaxf(fmaf(pr2, cst[S_QW + 6], fmaf(pr1, cst[S_QW + 3], fmaf(pr0, cst[S_QW + 0], cst[S_QB + 0]))), 0.f);
  const float qn1 = fmaxf(fmaf(pr2, cst[S_QW + 7], fmaf(pr1, cst[S_QW + 4], fmaf(pr0, cst[S_QW + 1], cst[S_QB + 1]))), 0.f);
  const float qn2 = fmaxf(fmaf(pr2, cst[S_QW + 8], fmaf(pr1, cst[S_QW + 5], fmaf(pr0, cst[S_QW + 2], cst[S_QB + 2]))), 0.f);
  float4 wka = *(const float4*)(wsoft + g * 8);
  float4 wkb = *(const float4*)(wsoft + g * 8 + 4);
  float wk[8] = {wka.x, wka.y, wka.z, wka.w, wkb.x, wkb.y, wkb.z, wkb.w};
  float sacc[8], vacc[8];
  #pragma unroll
  for (int t = 0; t < 8; ++t) { sacc[t] = ibsh[t]; vacc[t] = ixbsh[t]; }
  const float* zr = z + (size_t)j * 64;
  for (int c = 0; c < 64; c += 4) {
    float4 zv = *(const float4*)(zr + c);
    float4 l0 = *(const float4*)(lpw2sh + c);
    float4 l1 = *(const float4*)(lpw2sh + 64 + c);
    float4 l2 = *(const float4*)(lpw2sh + 128 + c);
    float4 lb = *(const float4*)(lpb2sh + c);
    float xkv[4];
    xkv[0] = (zv.x + fmaf(qn2, l2.x, fmaf(qn1, l1.x, fmaf(qn0, l0.x, lb.x)))) * wk[(c + 0) & 7];
    xkv[1] = (zv.y + fmaf(qn2, l2.y, fmaf(qn1, l1.y, fmaf(qn0, l0.y, lb.y)))) * wk[(c + 1) & 7];
    xkv[2] = (zv.z + fmaf(qn2, l2.z, fmaf(qn1, l1.z, fmaf(qn0, l0.z, lb.z)))) * wk[(c + 2) & 7];
    xkv[3] = (zv.w + fmaf(qn2, l2.w, fmaf(qn1, l1.w, fmaf(qn0, l0.w, lb.w)))) * wk[(c + 3) & 7];
    xksh[tid][c + 0] = xkv[0];
    xksh[tid][c + 1] = xkv[1];
    xksh[tid][c + 2] = xkv[2];
    xksh[tid][c + 3] = xkv[3];
    #pragma unroll
    for (int d = 0; d < 4; ++d) {
      const float xk = xkv[d];
      const float* iwc = iwsh + (c + d) * 8;
      const float* ixwc = ixwsh + (c + d) * 8;
      float4 a0 = *(const float4*)(iwc);
      float4 a1 = *(const float4*)(iwc + 4);
      float4 b0 = *(const float4*)(ixwc);
      float4 b1 = *(const float4*)(ixwc + 4);
      sacc[0] = fmaf(xk, a0.x, sacc[0]); sacc[1] = fmaf(xk, a0.y, sacc[1]); sacc[2] = fmaf(xk, a0.z, sacc[2]); sacc[3] = fmaf(xk, a0.w, sacc[3]);
      sacc[4] = fmaf(xk, a1.x, sacc[4]); sacc[5] = fmaf(xk, a1.y, sacc[5]); sacc[6] = fmaf(xk, a1.z, sacc[6]); sacc[7] = fmaf(xk, a1.w, sacc[7]);
      vacc[0] = fmaf(xk, b0.x, vacc[0]); vacc[1] = fmaf(xk, b0.y, vacc[1]); vacc[2] = fmaf(xk, b0.z, vacc[2]); vacc[3] = fmaf(xk, b0.w, vacc[3]);
      vacc[4] = fmaf(xk, b1.x, vacc[4]); vacc[5] = fmaf(xk, b1.y, vacc[5]); vacc[6] = fmaf(xk, b1.z, vacc[6]); vacc[7] = fmaf(xk, b1.w, vacc[7]);
    }
  }
  // fused scatter-softmax accumulation: ex = exp(s) (shift-free; |s| small),
  // XCD-local L2 atomics into this XCD's copy
  {
    float* base = segc + (size_t)j * 16;
    #pragma unroll
    for (int t = 0; t < 8; ++t) {
      float ex = __expf(sacc[t]);
      __hip_atomic_fetch_add(base + t, ex, __ATOMIC_RELAXED, __HIP_MEMORY_SCOPE_WORKGROUP);
      __hip_atomic_fetch_add(base + 8 + t, ex * vacc[t], __ATOMIC_RELAXED, __HIP_MEMORY_SCOPE_WORKGROUP);
    }
  }
  __syncthreads();
  const int nl = tid >> 4;
  const int cb = (tid & 15) * 4;
  float o0 = 0.f, o1 = 0.f, o2 = 0.f, o3 = 0.f;
  #pragma unroll
  for (int k = 0; k < 16; ++k) {
    const float* xr = &xksh[nl * 16 + k][cb];
    o0 += xr[0]; o1 += xr[1]; o2 += xr[2]; o3 += xr[3];
  }
  const size_t nrow = (size_t)blockIdx.x * 8 + nl;
  *(float4*)(x_intra + nrow * 64 + cb) = make_float4(o0, o1, o2, o3);
}

// ---------------- K6: combine 8 XCD copies -> resid ----------------
__global__ __launch_bounds__(256) void k_seg_final(
    const float* __restrict__ seg8, float* __restrict__ resid, long long nseg)
{
  const size_t g = (size_t)blockIdx.x * 256 + threadIdx.x;  // over n*8
  const size_t j = g >> 3;
  const int t = (int)(g & 7);
  float s = 0.f, r = 0.f;
  #pragma unroll
  for (int c = 0; c < 8; ++c) {
    const float* base = seg8 + (size_t)c * nseg + j * 16;
    s += base[t];
    r += base[8 + t];
  }
  resid[g] = (s > 0.f) ? (r / s) : 0.f;
}

// ---------------- K8: x2 = x_intra + tile(resid), bn2 partials ----------------
__global__ __launch_bounds__(256) void k_x2_stats(
    float* __restrict__ xi, const float* __restrict__ resid,
    float* __restrict__ partial, int n)
{
  __shared__ float bsum[64], bsq[64];
  const int tid = threadIdx.x;
  const int lane = tid & 63;
  const int wave = tid >> 6;
  if (tid < 64) { bsum[tid] = 0.f; bsq[tid] = 0.f; }
  __syncthreads();
  float ls = 0.f, lq = 0.f;
  const int row0 = (blockIdx.x * 4 + wave) * 16;
  for (int r = 0; r < 16; ++r) {
    const int row = row0 + r;
    float v = xi[(size_t)row * 64 + lane] + resid[(size_t)row * 8 + (lane & 7)];
    xi[(size_t)row * 64 + lane] = v;
    ls += v;
    lq = fmaf(v, v, lq);
  }
  atomicAdd(&bsum[lane], ls);
  atomicAdd(&bsq[lane], lq);
  __syncthreads();
  if (tid < 64) {
    partial[(size_t)tid * gridDim.x + blockIdx.x] = bsum[tid];
    partial[(size_t)(tid + 64) * gridDim.x + blockIdx.x] = bsq[tid];
  }
}

// ---------------- K10: final bn3 + residual + relu ----------------
__global__ __launch_bounds__(256) void k_out(
    const float* __restrict__ y3, const float* __restrict__ x0,
    const float* __restrict__ cst, float* __restrict__ out)
{
  __shared__ float scsh[64], shsh[64];
  const int tid = threadIdx.x;
  if (tid < 64) { scsh[tid] = cst[S_SC3 + tid]; shsh[tid] = cst[S_SH3 + tid]; }
  __syncthreads();
  const size_t i = ((size_t)blockIdx.x * 256 + tid) * 4;
  float4 y = *(const float4*)(y3 + i);
  float4 x = *(const float4*)(x0 + i);
  const int c = (int)(i & 63);
  float4 o;
  o.x = fmaxf(fmaf(y.x, scsh[c + 0], shsh[c + 0]) + x.x, 0.f);
  o.y = fmaxf(fmaf(y.y, scsh[c + 1], shsh[c + 1]) + x.y, 0.f);
  o.z = fmaxf(fmaf(y.z, scsh[c + 2], shsh[c + 2]) + x.z, 0.f);
  o.w = fmaxf(fmaf(y.w, scsh[c + 3], shsh[c + 3]) + x.w, 0.f);
  *(float4*)(out + i) = o;
}

// ---------------- launch ----------------
extern "C" void kernel_launch(void* const* d_in, const int* in_sizes, int n_in,
                              void* d_out, int out_size, void* d_ws, size_t ws_size,
                              hipStream_t stream)
{
  (void)n_in; (void)out_size; (void)ws_size;
  const float* p    = (const float*)d_in[0];
  const float* x    = (const float*)d_in[1];
  const int*   knn  = (const int*)d_in[2];
  const float* w1   = (const float*)d_in[3];
  const float* g1   = (const float*)d_in[4];
  const float* b1   = (const float*)d_in[5];
  const float* m1w1 = (const float*)d_in[6];
  const float* m1b1 = (const float*)d_in[7];
  const float* m1w2 = (const float*)d_in[8];
  const float* m1b2 = (const float*)d_in[9];
  const float* lpw1 = (const float*)d_in[10];
  const float* lpb1 = (const float*)d_in[11];
  const float* lpg  = (const float*)d_in[12];
  const float* lpbt = (const float*)d_in[13];
  const float* lpw2 = (const float*)d_in[14];
  const float* lpb2 = (const float*)d_in[15];
  const float* m2w1 = (const float*)d_in[16];
  const float* m2g1 = (const float*)d_in[17];
  const float* m2bt1= (const float*)d_in[18];
  const float* m2w2 = (const float*)d_in[19];
  const float* m2g2 = (const float*)d_in[20];
  const float* m2bt2= (const float*)d_in[21];
  const float* m2w3 = (const float*)d_in[22];
  const float* m2b3 = (const float*)d_in[23];
  const float* m3w  = (const float*)d_in[24];
  const float* m3b  = (const float*)d_in[25];
  const float* iw   = (const float*)d_in[26];
  const float* ib   = (const float*)d_in[27];
  const float* ixw  = (const float*)d_in[28];
  const float* ixb  = (const float*)d_in[29];
  const float* g2   = (const float*)d_in[30];
  const float* b2   = (const float*)d_in[31];
  const float* w3   = (const float*)d_in[32];
  const float* g3   = (const float*)d_in[33];
  const float* b3   = (const float*)d_in[34];
  float* out = (float*)d_out;
  float* ws  = (float*)d_ws;

  const int n = in_sizes[1] / 64;                // 32768
  const long long nk = (long long)n * 16;        // 524288
  const long long nseg = 16LL * n;               // accumulator floats per XCD copy

  float* cst  = ws;
  float* seg8 = ws + CONST_FLOATS;              // 8 * nseg = 128n floats (16 MB)
  float* resid = seg8 + 8LL * nseg;             // n*8
  float* y1 = resid + 8LL * n;                  // N*64, reused as y3
  float* z  = y1 + 64LL * n;                    // N*64
  float* xi = z + 64LL * n;                     // N*64 (x_intra -> x2)
  float* pr = xi + 64LL * n;                    // N*K*3
  float* en = pr + 48LL * n;                    // N*K*16
  float* h2 = en + 256LL * n;                   // N*K*8
  float* wsm = h2 + 128LL * n;                  // N*K*8

  const int gB   = n / 64;            // 512
  const int nkB  = (int)(nk / 256);   // 2048
  const int nkB2 = (int)(nk / 512);   // 1024
  const int nkBi = (int)(nk / 128);   // 4096

  // partial-sum scratch (channel-major)
  float* pbn1  = wsm + 128LL * n;                // 128 * gB
  float* plp   = pbn1 + 128LL * gB;              // 8 * nkB
  float* pm2b1 = plp + 8LL * nkB;                // 128 * nkB
  float* pm2b2 = pm2b1 + 128LL * nkB;            // 16 * nkB2
  float* pbn2  = pm2b2 + 16LL * nkB2;            // 128 * gB
  float* pbn3  = pbn2 + 128LL * gB;              // 128 * gB

  // zero const area + seg8 copies
  hipMemsetAsync(d_ws, 0, (size_t)(CONST_FLOATS + 8LL * nseg) * sizeof(float), stream);

  // 1) y1 = x @ w1, bn1 partials
  k_gemm64<<<gB, 256, 0, stream>>>(x, w1, nullptr, nullptr, nullptr, y1, pbn1, n);
  k_reduce<<<128, 256, 0, stream>>>(pbn1, cst + S_BN1_SUM, gB);
  k_finalize_bn<<<1, 64, 0, stream>>>(cst + S_BN1_SUM, cst + S_BN1_SQ, g1, b1,
                                      cst + S_SC1, cst + S_SH1, 1.f / (float)n, 64);
  // 2) z = relu(bn1(y1)) @ m3w + m3b
  k_gemm64<<<gB, 256, 0, stream>>>(y1, m3w, m3b, cst + S_SC1, cst + S_SH1, z, nullptr, n);
  // 3) p_r, energy, lp partials
  k_energy<<<nkB, 256, 0, stream>>>(p, y1, knn, m1w1, m1b1, m1w2, m1b2, lpw1, lpb1,
                                    cst + S_SC1, cst + S_SH1, pr, en, plp);
  k_reduce<<<8, 256, 0, stream>>>(plp, cst + S_LP_SUM, nkB);
  k_f2_lp<<<1, 64, 0, stream>>>(lpg, lpbt, lpw1, lpb1, lpw2, lpb2, cst, 1.f / (float)nk);
  // 4) h1 stats
  k_m2b1_stats<<<nkB, 256, 0, stream>>>(en, pr, cst, m2w1, pm2b1);
  k_reduce<<<128, 256, 0, stream>>>(pm2b1, cst + S_M2B1_SUM, nkB);
  k_finalize_bn<<<1, 64, 0, stream>>>(cst + S_M2B1_SUM, cst + S_M2B1_SQ, m2g1, m2bt1,
                                      cst + S_M2S1, cst + S_M2H1, 1.f / (float)nk, 64);
  // 5) h2 + stats
  k_h2<<<nkB2, 256, 0, stream>>>(en, pr, cst, m2w1, m2w2, h2, pm2b2);
  k_reduce<<<16, 256, 0, stream>>>(pm2b2, cst + S_M2B2_SUM, nkB2);
  k_finalize_bn<<<1, 64, 0, stream>>>(cst + S_M2B2_SUM, cst + S_M2B2_SQ, m2g2, m2bt2,
                                      cst + S_M2S2, cst + S_M2H2, 1.f / (float)nk, 8);
  // 6) softmax weights
  k_softmax<<<nkB, 256, 0, stream>>>(h2, cst, m2w3, m2b3, wsm);
  // 7) xk, x_intra, fused exp+segment-sums (XCD-local L2 atomics)
  k_intra<<<nkBi, 128, 0, stream>>>(z, pr, knn, cst, lpw2, lpb2, iw, ib, ixw, ixb, wsm,
                                    xi, seg8, nseg);
  // 8) combine copies -> resid
  k_seg_final<<<(int)(8LL * n / 256), 256, 0, stream>>>(seg8, resid, nseg);
  // 9) x2 = x_intra + tile(resid), bn2 partials
  k_x2_stats<<<gB, 256, 0, stream>>>(xi, resid, pbn2, n);
  k_reduce<<<128, 256, 0, stream>>>(pbn2, cst + S_BN2_SUM, gB);
  k_finalize_bn<<<1, 64, 0, stream>>>(cst + S_BN2_SUM, cst + S_BN2_SQ, g2, b2,
                                      cst + S_SC2, cst + S_SH2, 1.f / (float)n, 64);
  // 10) y3 = relu(bn2(x2)) @ w3, bn3 partials
  k_gemm64<<<gB, 256, 0, stream>>>(xi, w3, nullptr, cst + S_SC2, cst + S_SH2, y1, pbn3, n);
  k_reduce<<<128, 256, 0, stream>>>(pbn3, cst + S_BN3_SUM, gB);
  k_finalize_bn<<<1, 64, 0, stream>>>(cst + S_BN3_SUM, cst + S_BN3_SQ, g3, b3,
                                      cst + S_SC3, cst + S_SH3, 1.f / (float)n, 64);
  // 11) out = relu(bn3(y3) + x)
  k_out<<<(int)((long long)n * 64 / 1024), 256, 0, stream>>>(y1, x, cst, out);
}

// Round 4
// 509.895 us; speedup vs baseline: 3.1459x; 1.5033x over previous
//
#include <hip/hip_runtime.h>

// N = 32768 (runtime), C = 64, K = 16, CS = 8, SHARE = 8

enum {
  S_BN1_SUM = 0,    S_BN1_SQ = 64,
  S_LP_SUM = 128,   S_LP_SQ = 132,
  S_M2B1_SUM = 136, S_M2B1_SQ = 200,
  S_M2B2_SUM = 264, S_M2B2_SQ = 272,
  S_BN2_SUM = 280,  S_BN2_SQ = 344,
  S_BN3_SUM = 408,  S_BN3_SQ = 472,
  S_SC1 = 536,  S_SH1 = 600,
  S_LPSC = 664, S_LPSH = 668,
  S_M2S1 = 672, S_M2H1 = 736,
  S_M2S2 = 800, S_M2H2 = 808,
  S_SC2 = 816,  S_SH2 = 880,
  S_SC3 = 944,  S_SH3 = 1008,
  S_LPW2S = 1072, S_LPB2S = 1120,
  S_QW = 1136, S_QB = 1148,
  CONST_FLOATS = 1280
};

// ---------------- partial-sum reduce: one block per channel ----------------
__global__ __launch_bounds__(256) void k_reduce(
    const float* __restrict__ partial, float* __restrict__ outbuf, int nblocks)
{
  const int tid = threadIdx.x;
  const float* src = partial + (size_t)blockIdx.x * nblocks;
  float s = 0.f;
  for (int t = tid; t < nblocks; t += 256) s += src[t];
  #pragma unroll
  for (int m = 1; m < 64; m <<= 1) s += __shfl_xor(s, m);
  __shared__ float wsum[4];
  if ((tid & 63) == 0) wsum[tid >> 6] = s;
  __syncthreads();
  if (tid == 0) outbuf[blockIdx.x] = wsum[0] + wsum[1] + wsum[2] + wsum[3];
}

// ---------------- generic 64x64 GEMM ----------------
__global__ __launch_bounds__(256) void k_gemm64(
    const float* __restrict__ in, const float* __restrict__ w,
    const float* __restrict__ bias,
    const float* __restrict__ sc, const float* __restrict__ sh,
    float* __restrict__ out,
    float* __restrict__ partial,   // [128 * gridDim.x] channel-major, or null
    int n)
{
  __shared__ float scsh[64], shsh[64];
  __shared__ float bsum[64], bsq[64];
  const int tid = threadIdx.x;
  const int lane = tid & 63;
  const int wave = tid >> 6;
  if (sc != nullptr && tid < 64) { scsh[tid] = sc[tid]; shsh[tid] = sh[tid]; }
  if (tid < 64) { bsum[tid] = 0.f; bsq[tid] = 0.f; }
  __syncthreads();

  float wreg[64];
  #pragma unroll
  for (int k = 0; k < 64; ++k) wreg[k] = w[k * 64 + lane];
  const float bz = bias ? bias[lane] : 0.f;

  float lsum = 0.f, lsq = 0.f;
  const int row0 = (blockIdx.x * 4 + wave) * 16;
  for (int r = 0; r < 16; ++r) {
    const int row = row0 + r;
    const float* xr = in + (size_t)row * 64;
    float acc = bz;
    if (sc != nullptr) {
      #pragma unroll
      for (int k = 0; k < 64; k += 4) {
        float4 xv = *(const float4*)(xr + k);
        float x0 = fmaxf(fmaf(xv.x, scsh[k + 0], shsh[k + 0]), 0.f);
        float x1 = fmaxf(fmaf(xv.y, scsh[k + 1], shsh[k + 1]), 0.f);
        float x2 = fmaxf(fmaf(xv.z, scsh[k + 2], shsh[k + 2]), 0.f);
        float x3 = fmaxf(fmaf(xv.w, scsh[k + 3], shsh[k + 3]), 0.f);
        acc = fmaf(x0, wreg[k + 0], acc);
        acc = fmaf(x1, wreg[k + 1], acc);
        acc = fmaf(x2, wreg[k + 2], acc);
        acc = fmaf(x3, wreg[k + 3], acc);
      }
    } else {
      #pragma unroll
      for (int k = 0; k < 64; k += 4) {
        float4 xv = *(const float4*)(xr + k);
        acc = fmaf(xv.x, wreg[k + 0], acc);
        acc = fmaf(xv.y, wreg[k + 1], acc);
        acc = fmaf(xv.z, wreg[k + 2], acc);
        acc = fmaf(xv.w, wreg[k + 3], acc);
      }
    }
    out[(size_t)row * 64 + lane] = acc;
    lsum += acc;
    lsq = fmaf(acc, acc, lsq);
  }
  if (partial != nullptr) {
    atomicAdd(&bsum[lane], lsum);
    atomicAdd(&bsq[lane], lsq);
    __syncthreads();
    if (tid < 64) {
      partial[(size_t)tid * gridDim.x + blockIdx.x] = bsum[tid];
      partial[(size_t)(tid + 64) * gridDim.x + blockIdx.x] = bsq[tid];
    }
  }
}

// ---------------- BN finalize ----------------
__global__ void k_finalize_bn(const float* __restrict__ ssum, const float* __restrict__ ssq,
                              const float* __restrict__ g, const float* __restrict__ b,
                              float* __restrict__ scale, float* __restrict__ shift,
                              float inv_count, int nch)
{
  int i = threadIdx.x;
  if (i < nch) {
    float m = ssum[i] * inv_count;
    float v = ssq[i] * inv_count - m * m;
    float rs = rsqrtf(v + 1e-5f);
    float s = g[i] * rs;
    scale[i] = s;
    shift[i] = fmaf(-m, s, b[i]);
  }
}

// ---------------- lp finalize + weight folding ----------------
__global__ void k_f2_lp(const float* __restrict__ lpg, const float* __restrict__ lpbt,
                        const float* __restrict__ lpw1, const float* __restrict__ lpb1,
                        const float* __restrict__ lpw2, const float* __restrict__ lpb2,
                        float* __restrict__ cst, float inv_count)
{
  int t = threadIdx.x;
  if (t < 3) {
    float m = cst[S_LP_SUM + t] * inv_count;
    float v = cst[S_LP_SQ + t] * inv_count - m * m;
    float rs = rsqrtf(v + 1e-5f);
    float s = lpg[t] * rs;
    cst[S_LPSC + t] = s;
    cst[S_LPSH + t] = fmaf(-m, s, lpbt[t]);
  }
  __syncthreads();
  if (t < 9)  cst[S_QW + t] = lpw1[t] * cst[S_LPSC + (t % 3)];
  if (t < 3)  cst[S_QB + t] = fmaf(lpb1[t], cst[S_LPSC + t], cst[S_LPSH + t]);
  if (t < 16) {
    float b = 0.f;
    for (int c2 = 0; c2 < 4; ++c2) b += lpb2[c2 * 16 + t];
    cst[S_LPB2S + t] = b;
    for (int r = 0; r < 3; ++r) {
      float w = 0.f;
      for (int c2 = 0; c2 < 4; ++c2) w += lpw2[r * 64 + c2 * 16 + t];
      cst[S_LPW2S + r * 16 + t] = w;
    }
  }
}

// ---------------- CSR build: histogram ----------------
__global__ __launch_bounds__(256) void k_hist(
    const int* __restrict__ knn, int* __restrict__ cnt)
{
  const size_t g = (size_t)blockIdx.x * 256 + threadIdx.x;
  atomicAdd(&cnt[knn[g]], 1);
}

// ---------------- CSR build: scan (one block, 1024 threads, n%1024==0) ----------------
__global__ __launch_bounds__(1024) void k_scan(
    const int* __restrict__ cnt, int* __restrict__ rowstart,
    int* __restrict__ cursor, int n)
{
  __shared__ int tsum[1024];
  const int tid = threadIdx.x;
  const int per = n >> 10;          // 32
  const int base = tid * per;
  int local[32];
  int s = 0;
  for (int u = 0; u < per; ++u) { local[u] = cnt[base + u]; s += local[u]; }
  tsum[tid] = s;
  __syncthreads();
  for (int off = 1; off < 1024; off <<= 1) {
    int v = (tid >= off) ? tsum[tid - off] : 0;
    __syncthreads();
    tsum[tid] += v;
    __syncthreads();
  }
  int run = tsum[tid] - s;          // exclusive offset
  for (int u = 0; u < per; ++u) {
    rowstart[base + u] = run;
    cursor[base + u] = run;
    run += local[u];
  }
  if (tid == 1023) rowstart[n] = run;
}

// ---------------- CSR build: fill buckets ----------------
__global__ __launch_bounds__(256) void k_fill(
    const int* __restrict__ knn, int* __restrict__ cursor, int* __restrict__ bucket)
{
  const size_t g = (size_t)blockIdx.x * 256 + threadIdx.x;
  const int j = knn[g];
  const int pos = atomicAdd(&cursor[j], 1);
  bucket[pos] = (int)g;
}

// ---------------- K2: p_r, energy, lp partials ----------------
__global__ __launch_bounds__(256) void k_energy(
    const float* __restrict__ p, const float* __restrict__ y1,
    const int* __restrict__ knn,
    const float* __restrict__ m1w1, const float* __restrict__ m1b1,
    const float* __restrict__ m1w2, const float* __restrict__ m1b2,
    const float* __restrict__ lpw1, const float* __restrict__ lpb1,
    const float* __restrict__ sc1, const float* __restrict__ sh1,
    float* __restrict__ p_r, float* __restrict__ energy,
    float* __restrict__ plp)    // [8 * gridDim.x] channel-major
{
  __shared__ float w1sh[67 * 16];
  __shared__ float w2sh[256];
  __shared__ float b1sh[16], b2sh[16];
  __shared__ float scsh[64], shsh[64];
  __shared__ float lpw1sh[9], lpb1sh[3];
  __shared__ float lpsh[4][8];
  const int tid = threadIdx.x;
  for (int i = tid; i < 67 * 16; i += 256) w1sh[i] = m1w1[i];
  w2sh[tid] = m1w2[tid];
  if (tid < 16) { b1sh[tid] = m1b1[tid]; b2sh[tid] = m1b2[tid]; }
  if (tid < 64) { scsh[tid] = sc1[tid]; shsh[tid] = sh1[tid]; }
  if (tid < 9) lpw1sh[tid] = lpw1[tid];
  if (tid < 3) lpb1sh[tid] = lpb1[tid];
  __syncthreads();

  const size_t g = (size_t)blockIdx.x * 256 + tid;
  const int i = (int)(g >> 4);
  const int j = knn[g];
  const float pr0 = p[j * 3 + 0] - p[i * 3 + 0];
  const float pr1 = p[j * 3 + 1] - p[i * 3 + 1];
  const float pr2 = p[j * 3 + 2] - p[i * 3 + 2];
  p_r[g * 3 + 0] = pr0; p_r[g * 3 + 1] = pr1; p_r[g * 3 + 2] = pr2;

  float acc1[16];
  #pragma unroll
  for (int t4 = 0; t4 < 16; t4 += 4) {
    float4 w0 = *(const float4*)(w1sh + 0 * 16 + t4);
    float4 w1v = *(const float4*)(w1sh + 1 * 16 + t4);
    float4 w2v = *(const float4*)(w1sh + 2 * 16 + t4);
    float4 bb = *(const float4*)(b1sh + t4);
    acc1[t4 + 0] = fmaf(pr2, w2v.x, fmaf(pr1, w1v.x, fmaf(pr0, w0.x, bb.x)));
    acc1[t4 + 1] = fmaf(pr2, w2v.y, fmaf(pr1, w1v.y, fmaf(pr0, w0.y, bb.y)));
    acc1[t4 + 2] = fmaf(pr2, w2v.z, fmaf(pr1, w1v.z, fmaf(pr0, w0.z, bb.z)));
    acc1[t4 + 3] = fmaf(pr2, w2v.w, fmaf(pr1, w1v.w, fmaf(pr0, w0.w, bb.w)));
  }
  const float* yr = y1 + (size_t)j * 64;
  for (int c = 0; c < 64; c += 4) {
    float4 yv = *(const float4*)(yr + c);
    float xx0 = fmaxf(fmaf(yv.x, scsh[c + 0], shsh[c + 0]), 0.f);
    float xx1 = fmaxf(fmaf(yv.y, scsh[c + 1], shsh[c + 1]), 0.f);
    float xx2 = fmaxf(fmaf(yv.z, scsh[c + 2], shsh[c + 2]), 0.f);
    float xx3 = fmaxf(fmaf(yv.w, scsh[c + 3], shsh[c + 3]), 0.f);
    float xx[4] = {xx0, xx1, xx2, xx3};
    #pragma unroll
    for (int d = 0; d < 4; ++d) {
      const float* wrow = w1sh + (3 + c + d) * 16;
      const float x = xx[d];
      #pragma unroll
      for (int t4 = 0; t4 < 16; t4 += 4) {
        float4 wv = *(const float4*)(wrow + t4);
        acc1[t4 + 0] = fmaf(x, wv.x, acc1[t4 + 0]);
        acc1[t4 + 1] = fmaf(x, wv.y, acc1[t4 + 1]);
        acc1[t4 + 2] = fmaf(x, wv.z, acc1[t4 + 2]);
        acc1[t4 + 3] = fmaf(x, wv.w, acc1[t4 + 3]);
      }
    }
  }
  float acc2[16];
  #pragma unroll
  for (int t4 = 0; t4 < 16; t4 += 4) {
    float4 bb = *(const float4*)(b2sh + t4);
    acc2[t4 + 0] = bb.x; acc2[t4 + 1] = bb.y; acc2[t4 + 2] = bb.z; acc2[t4 + 3] = bb.w;
  }
  #pragma unroll
  for (int t = 0; t < 16; ++t) {
    float a = fmaxf(acc1[t], 0.f);
    const float* wrow = w2sh + t * 16;
    #pragma unroll
    for (int t4 = 0; t4 < 16; t4 += 4) {
      float4 wv = *(const float4*)(wrow + t4);
      acc2[t4 + 0] = fmaf(a, wv.x, acc2[t4 + 0]);
      acc2[t4 + 1] = fmaf(a, wv.y, acc2[t4 + 1]);
      acc2[t4 + 2] = fmaf(a, wv.z, acc2[t4 + 2]);
      acc2[t4 + 3] = fmaf(a, wv.w, acc2[t4 + 3]);
    }
  }
  #pragma unroll
  for (int t = 0; t < 16; t += 4)
    *(float4*)(energy + g * 16 + t) = make_float4(acc2[t], acc2[t + 1], acc2[t + 2], acc2[t + 3]);

  // lp stats partials
  float q0 = fmaf(pr2, lpw1sh[6], fmaf(pr1, lpw1sh[3], fmaf(pr0, lpw1sh[0], lpb1sh[0])));
  float q1 = fmaf(pr2, lpw1sh[7], fmaf(pr1, lpw1sh[4], fmaf(pr0, lpw1sh[1], lpb1sh[1])));
  float q2 = fmaf(pr2, lpw1sh[8], fmaf(pr1, lpw1sh[5], fmaf(pr0, lpw1sh[2], lpb1sh[2])));
  float s0 = q0, s1 = q1, s2 = q2, qq0 = q0 * q0, qq1 = q1 * q1, qq2 = q2 * q2;
  #pragma unroll
  for (int m = 1; m < 64; m <<= 1) {
    s0 += __shfl_xor(s0, m); s1 += __shfl_xor(s1, m); s2 += __shfl_xor(s2, m);
    qq0 += __shfl_xor(qq0, m); qq1 += __shfl_xor(qq1, m); qq2 += __shfl_xor(qq2, m);
  }
  if ((tid & 63) == 0) {
    const int w = tid >> 6;
    lpsh[w][0] = s0; lpsh[w][1] = s1; lpsh[w][2] = s2; lpsh[w][3] = 0.f;
    lpsh[w][4] = qq0; lpsh[w][5] = qq1; lpsh[w][6] = qq2; lpsh[w][7] = 0.f;
  }
  __syncthreads();
  if (tid < 8) {
    float v = lpsh[0][tid] + lpsh[1][tid] + lpsh[2][tid] + lpsh[3][tid];
    plp[(size_t)tid * gridDim.x + blockIdx.x] = v;
  }
}

// ---------------- e-vector recompute helper ----------------
__device__ __forceinline__ void load_e(const float* __restrict__ energy,
                                       const float* __restrict__ p_r,
                                       const float* __restrict__ cst,
                                       size_t g, float* e)
{
  float4 t0 = *(const float4*)(energy + g * 16);
  float4 t1 = *(const float4*)(energy + g * 16 + 4);
  float4 t2 = *(const float4*)(energy + g * 16 + 8);
  float4 t3 = *(const float4*)(energy + g * 16 + 12);
  e[0] = t0.x; e[1] = t0.y; e[2] = t0.z; e[3] = t0.w;
  e[4] = t1.x; e[5] = t1.y; e[6] = t1.z; e[7] = t1.w;
  e[8] = t2.x; e[9] = t2.y; e[10] = t2.z; e[11] = t2.w;
  e[12] = t3.x; e[13] = t3.y; e[14] = t3.z; e[15] = t3.w;
  float pr0 = p_r[g * 3 + 0], pr1 = p_r[g * 3 + 1], pr2 = p_r[g * 3 + 2];
  float qn0 = fmaxf(fmaf(pr2, cst[S_QW + 6], fmaf(pr1, cst[S_QW + 3], fmaf(pr0, cst[S_QW + 0], cst[S_QB + 0]))), 0.f);
  float qn1 = fmaxf(fmaf(pr2, cst[S_QW + 7], fmaf(pr1, cst[S_QW + 4], fmaf(pr0, cst[S_QW + 1], cst[S_QB + 1]))), 0.f);
  float qn2 = fmaxf(fmaf(pr2, cst[S_QW + 8], fmaf(pr1, cst[S_QW + 5], fmaf(pr0, cst[S_QW + 2], cst[S_QB + 2]))), 0.f);
  #pragma unroll
  for (int t = 0; t < 16; ++t)
    e[16 + t] = fmaf(qn2, cst[S_LPW2S + 32 + t],
                fmaf(qn1, cst[S_LPW2S + 16 + t],
                fmaf(qn0, cst[S_LPW2S + t], cst[S_LPB2S + t])));
}

// ---------------- K3: stats of h1 = e @ m2w1 ----------------
__global__ __launch_bounds__(256) void k_m2b1_stats(
    const float* __restrict__ energy, const float* __restrict__ p_r,
    const float* __restrict__ cst, const float* __restrict__ m2w1,
    float* __restrict__ partial)   // [128 * gridDim.x]
{
  __shared__ float esh[32 * 260];
  __shared__ float lsum[64], lsq[64];
  const int tid = threadIdx.x;
  const int lane = tid & 63;
  const int wave = tid >> 6;
  if (tid < 64) { lsum[tid] = 0.f; lsq[tid] = 0.f; }
  float wreg[32];
  #pragma unroll
  for (int k = 0; k < 32; ++k) wreg[k] = m2w1[k * 64 + lane];

  const size_t g = (size_t)blockIdx.x * 256 + tid;
  float e[32];
  load_e(energy, p_r, cst, g, e);
  #pragma unroll
  for (int k = 0; k < 32; ++k) esh[k * 260 + tid] = e[k];
  __syncthreads();

  float ls = 0.f, lq = 0.f;
  for (int g4 = wave * 64; g4 < wave * 64 + 64; g4 += 4) {
    float h0 = 0.f, h1 = 0.f, h2 = 0.f, h3 = 0.f;
    #pragma unroll
    for (int k = 0; k < 32; ++k) {
      float4 ev = *(const float4*)(esh + k * 260 + g4);
      h0 = fmaf(ev.x, wreg[k], h0);
      h1 = fmaf(ev.y, wreg[k], h1);
      h2 = fmaf(ev.z, wreg[k], h2);
      h3 = fmaf(ev.w, wreg[k], h3);
    }
    ls += h0 + h1 + h2 + h3;
    lq += h0 * h0 + h1 * h1 + h2 * h2 + h3 * h3;
  }
  atomicAdd(&lsum[lane], ls);
  atomicAdd(&lsq[lane], lq);
  __syncthreads();
  if (tid < 64) {
    partial[(size_t)tid * gridDim.x + blockIdx.x] = lsum[tid];
    partial[(size_t)(tid + 64) * gridDim.x + blockIdx.x] = lsq[tid];
  }
}

// ---------------- K4: h2 = relu(bn(h1)) @ m2w2, + partials ----------------
__global__ __launch_bounds__(256) void k_h2(
    const float* __restrict__ energy, const float* __restrict__ p_r,
    const float* __restrict__ cst, const float* __restrict__ m2w1, const float* __restrict__ m2w2,
    float* __restrict__ h2out,
    float* __restrict__ partial)   // [16 * gridDim.x]
{
  __shared__ float wT[64 * 36];
  __shared__ float w2sh[512];
  __shared__ float scsh[64], shsh[64];
  __shared__ float redsh[4][16];
  const int tid = threadIdx.x;
  for (int idx = tid; idx < 2048; idx += 256) { int k = idx >> 6, c = idx & 63; wT[c * 36 + k] = m2w1[idx]; }
  for (int idx = tid; idx < 512; idx += 256) w2sh[idx] = m2w2[idx];
  if (tid < 64) { scsh[tid] = cst[S_M2S1 + tid]; shsh[tid] = cst[S_M2H1 + tid]; }
  __syncthreads();

  const size_t g0 = ((size_t)blockIdx.x * 256 + tid) * 2;
  float e0[32], e1[32];
  load_e(energy, p_r, cst, g0 + 0, e0);
  load_e(energy, p_r, cst, g0 + 1, e1);
  float a0[8], a1[8];
  #pragma unroll
  for (int t = 0; t < 8; ++t) { a0[t] = 0.f; a1[t] = 0.f; }
  for (int c = 0; c < 64; ++c) {
    const float* wc = wT + c * 36;
    float h0 = 0.f, h1 = 0.f;
    #pragma unroll
    for (int k = 0; k < 32; k += 4) {
      float4 wv = *(const float4*)(wc + k);
      h0 = fmaf(e0[k + 3], wv.w, fmaf(e0[k + 2], wv.z, fmaf(e0[k + 1], wv.y, fmaf(e0[k + 0], wv.x, h0))));
      h1 = fmaf(e1[k + 3], wv.w, fmaf(e1[k + 2], wv.z, fmaf(e1[k + 1], wv.y, fmaf(e1[k + 0], wv.x, h1))));
    }
    float x0 = fmaxf(fmaf(h0, scsh[c], shsh[c]), 0.f);
    float x1 = fmaxf(fmaf(h1, scsh[c], shsh[c]), 0.f);
    float4 wa = *(const float4*)(w2sh + c * 8);
    float4 wb = *(const float4*)(w2sh + c * 8 + 4);
    a0[0] = fmaf(x0, wa.x, a0[0]); a0[1] = fmaf(x0, wa.y, a0[1]); a0[2] = fmaf(x0, wa.z, a0[2]); a0[3] = fmaf(x0, wa.w, a0[3]);
    a0[4] = fmaf(x0, wb.x, a0[4]); a0[5] = fmaf(x0, wb.y, a0[5]); a0[6] = fmaf(x0, wb.z, a0[6]); a0[7] = fmaf(x0, wb.w, a0[7]);
    a1[0] = fmaf(x1, wa.x, a1[0]); a1[1] = fmaf(x1, wa.y, a1[1]); a1[2] = fmaf(x1, wa.z, a1[2]); a1[3] = fmaf(x1, wa.w, a1[3]);
    a1[4] = fmaf(x1, wb.x, a1[4]); a1[5] = fmaf(x1, wb.y, a1[5]); a1[6] = fmaf(x1, wb.z, a1[6]); a1[7] = fmaf(x1, wb.w, a1[7]);
  }
  *(float4*)(h2out + g0 * 8)      = make_float4(a0[0], a0[1], a0[2], a0[3]);
  *(float4*)(h2out + g0 * 8 + 4)  = make_float4(a0[4], a0[5], a0[6], a0[7]);
  *(float4*)(h2out + g0 * 8 + 8)  = make_float4(a1[0], a1[1], a1[2], a1[3]);
  *(float4*)(h2out + g0 * 8 + 12) = make_float4(a1[4], a1[5], a1[6], a1[7]);

  float st[8], sq[8];
  #pragma unroll
  for (int t = 0; t < 8; ++t) {
    st[t] = a0[t] + a1[t];
    sq[t] = fmaf(a0[t], a0[t], a1[t] * a1[t]);
  }
  #pragma unroll
  for (int m = 1; m < 64; m <<= 1) {
    #pragma unroll
    for (int t = 0; t < 8; ++t) { st[t] += __shfl_xor(st[t], m); sq[t] += __shfl_xor(sq[t], m); }
  }
  if ((tid & 63) == 0) {
    const int w = tid >> 6;
    #pragma unroll
    for (int t = 0; t < 8; ++t) { redsh[w][t] = st[t]; redsh[w][8 + t] = sq[t]; }
  }
  __syncthreads();
  if (tid < 16) {
    float v = redsh[0][tid] + redsh[1][tid] + redsh[2][tid] + redsh[3][tid];
    partial[(size_t)tid * gridDim.x + blockIdx.x] = v;
  }
}

// ---------------- K5a: softmax over k ----------------
__global__ __launch_bounds__(256) void k_softmax(
    const float* __restrict__ h2, const float* __restrict__ cst,
    const float* __restrict__ m2w3, const float* __restrict__ m2b3,
    float* __restrict__ wout)
{
  __shared__ float w3sh[64];
  __shared__ float b3sh[8], s2sh[8], h2sh[8];
  const int tid = threadIdx.x;
  if (tid < 64) w3sh[tid] = m2w3[tid];
  if (tid < 8) { b3sh[tid] = m2b3[tid]; s2sh[tid] = cst[S_M2S2 + tid]; h2sh[tid] = cst[S_M2H2 + tid]; }
  __syncthreads();
  const size_t g = (size_t)blockIdx.x * 256 + tid;
  float4 ha = *(const float4*)(h2 + g * 8);
  float4 hb = *(const float4*)(h2 + g * 8 + 4);
  float hn[8];
  hn[0] = fmaxf(fmaf(ha.x, s2sh[0], h2sh[0]), 0.f);
  hn[1] = fmaxf(fmaf(ha.y, s2sh[1], h2sh[1]), 0.f);
  hn[2] = fmaxf(fmaf(ha.z, s2sh[2], h2sh[2]), 0.f);
  hn[3] = fmaxf(fmaf(ha.w, s2sh[3], h2sh[3]), 0.f);
  hn[4] = fmaxf(fmaf(hb.x, s2sh[4], h2sh[4]), 0.f);
  hn[5] = fmaxf(fmaf(hb.y, s2sh[5], h2sh[5]), 0.f);
  hn[6] = fmaxf(fmaf(hb.z, s2sh[6], h2sh[6]), 0.f);
  hn[7] = fmaxf(fmaf(hb.w, s2sh[7], h2sh[7]), 0.f);
  float lg[8];
  #pragma unroll
  for (int t = 0; t < 8; ++t) {
    float a = b3sh[t];
    #pragma unroll
    for (int u = 0; u < 8; ++u) a = fmaf(hn[u], w3sh[u * 8 + t], a);
    lg[t] = a;
  }
  #pragma unroll
  for (int t = 0; t < 8; ++t) {
    float m = lg[t];
    m = fmaxf(m, __shfl_xor(m, 1));
    m = fmaxf(m, __shfl_xor(m, 2));
    m = fmaxf(m, __shfl_xor(m, 4));
    m = fmaxf(m, __shfl_xor(m, 8));
    float ex = __expf(lg[t] - m);
    float s = ex;
    s += __shfl_xor(s, 1);
    s += __shfl_xor(s, 2);
    s += __shfl_xor(s, 4);
    s += __shfl_xor(s, 8);
    lg[t] = ex / s;
  }
  *(float4*)(wout + g * 8)     = make_float4(lg[0], lg[1], lg[2], lg[3]);
  *(float4*)(wout + g * 8 + 4) = make_float4(lg[4], lg[5], lg[6], lg[7]);
}

// ---------------- K5b: xk, x_intra (shuffle-reduced), exv store ----------------
__global__ __launch_bounds__(128) void k_intra(
    const float* __restrict__ z, const float* __restrict__ p_r,
    const int* __restrict__ knn, const float* __restrict__ cst,
    const float* __restrict__ lpw2, const float* __restrict__ lpb2,
    const float* __restrict__ iw, const float* __restrict__ ib,
    const float* __restrict__ ixw, const float* __restrict__ ixb,
    const float* __restrict__ wsoft,
    float* __restrict__ x_intra, float* __restrict__ exv)
{
  __shared__ float lpw2sh[192], lpb2sh[64];
  __shared__ float iwsh[512], ixwsh[512];
  __shared__ float ibsh[8], ixbsh[8];
  const int tid = threadIdx.x;
  for (int idx = tid; idx < 192; idx += 128) lpw2sh[idx] = lpw2[idx];
  if (tid < 64) lpb2sh[tid] = lpb2[tid];
  for (int idx = tid; idx < 512; idx += 128) { iwsh[idx] = iw[idx]; ixwsh[idx] = ixw[idx]; }
  if (tid < 8) { ibsh[tid] = ib[tid]; ixbsh[tid] = ixb[tid]; }
  __syncthreads();

  const size_t g = (size_t)blockIdx.x * 128 + tid;
  const int j = knn[g];
  const int own = tid & 15;
  const float pr0 = p_r[g * 3 + 0], pr1 = p_r[g * 3 + 1], pr2 = p_r[g * 3 + 2];
  const float qn0 = fmaxf(fmaf(pr2, cst[S_QW + 6], fmaf(pr1, cst[S_QW + 3], fmaf(pr0, cst[S_QW + 0], cst[S_QB + 0]))), 0.f);
  const float qn1 = fmaxf(fmaf(pr2, cst[S_QW + 7], fmaf(pr1, cst[S_QW + 4], fmaf(pr0, cst[S_QW + 1], cst[S_QB + 1]))), 0.f);
  const float qn2 = fmaxf(fmaf(pr2, cst[S_QW + 8], fmaf(pr1, cst[S_QW + 5], fmaf(pr0, cst[S_QW + 2], cst[S_QB + 2]))), 0.f);
  float4 wka = *(const float4*)(wsoft + g * 8);
  float4 wkb = *(const float4*)(wsoft + g * 8 + 4);
  float wk[8] = {wka.x, wka.y, wka.z, wka.w, wkb.x, wkb.y, wkb.z, wkb.w};
  float sacc[8], vacc[8];
  #pragma unroll
  for (int t = 0; t < 8; ++t) { sacc[t] = ibsh[t]; vacc[t] = ixbsh[t]; }
  float4 o = make_float4(0.f, 0.f, 0.f, 0.f);
  const float* zr = z + (size_t)j * 64;
  for (int c = 0; c < 64; c += 4) {
    float4 zv = *(const float4*)(zr + c);
    float4 l0 = *(const float4*)(lpw2sh + c);
    float4 l1 = *(const float4*)(lpw2sh + 64 + c);
    float4 l2 = *(const float4*)(lpw2sh + 128 + c);
    float4 lb = *(const float4*)(lpb2sh + c);
    float xkv[4];
    xkv[0] = (zv.x + fmaf(qn2, l2.x, fmaf(qn1, l1.x, fmaf(qn0, l0.x, lb.x)))) * wk[(c + 0) & 7];
    xkv[1] = (zv.y + fmaf(qn2, l2.y, fmaf(qn1, l1.y, fmaf(qn0, l0.y, lb.y)))) * wk[(c + 1) & 7];
    xkv[2] = (zv.z + fmaf(qn2, l2.z, fmaf(qn1, l1.z, fmaf(qn0, l0.z, lb.z)))) * wk[(c + 2) & 7];
    xkv[3] = (zv.w + fmaf(qn2, l2.w, fmaf(qn1, l1.w, fmaf(qn0, l0.w, lb.w)))) * wk[(c + 3) & 7];
    // x_intra: reduce xk over the 16 k's (16-lane groups share one i)
    float r0 = xkv[0], r1 = xkv[1], r2 = xkv[2], r3 = xkv[3];
    #pragma unroll
    for (int m = 1; m < 16; m <<= 1) {
      r0 += __shfl_xor(r0, m);
      r1 += __shfl_xor(r1, m);
      r2 += __shfl_xor(r2, m);
      r3 += __shfl_xor(r3, m);
    }
    if (own == (c >> 2)) o = make_float4(r0, r1, r2, r3);
    #pragma unroll
    for (int d = 0; d < 4; ++d) {
      const float xk = xkv[d];
      const float* iwc = iwsh + (c + d) * 8;
      const float* ixwc = ixwsh + (c + d) * 8;
      float4 a0 = *(const float4*)(iwc);
      float4 a1 = *(const float4*)(iwc + 4);
      float4 b0 = *(const float4*)(ixwc);
      float4 b1 = *(const float4*)(ixwc + 4);
      sacc[0] = fmaf(xk, a0.x, sacc[0]); sacc[1] = fmaf(xk, a0.y, sacc[1]); sacc[2] = fmaf(xk, a0.z, sacc[2]); sacc[3] = fmaf(xk, a0.w, sacc[3]);
      sacc[4] = fmaf(xk, a1.x, sacc[4]); sacc[5] = fmaf(xk, a1.y, sacc[5]); sacc[6] = fmaf(xk, a1.z, sacc[6]); sacc[7] = fmaf(xk, a1.w, sacc[7]);
      vacc[0] = fmaf(xk, b0.x, vacc[0]); vacc[1] = fmaf(xk, b0.y, vacc[1]); vacc[2] = fmaf(xk, b0.z, vacc[2]); vacc[3] = fmaf(xk, b0.w, vacc[3]);
      vacc[4] = fmaf(xk, b1.x, vacc[4]); vacc[5] = fmaf(xk, b1.y, vacc[5]); vacc[6] = fmaf(xk, b1.z, vacc[6]); vacc[7] = fmaf(xk, b1.w, vacc[7]);
    }
  }
  // ex = exp(s) (shift-free; |s| is O(1)); store ex and ex*v, coalesced
  float ex[8];
  #pragma unroll
  for (int t = 0; t < 8; ++t) ex[t] = __expf(sacc[t]);
  *(float4*)(exv + g * 16)      = make_float4(ex[0], ex[1], ex[2], ex[3]);
  *(float4*)(exv + g * 16 + 4)  = make_float4(ex[4], ex[5], ex[6], ex[7]);
  *(float4*)(exv + g * 16 + 8)  = make_float4(ex[0] * vacc[0], ex[1] * vacc[1], ex[2] * vacc[2], ex[3] * vacc[3]);
  *(float4*)(exv + g * 16 + 12) = make_float4(ex[4] * vacc[4], ex[5] * vacc[5], ex[6] * vacc[6], ex[7] * vacc[7]);

  const size_t i = g >> 4;
  *(float4*)(x_intra + i * 64 + own * 4) = o;
}

// ---------------- K6: CSR segment reduce -> resid ----------------
// 16 lanes per segment j: lane t sums exv[g*16+t] over the segment's entries.
__global__ __launch_bounds__(256) void k_inter(
    const int* __restrict__ rowstart, const int* __restrict__ bucket,
    const float* __restrict__ exv, float* __restrict__ resid)
{
  const int tid = threadIdx.x;
  const int t = tid & 15;
  const int j = blockIdx.x * 16 + (tid >> 4);
  const int start = rowstart[j];
  const int end = rowstart[j + 1];
  float acc = 0.f;
  for (int e = start; e < end; ++e) {
    const int gg = bucket[e];
    acc += exv[(size_t)gg * 16 + t];
  }
  const float other = __shfl_xor(acc, 8);
  if (t < 8) {
    // acc = sum(ex), other = sum(ex*v)
    resid[(size_t)j * 8 + t] = (acc > 0.f) ? (other / acc) : 0.f;
  }
}

// ---------------- K8: x2 = x_intra + tile(resid), bn2 partials ----------------
__global__ __launch_bounds__(256) void k_x2_stats(
    float* __restrict__ xi, const float* __restrict__ resid,
    float* __restrict__ partial, int n)
{
  __shared__ float bsum[64], bsq[64];
  const int tid = threadIdx.x;
  const int lane = tid & 63;
  const int wave = tid >> 6;
  if (tid < 64) { bsum[tid] = 0.f; bsq[tid] = 0.f; }
  __syncthreads();
  float ls = 0.f, lq = 0.f;
  const int row0 = (blockIdx.x * 4 + wave) * 16;
  for (int r = 0; r < 16; ++r) {
    const int row = row0 + r;
    float v = xi[(size_t)row * 64 + lane] + resid[(size_t)row * 8 + (lane & 7)];
    xi[(size_t)row * 64 + lane] = v;
    ls += v;
    lq = fmaf(v, v, lq);
  }
  atomicAdd(&bsum[lane], ls);
  atomicAdd(&bsq[lane], lq);
  __syncthreads();
  if (tid < 64) {
    partial[(size_t)tid * gridDim.x + blockIdx.x] = bsum[tid];
    partial[(size_t)(tid + 64) * gridDim.x + blockIdx.x] = bsq[tid];
  }
}

// ---------------- K10: final bn3 + residual + relu ----------------
__global__ __launch_bounds__(256) void k_out(
    const float* __restrict__ y3, const float* __restrict__ x0,
    const float* __restrict__ cst, float* __restrict__ out)
{
  __shared__ float scsh[64], shsh[64];
  const int tid = threadIdx.x;
  if (tid < 64) { scsh[tid] = cst[S_SC3 + tid]; shsh[tid] = cst[S_SH3 + tid]; }
  __syncthreads();
  const size_t i = ((size_t)blockIdx.x * 256 + tid) * 4;
  float4 y = *(const float4*)(y3 + i);
  float4 x = *(const float4*)(x0 + i);
  const int c = (int)(i & 63);
  float4 o;
  o.x = fmaxf(fmaf(y.x, scsh[c + 0], shsh[c + 0]) + x.x, 0.f);
  o.y = fmaxf(fmaf(y.y, scsh[c + 1], shsh[c + 1]) + x.y, 0.f);
  o.z = fmaxf(fmaf(y.z, scsh[c + 2], shsh[c + 2]) + x.z, 0.f);
  o.w = fmaxf(fmaf(y.w, scsh[c + 3], shsh[c + 3]) + x.w, 0.f);
  *(float4*)(out + i) = o;
}

// ---------------- launch ----------------
extern "C" void kernel_launch(void* const* d_in, const int* in_sizes, int n_in,
                              void* d_out, int out_size, void* d_ws, size_t ws_size,
                              hipStream_t stream)
{
  (void)n_in; (void)out_size; (void)ws_size;
  const float* p    = (const float*)d_in[0];
  const float* x    = (const float*)d_in[1];
  const int*   knn  = (const int*)d_in[2];
  const float* w1   = (const float*)d_in[3];
  const float* g1   = (const float*)d_in[4];
  const float* b1   = (const float*)d_in[5];
  const float* m1w1 = (const float*)d_in[6];
  const float* m1b1 = (const float*)d_in[7];
  const float* m1w2 = (const float*)d_in[8];
  const float* m1b2 = (const float*)d_in[9];
  const float* lpw1 = (const float*)d_in[10];
  const float* lpb1 = (const float*)d_in[11];
  const float* lpg  = (const float*)d_in[12];
  const float* lpbt = (const float*)d_in[13];
  const float* lpw2 = (const float*)d_in[14];
  const float* lpb2 = (const float*)d_in[15];
  const float* m2w1 = (const float*)d_in[16];
  const float* m2g1 = (const float*)d_in[17];
  const float* m2bt1= (const float*)d_in[18];
  const float* m2w2 = (const float*)d_in[19];
  const float* m2g2 = (const float*)d_in[20];
  const float* m2bt2= (const float*)d_in[21];
  const float* m2w3 = (const float*)d_in[22];
  const float* m2b3 = (const float*)d_in[23];
  const float* m3w  = (const float*)d_in[24];
  const float* m3b  = (const float*)d_in[25];
  const float* iw   = (const float*)d_in[26];
  const float* ib   = (const float*)d_in[27];
  const float* ixw  = (const float*)d_in[28];
  const float* ixb  = (const float*)d_in[29];
  const float* g2   = (const float*)d_in[30];
  const float* b2   = (const float*)d_in[31];
  const float* w3   = (const float*)d_in[32];
  const float* g3   = (const float*)d_in[33];
  const float* b3   = (const float*)d_in[34];
  float* out = (float*)d_out;
  float* ws  = (float*)d_ws;

  const int n = in_sizes[1] / 64;                // 32768
  const long long nk = (long long)n * 16;        // 524288

  float* cst  = ws;
  int* cnt      = (int*)(ws + CONST_FLOATS);    // n ints (zeroed with cst)
  int* rowstart = cnt + n;                      // n+1 ints
  int* cursor   = rowstart + n + 1;             // n ints
  int* bucket   = cursor + n;                   // nk ints
  float* resid = (float*)(bucket + nk);         // n*8
  float* y1 = resid + 8LL * n;                  // N*64, reused as y3
  float* z  = y1 + 64LL * n;                    // N*64
  float* xi = z + 64LL * n;                     // N*64 (x_intra -> x2)
  float* pr = xi + 64LL * n;                    // N*K*3
  float* en = pr + 48LL * n;                    // N*K*16
  float* h2 = en + 256LL * n;                   // N*K*8
  float* wsm = h2 + 128LL * n;                  // N*K*8
  float* exv = wsm + 128LL * n;                 // N*K*16

  const int gB   = n / 64;            // 512
  const int nkB  = (int)(nk / 256);   // 2048
  const int nkB2 = (int)(nk / 512);   // 1024
  const int nkBi = (int)(nk / 128);   // 4096

  // partial-sum scratch (channel-major)
  float* pbn1  = exv + 256LL * n;                // 128 * gB
  float* plp   = pbn1 + 128LL * gB;              // 8 * nkB
  float* pm2b1 = plp + 8LL * nkB;                // 128 * nkB
  float* pm2b2 = pm2b1 + 128LL * nkB;            // 16 * nkB2
  float* pbn2  = pm2b2 + 16LL * nkB2;            // 128 * gB
  float* pbn3  = pbn2 + 128LL * gB;              // 128 * gB

  // zero const area + histogram counts
  hipMemsetAsync(d_ws, 0, (size_t)CONST_FLOATS * sizeof(float) + (size_t)n * sizeof(int), stream);

  // CSR build (independent of the GEMM chain)
  k_hist<<<nkB, 256, 0, stream>>>(knn, cnt);
  k_scan<<<1, 1024, 0, stream>>>(cnt, rowstart, cursor, n);
  k_fill<<<nkB, 256, 0, stream>>>(knn, cursor, bucket);

  // 1) y1 = x @ w1, bn1 partials
  k_gemm64<<<gB, 256, 0, stream>>>(x, w1, nullptr, nullptr, nullptr, y1, pbn1, n);
  k_reduce<<<128, 256, 0, stream>>>(pbn1, cst + S_BN1_SUM, gB);
  k_finalize_bn<<<1, 64, 0, stream>>>(cst + S_BN1_SUM, cst + S_BN1_SQ, g1, b1,
                                      cst + S_SC1, cst + S_SH1, 1.f / (float)n, 64);
  // 2) z = relu(bn1(y1)) @ m3w + m3b
  k_gemm64<<<gB, 256, 0, stream>>>(y1, m3w, m3b, cst + S_SC1, cst + S_SH1, z, nullptr, n);
  // 3) p_r, energy, lp partials
  k_energy<<<nkB, 256, 0, stream>>>(p, y1, knn, m1w1, m1b1, m1w2, m1b2, lpw1, lpb1,
                                    cst + S_SC1, cst + S_SH1, pr, en, plp);
  k_reduce<<<8, 256, 0, stream>>>(plp, cst + S_LP_SUM, nkB);
  k_f2_lp<<<1, 64, 0, stream>>>(lpg, lpbt, lpw1, lpb1, lpw2, lpb2, cst, 1.f / (float)nk);
  // 4) h1 stats
  k_m2b1_stats<<<nkB, 256, 0, stream>>>(en, pr, cst, m2w1, pm2b1);
  k_reduce<<<128, 256, 0, stream>>>(pm2b1, cst + S_M2B1_SUM, nkB);
  k_finalize_bn<<<1, 64, 0, stream>>>(cst + S_M2B1_SUM, cst + S_M2B1_SQ, m2g1, m2bt1,
                                      cst + S_M2S1, cst + S_M2H1, 1.f / (float)nk, 64);
  // 5) h2 + stats
  k_h2<<<nkB2, 256, 0, stream>>>(en, pr, cst, m2w1, m2w2, h2, pm2b2);
  k_reduce<<<16, 256, 0, stream>>>(pm2b2, cst + S_M2B2_SUM, nkB2);
  k_finalize_bn<<<1, 64, 0, stream>>>(cst + S_M2B2_SUM, cst + S_M2B2_SQ, m2g2, m2bt2,
                                      cst + S_M2S2, cst + S_M2H2, 1.f / (float)nk, 8);
  // 6) softmax weights
  k_softmax<<<nkB, 256, 0, stream>>>(h2, cst, m2w3, m2b3, wsm);
  // 7) xk, x_intra, exv
  k_intra<<<nkBi, 128, 0, stream>>>(z, pr, knn, cst, lpw2, lpb2, iw, ib, ixw, ixb, wsm,
                                    xi, exv);
  // 8) CSR segment reduce -> resid
  k_inter<<<n / 16, 256, 0, stream>>>(rowstart, bucket, exv, resid);
  // 9) x2 = x_intra + tile(resid), bn2 partials
  k_x2_stats<<<gB, 256, 0, stream>>>(xi, resid, pbn2, n);
  k_reduce<<<128, 256, 0, stream>>>(pbn2, cst + S_BN2_SUM, gB);
  k_finalize_bn<<<1, 64, 0, stream>>>(cst + S_BN2_SUM, cst + S_BN2_SQ, g2, b2,
                                      cst + S_SC2, cst + S_SH2, 1.f / (float)n, 64);
  // 10) y3 = relu(bn2(x2)) @ w3, bn3 partials
  k_gemm64<<<gB, 256, 0, stream>>>(xi, w3, nullptr, cst + S_SC2, cst + S_SH2, y1, pbn3, n);
  k_reduce<<<128, 256, 0, stream>>>(pbn3, cst + S_BN3_SUM, gB);
  k_finalize_bn<<<1, 64, 0, stream>>>(cst + S_BN3_SUM, cst + S_BN3_SQ, g3, b3,
                                      cst + S_SC3, cst + S_SH3, 1.f / (float)n, 64);
  // 11) out = relu(bn3(y3) + x)
  k_out<<<(int)((long long)n * 64 / 1024), 256, 0, stream>>>(y1, x, cst, out);
}

// Round 5
// 469.085 us; speedup vs baseline: 3.4196x; 1.0870x over previous
//
#include <hip/hip_runtime.h>

// N = 32768 (runtime), C = 64, K = 16, CS = 8, SHARE = 8

enum {
  S_SC1 = 0,    S_SH1 = 64,
  S_LPSC = 128, S_LPSH = 132,
  S_M2S1 = 136, S_M2H1 = 200,
  S_M2S2 = 264, S_M2H2 = 272,
  S_SC2 = 280,  S_SH2 = 344,
  S_SC3 = 408,  S_SH3 = 472,
  S_LPW2S = 536, S_LPB2S = 584,
  S_QW = 600, S_QB = 612,
  CONST_FLOATS = 640
};

// ---------------- fused partial-reduce + BN finalize: one block per channel ----------------
__global__ __launch_bounds__(256) void k_rbn(
    const float* __restrict__ partial, int nb, int nch,
    const float* __restrict__ g, const float* __restrict__ b,
    float* __restrict__ scale, float* __restrict__ shift, float inv_count)
{
  const int c = blockIdx.x;
  const int tid = threadIdx.x;
  float s = 0.f, q = 0.f;
  for (int i = tid; i < nb; i += 256) {
    s += partial[(size_t)c * nb + i];
    q += partial[(size_t)(c + nch) * nb + i];
  }
  #pragma unroll
  for (int m = 1; m < 64; m <<= 1) { s += __shfl_xor(s, m); q += __shfl_xor(q, m); }
  __shared__ float ws[4], wq[4];
  if ((tid & 63) == 0) { ws[tid >> 6] = s; wq[tid >> 6] = q; }
  __syncthreads();
  if (tid == 0) {
    float S = ws[0] + ws[1] + ws[2] + ws[3];
    float Q = wq[0] + wq[1] + wq[2] + wq[3];
    float m = S * inv_count;
    float v = Q * inv_count - m * m;
    float rs = rsqrtf(v + 1e-5f);
    float sc = g[c] * rs;
    scale[c] = sc;
    shift[c] = fmaf(-m, sc, b[c]);
  }
}

// ---------------- generic 64x64 GEMM ----------------
__global__ __launch_bounds__(256) void k_gemm64(
    const float* __restrict__ in, const float* __restrict__ w,
    const float* __restrict__ bias,
    const float* __restrict__ sc, const float* __restrict__ sh,
    float* __restrict__ out,
    float* __restrict__ partial,   // [128 * gridDim.x] channel-major, or null
    int n)
{
  __shared__ float scsh[64], shsh[64];
  __shared__ float bsum[64], bsq[64];
  const int tid = threadIdx.x;
  const int lane = tid & 63;
  const int wave = tid >> 6;
  if (sc != nullptr && tid < 64) { scsh[tid] = sc[tid]; shsh[tid] = sh[tid]; }
  if (tid < 64) { bsum[tid] = 0.f; bsq[tid] = 0.f; }
  __syncthreads();

  float wreg[64];
  #pragma unroll
  for (int k = 0; k < 64; ++k) wreg[k] = w[k * 64 + lane];
  const float bz = bias ? bias[lane] : 0.f;

  float lsum = 0.f, lsq = 0.f;
  const int row0 = (blockIdx.x * 4 + wave) * 16;
  for (int r = 0; r < 16; ++r) {
    const int row = row0 + r;
    const float* xr = in + (size_t)row * 64;
    float acc = bz;
    if (sc != nullptr) {
      #pragma unroll
      for (int k = 0; k < 64; k += 4) {
        float4 xv = *(const float4*)(xr + k);
        float x0 = fmaxf(fmaf(xv.x, scsh[k + 0], shsh[k + 0]), 0.f);
        float x1 = fmaxf(fmaf(xv.y, scsh[k + 1], shsh[k + 1]), 0.f);
        float x2 = fmaxf(fmaf(xv.z, scsh[k + 2], shsh[k + 2]), 0.f);
        float x3 = fmaxf(fmaf(xv.w, scsh[k + 3], shsh[k + 3]), 0.f);
        acc = fmaf(x0, wreg[k + 0], acc);
        acc = fmaf(x1, wreg[k + 1], acc);
        acc = fmaf(x2, wreg[k + 2], acc);
        acc = fmaf(x3, wreg[k + 3], acc);
      }
    } else {
      #pragma unroll
      for (int k = 0; k < 64; k += 4) {
        float4 xv = *(const float4*)(xr + k);
        acc = fmaf(xv.x, wreg[k + 0], acc);
        acc = fmaf(xv.y, wreg[k + 1], acc);
        acc = fmaf(xv.z, wreg[k + 2], acc);
        acc = fmaf(xv.w, wreg[k + 3], acc);
      }
    }
    out[(size_t)row * 64 + lane] = acc;
    lsum += acc;
    lsq = fmaf(acc, acc, lsq);
  }
  if (partial != nullptr) {
    atomicAdd(&bsum[lane], lsum);
    atomicAdd(&bsq[lane], lsq);
    __syncthreads();
    if (tid < 64) {
      partial[(size_t)tid * gridDim.x + blockIdx.x] = bsum[tid];
      partial[(size_t)(tid + 64) * gridDim.x + blockIdx.x] = bsq[tid];
    }
  }
}

// ---------------- Y16 = normrelu(y1) @ m1w1[3:67] ----------------
__global__ __launch_bounds__(256) void k_gemm16(
    const float* __restrict__ in, const float* __restrict__ w,  // w = m1w1 + 48, 64x16 row-major
    const float* __restrict__ sc, const float* __restrict__ sh,
    float* __restrict__ out16)
{
  __shared__ float xn[16][65];
  __shared__ float wsh[1024];
  __shared__ float scsh[64], shsh[64];
  const int tid = threadIdx.x;
  if (tid < 64) { scsh[tid] = sc[tid]; shsh[tid] = sh[tid]; }
  for (int idx = tid; idx < 1024; idx += 256) wsh[idx] = w[idx];
  __syncthreads();
  const int base = blockIdx.x * 16;
  for (int idx = tid; idx < 1024; idx += 256) {
    int r = idx >> 6, c = idx & 63;
    float v = in[(size_t)(base + r) * 64 + c];
    xn[r][c] = fmaxf(fmaf(v, scsh[c], shsh[c]), 0.f);
  }
  __syncthreads();
  const int r = tid >> 4, t = tid & 15;
  float acc = 0.f;
  #pragma unroll
  for (int c = 0; c < 64; ++c) acc = fmaf(xn[r][c], wsh[c * 16 + t], acc);
  out16[(size_t)(base + r) * 16 + t] = acc;
}

// ---------------- lp finalize + weight folding (with built-in reduce) ----------------
__global__ __launch_bounds__(256) void k_f2_lp(
    const float* __restrict__ plp, int nb,
    const float* __restrict__ lpg, const float* __restrict__ lpbt,
    const float* __restrict__ lpw1, const float* __restrict__ lpb1,
    const float* __restrict__ lpw2, const float* __restrict__ lpb2,
    float* __restrict__ cst, float inv_count)
{
  __shared__ float S[8];
  const int tid = threadIdx.x;
  const int row = tid >> 5, l32 = tid & 31;
  float s = 0.f;
  for (int i = l32; i < nb; i += 32) s += plp[(size_t)row * nb + i];
  #pragma unroll
  for (int m = 1; m < 32; m <<= 1) s += __shfl_xor(s, m);
  if (l32 == 0) S[row] = s;
  __syncthreads();
  const int t = tid;
  if (t < 3) {
    float m = S[t] * inv_count;
    float v = S[4 + t] * inv_count - m * m;
    float rs = rsqrtf(v + 1e-5f);
    float sc = lpg[t] * rs;
    cst[S_LPSC + t] = sc;
    cst[S_LPSH + t] = fmaf(-m, sc, lpbt[t]);
  }
  __syncthreads();
  if (t < 9)  cst[S_QW + t] = lpw1[t] * cst[S_LPSC + (t % 3)];
  if (t < 3)  cst[S_QB + t] = fmaf(lpb1[t], cst[S_LPSC + t], cst[S_LPSH + t]);
  if (t < 16) {
    float b = 0.f;
    for (int c2 = 0; c2 < 4; ++c2) b += lpb2[c2 * 16 + t];
    cst[S_LPB2S + t] = b;
    for (int r = 0; r < 3; ++r) {
      float w = 0.f;
      for (int c2 = 0; c2 < 4; ++c2) w += lpw2[r * 64 + c2 * 16 + t];
      cst[S_LPW2S + r * 16 + t] = w;
    }
  }
}

// ---------------- K1: p_r, lp partials, knn histogram ----------------
__global__ __launch_bounds__(256) void k_prhist(
    const float* __restrict__ p, const int* __restrict__ knn,
    const float* __restrict__ lpw1, const float* __restrict__ lpb1,
    float* __restrict__ p_r, float* __restrict__ plp, int* __restrict__ cnt)
{
  __shared__ float lpw1sh[9], lpb1sh[3];
  __shared__ float lpsh[4][8];
  const int tid = threadIdx.x;
  if (tid < 9) lpw1sh[tid] = lpw1[tid];
  if (tid < 3) lpb1sh[tid] = lpb1[tid];
  __syncthreads();

  const size_t g = (size_t)blockIdx.x * 256 + tid;
  const int i = (int)(g >> 4);
  const int j = knn[g];
  const float pr0 = p[j * 3 + 0] - p[i * 3 + 0];
  const float pr1 = p[j * 3 + 1] - p[i * 3 + 1];
  const float pr2 = p[j * 3 + 2] - p[i * 3 + 2];
  p_r[g * 3 + 0] = pr0; p_r[g * 3 + 1] = pr1; p_r[g * 3 + 2] = pr2;
  atomicAdd(&cnt[j], 1);

  float q0 = fmaf(pr2, lpw1sh[6], fmaf(pr1, lpw1sh[3], fmaf(pr0, lpw1sh[0], lpb1sh[0])));
  float q1 = fmaf(pr2, lpw1sh[7], fmaf(pr1, lpw1sh[4], fmaf(pr0, lpw1sh[1], lpb1sh[1])));
  float q2 = fmaf(pr2, lpw1sh[8], fmaf(pr1, lpw1sh[5], fmaf(pr0, lpw1sh[2], lpb1sh[2])));
  float s0 = q0, s1 = q1, s2 = q2, qq0 = q0 * q0, qq1 = q1 * q1, qq2 = q2 * q2;
  #pragma unroll
  for (int m = 1; m < 64; m <<= 1) {
    s0 += __shfl_xor(s0, m); s1 += __shfl_xor(s1, m); s2 += __shfl_xor(s2, m);
    qq0 += __shfl_xor(qq0, m); qq1 += __shfl_xor(qq1, m); qq2 += __shfl_xor(qq2, m);
  }
  if ((tid & 63) == 0) {
    const int w = tid >> 6;
    lpsh[w][0] = s0; lpsh[w][1] = s1; lpsh[w][2] = s2; lpsh[w][3] = 0.f;
    lpsh[w][4] = qq0; lpsh[w][5] = qq1; lpsh[w][6] = qq2; lpsh[w][7] = 0.f;
  }
  __syncthreads();
  if (tid < 8) {
    float v = lpsh[0][tid] + lpsh[1][tid] + lpsh[2][tid] + lpsh[3][tid];
    plp[(size_t)tid * gridDim.x + blockIdx.x] = v;
  }
}

// ---------------- CSR build: scan (one block, 1024 threads, n%1024==0) ----------------
__global__ __launch_bounds__(1024) void k_scan(
    const int* __restrict__ cnt, int* __restrict__ rowstart,
    int* __restrict__ cursor, int n)
{
  __shared__ int tsum[1024];
  const int tid = threadIdx.x;
  const int per = n >> 10;
  const int base = tid * per;
  int local[32];
  int s = 0;
  for (int u = 0; u < per; ++u) { local[u] = cnt[base + u]; s += local[u]; }
  tsum[tid] = s;
  __syncthreads();
  for (int off = 1; off < 1024; off <<= 1) {
    int v = (tid >= off) ? tsum[tid - off] : 0;
    __syncthreads();
    tsum[tid] += v;
    __syncthreads();
  }
  int run = tsum[tid] - s;
  for (int u = 0; u < per; ++u) {
    rowstart[base + u] = run;
    cursor[base + u] = run;
    run += local[u];
  }
  if (tid == 1023) rowstart[n] = run;
}

// ---------------- CSR build: fill buckets ----------------
__global__ __launch_bounds__(256) void k_fill(
    const int* __restrict__ knn, int* __restrict__ cursor, int* __restrict__ bucket)
{
  const size_t g = (size_t)blockIdx.x * 256 + threadIdx.x;
  const int j = knn[g];
  const int pos = atomicAdd(&cursor[j], 1);
  bucket[pos] = (int)g;
}

// ---------------- K2: e-recompute + h1 BN stats (no energy materialization) ----------------
__global__ __launch_bounds__(256) void k_e_stats(
    const float* __restrict__ y16, const float* __restrict__ p_r,
    const int* __restrict__ knn,
    const float* __restrict__ m1w1, const float* __restrict__ m1b1,
    const float* __restrict__ m1w2, const float* __restrict__ m1b2,
    const float* __restrict__ cst, const float* __restrict__ m2w1,
    float* __restrict__ partial)   // [128 * gridDim.x]
{
  __shared__ float esh[32 * 260];
  __shared__ float w1p[48], b1sh[16], w2sh[256], b2sh[16];
  __shared__ float lpwsh[48], lpbsh[16], qwsh[9], qbsh[3];
  __shared__ float lsum[64], lsq[64];
  const int tid = threadIdx.x;
  const int lane = tid & 63;
  const int wave = tid >> 6;
  if (tid < 48) w1p[tid] = m1w1[tid];
  if (tid < 16) { b1sh[tid] = m1b1[tid]; b2sh[tid] = m1b2[tid]; }
  w2sh[tid] = m1w2[tid];
  if (tid < 48) lpwsh[tid] = cst[S_LPW2S + tid];
  if (tid < 16) lpbsh[tid] = cst[S_LPB2S + tid];
  if (tid < 9) qwsh[tid] = cst[S_QW + tid];
  if (tid < 3) qbsh[tid] = cst[S_QB + tid];
  if (tid < 64) { lsum[tid] = 0.f; lsq[tid] = 0.f; }
  float wreg[32];
  #pragma unroll
  for (int k = 0; k < 32; ++k) wreg[k] = m2w1[k * 64 + lane];
  __syncthreads();

  const size_t g = (size_t)blockIdx.x * 256 + tid;
  const int j = knn[g];
  const float pr0 = p_r[g * 3 + 0], pr1 = p_r[g * 3 + 1], pr2 = p_r[g * 3 + 2];
  const float* yj = y16 + (size_t)j * 16;
  float4 ya = *(const float4*)(yj);
  float4 yb = *(const float4*)(yj + 4);
  float4 yc = *(const float4*)(yj + 8);
  float4 yd = *(const float4*)(yj + 12);
  float t1[16] = {ya.x, ya.y, ya.z, ya.w, yb.x, yb.y, yb.z, yb.w,
                  yc.x, yc.y, yc.z, yc.w, yd.x, yd.y, yd.z, yd.w};
  #pragma unroll
  for (int t = 0; t < 16; ++t) {
    t1[t] = fmaxf(fmaf(pr2, w1p[32 + t], fmaf(pr1, w1p[16 + t],
                  fmaf(pr0, w1p[t], t1[t] + b1sh[t]))), 0.f);
  }
  float e[32];
  #pragma unroll
  for (int t = 0; t < 16; ++t) {
    float a = b2sh[t];
    #pragma unroll
    for (int u = 0; u < 16; ++u) a = fmaf(t1[u], w2sh[u * 16 + t], a);
    e[t] = a;
  }
  const float qn0 = fmaxf(fmaf(pr2, qwsh[6], fmaf(pr1, qwsh[3], fmaf(pr0, qwsh[0], qbsh[0]))), 0.f);
  const float qn1 = fmaxf(fmaf(pr2, qwsh[7], fmaf(pr1, qwsh[4], fmaf(pr0, qwsh[1], qbsh[1]))), 0.f);
  const float qn2 = fmaxf(fmaf(pr2, qwsh[8], fmaf(pr1, qwsh[5], fmaf(pr0, qwsh[2], qbsh[2]))), 0.f);
  #pragma unroll
  for (int t = 0; t < 16; ++t)
    e[16 + t] = fmaf(qn2, lpwsh[32 + t], fmaf(qn1, lpwsh[16 + t], fmaf(qn0, lpwsh[t], lpbsh[t])));

  #pragma unroll
  for (int k = 0; k < 32; ++k) esh[k * 260 + tid] = e[k];
  __syncthreads();

  float ls = 0.f, lq = 0.f;
  for (int g4 = wave * 64; g4 < wave * 64 + 64; g4 += 4) {
    float h0 = 0.f, h1 = 0.f, h2 = 0.f, h3 = 0.f;
    #pragma unroll
    for (int k = 0; k < 32; ++k) {
      float4 ev = *(const float4*)(esh + k * 260 + g4);
      h0 = fmaf(ev.x, wreg[k], h0);
      h1 = fmaf(ev.y, wreg[k], h1);
      h2 = fmaf(ev.z, wreg[k], h2);
      h3 = fmaf(ev.w, wreg[k], h3);
    }
    ls += h0 + h1 + h2 + h3;
    lq += h0 * h0 + h1 * h1 + h2 * h2 + h3 * h3;
  }
  atomicAdd(&lsum[lane], ls);
  atomicAdd(&lsq[lane], lq);
  __syncthreads();
  if (tid < 64) {
    partial[(size_t)tid * gridDim.x + blockIdx.x] = lsum[tid];
    partial[(size_t)(tid + 64) * gridDim.x + blockIdx.x] = lsq[tid];
  }
}

// ---------------- K3: h2 = relu(bn(h1)) @ m2w2, + partials ----------------
__global__ __launch_bounds__(256) void k_h2(
    const float* __restrict__ y16, const float* __restrict__ p_r,
    const int* __restrict__ knn,
    const float* __restrict__ m1w1, const float* __restrict__ m1b1,
    const float* __restrict__ m1w2, const float* __restrict__ m1b2,
    const float* __restrict__ cst, const float* __restrict__ m2w1,
    const float* __restrict__ m2w2,
    float* __restrict__ h2out,
    float* __restrict__ partial)   // [16 * gridDim.x]
{
  __shared__ float wT[64 * 36];
  __shared__ float w2m[512];
  __shared__ float w1p[48], b1sh[16], w2sh[256], b2sh[16];
  __shared__ float lpwsh[48], lpbsh[16], qwsh[9], qbsh[3];
  __shared__ float scsh[64], shsh[64];
  __shared__ float redsh[4][16];
  const int tid = threadIdx.x;
  for (int idx = tid; idx < 2048; idx += 256) { int k = idx >> 6, c = idx & 63; wT[c * 36 + k] = m2w1[idx]; }
  for (int idx = tid; idx < 512; idx += 256) w2m[idx] = m2w2[idx];
  if (tid < 48) w1p[tid] = m1w1[tid];
  if (tid < 16) { b1sh[tid] = m1b1[tid]; b2sh[tid] = m1b2[tid]; }
  w2sh[tid] = m1w2[tid];
  if (tid < 48) lpwsh[tid] = cst[S_LPW2S + tid];
  if (tid < 16) lpbsh[tid] = cst[S_LPB2S + tid];
  if (tid < 9) qwsh[tid] = cst[S_QW + tid];
  if (tid < 3) qbsh[tid] = cst[S_QB + tid];
  if (tid < 64) { scsh[tid] = cst[S_M2S1 + tid]; shsh[tid] = cst[S_M2H1 + tid]; }
  __syncthreads();

  const size_t g0 = ((size_t)blockIdx.x * 256 + tid) * 2;
  float e[2][32];
  #pragma unroll
  for (int gg = 0; gg < 2; ++gg) {
    const size_t g = g0 + gg;
    const int j = knn[g];
    const float pr0 = p_r[g * 3 + 0], pr1 = p_r[g * 3 + 1], pr2 = p_r[g * 3 + 2];
    const float* yj = y16 + (size_t)j * 16;
    float4 ya = *(const float4*)(yj);
    float4 yb = *(const float4*)(yj + 4);
    float4 yc = *(const float4*)(yj + 8);
    float4 yd = *(const float4*)(yj + 12);
    float t1[16] = {ya.x, ya.y, ya.z, ya.w, yb.x, yb.y, yb.z, yb.w,
                    yc.x, yc.y, yc.z, yc.w, yd.x, yd.y, yd.z, yd.w};
    #pragma unroll
    for (int t = 0; t < 16; ++t) {
      t1[t] = fmaxf(fmaf(pr2, w1p[32 + t], fmaf(pr1, w1p[16 + t],
                    fmaf(pr0, w1p[t], t1[t] + b1sh[t]))), 0.f);
    }
    #pragma unroll
    for (int t = 0; t < 16; ++t) {
      float a = b2sh[t];
      #pragma unroll
      for (int u = 0; u < 16; ++u) a = fmaf(t1[u], w2sh[u * 16 + t], a);
      e[gg][t] = a;
    }
    const float qn0 = fmaxf(fmaf(pr2, qwsh[6], fmaf(pr1, qwsh[3], fmaf(pr0, qwsh[0], qbsh[0]))), 0.f);
    const float qn1 = fmaxf(fmaf(pr2, qwsh[7], fmaf(pr1, qwsh[4], fmaf(pr0, qwsh[1], qbsh[1]))), 0.f);
    const float qn2 = fmaxf(fmaf(pr2, qwsh[8], fmaf(pr1, qwsh[5], fmaf(pr0, qwsh[2], qbsh[2]))), 0.f);
    #pragma unroll
    for (int t = 0; t < 16; ++t)
      e[gg][16 + t] = fmaf(qn2, lpwsh[32 + t], fmaf(qn1, lpwsh[16 + t], fmaf(qn0, lpwsh[t], lpbsh[t])));
  }

  float a0[8], a1[8];
  #pragma unroll
  for (int t = 0; t < 8; ++t) { a0[t] = 0.f; a1[t] = 0.f; }
  for (int c = 0; c < 64; ++c) {
    const float* wc = wT + c * 36;
    float h0 = 0.f, h1 = 0.f;
    #pragma unroll
    for (int k = 0; k < 32; k += 4) {
      float4 wv = *(const float4*)(wc + k);
      h0 = fmaf(e[0][k + 3], wv.w, fmaf(e[0][k + 2], wv.z, fmaf(e[0][k + 1], wv.y, fmaf(e[0][k + 0], wv.x, h0))));
      h1 = fmaf(e[1][k + 3], wv.w, fmaf(e[1][k + 2], wv.z, fmaf(e[1][k + 1], wv.y, fmaf(e[1][k + 0], wv.x, h1))));
    }
    float x0 = fmaxf(fmaf(h0, scsh[c], shsh[c]), 0.f);
    float x1 = fmaxf(fmaf(h1, scsh[c], shsh[c]), 0.f);
    float4 wa = *(const float4*)(w2m + c * 8);
    float4 wb = *(const float4*)(w2m + c * 8 + 4);
    a0[0] = fmaf(x0, wa.x, a0[0]); a0[1] = fmaf(x0, wa.y, a0[1]); a0[2] = fmaf(x0, wa.z, a0[2]); a0[3] = fmaf(x0, wa.w, a0[3]);
    a0[4] = fmaf(x0, wb.x, a0[4]); a0[5] = fmaf(x0, wb.y, a0[5]); a0[6] = fmaf(x0, wb.z, a0[6]); a0[7] = fmaf(x0, wb.w, a0[7]);
    a1[0] = fmaf(x1, wa.x, a1[0]); a1[1] = fmaf(x1, wa.y, a1[1]); a1[2] = fmaf(x1, wa.z, a1[2]); a1[3] = fmaf(x1, wa.w, a1[3]);
    a1[4] = fmaf(x1, wb.x, a1[4]); a1[5] = fmaf(x1, wb.y, a1[5]); a1[6] = fmaf(x1, wb.z, a1[6]); a1[7] = fmaf(x1, wb.w, a1[7]);
  }
  *(float4*)(h2out + g0 * 8)      = make_float4(a0[0], a0[1], a0[2], a0[3]);
  *(float4*)(h2out + g0 * 8 + 4)  = make_float4(a0[4], a0[5], a0[6], a0[7]);
  *(float4*)(h2out + g0 * 8 + 8)  = make_float4(a1[0], a1[1], a1[2], a1[3]);
  *(float4*)(h2out + g0 * 8 + 12) = make_float4(a1[4], a1[5], a1[6], a1[7]);

  float st[8], sq[8];
  #pragma unroll
  for (int t = 0; t < 8; ++t) {
    st[t] = a0[t] + a1[t];
    sq[t] = fmaf(a0[t], a0[t], a1[t] * a1[t]);
  }
  #pragma unroll
  for (int m = 1; m < 64; m <<= 1) {
    #pragma unroll
    for (int t = 0; t < 8; ++t) { st[t] += __shfl_xor(st[t], m); sq[t] += __shfl_xor(sq[t], m); }
  }
  if ((tid & 63) == 0) {
    const int w = tid >> 6;
    #pragma unroll
    for (int t = 0; t < 8; ++t) { redsh[w][t] = st[t]; redsh[w][8 + t] = sq[t]; }
  }
  __syncthreads();
  if (tid < 16) {
    float v = redsh[0][tid] + redsh[1][tid] + redsh[2][tid] + redsh[3][tid];
    partial[(size_t)tid * gridDim.x + blockIdx.x] = v;
  }
}

// ---------------- K4: fused softmax + xk + x_intra + exv ----------------
__global__ __launch_bounds__(128) void k_intra(
    const float* __restrict__ z, const float* __restrict__ p_r,
    const int* __restrict__ knn, const float* __restrict__ cst,
    const float* __restrict__ lpw2, const float* __restrict__ lpb2,
    const float* __restrict__ iw, const float* __restrict__ ib,
    const float* __restrict__ ixw, const float* __restrict__ ixb,
    const float* __restrict__ h2, const float* __restrict__ m2w3,
    const float* __restrict__ m2b3,
    float* __restrict__ x_intra, float* __restrict__ exv)
{
  __shared__ float lpw2sh[192], lpb2sh[64];
  __shared__ float iwsh[512], ixwsh[512];
  __shared__ float ibsh[8], ixbsh[8];
  __shared__ float w3sh[64], b3sh[8], s2sh[8], h2ssh[8];
  const int tid = threadIdx.x;
  for (int idx = tid; idx < 192; idx += 128) lpw2sh[idx] = lpw2[idx];
  if (tid < 64) { lpb2sh[tid] = lpb2[tid]; w3sh[tid] = m2w3[tid]; }
  for (int idx = tid; idx < 512; idx += 128) { iwsh[idx] = iw[idx]; ixwsh[idx] = ixw[idx]; }
  if (tid < 8) {
    ibsh[tid] = ib[tid]; ixbsh[tid] = ixb[tid];
    b3sh[tid] = m2b3[tid]; s2sh[tid] = cst[S_M2S2 + tid]; h2ssh[tid] = cst[S_M2H2 + tid];
  }
  __syncthreads();

  const size_t g = (size_t)blockIdx.x * 128 + tid;
  const int j = knn[g];
  const int own = tid & 15;
  const float pr0 = p_r[g * 3 + 0], pr1 = p_r[g * 3 + 1], pr2 = p_r[g * 3 + 2];
  const float qn0 = fmaxf(fmaf(pr2, cst[S_QW + 6], fmaf(pr1, cst[S_QW + 3], fmaf(pr0, cst[S_QW + 0], cst[S_QB + 0]))), 0.f);
  const float qn1 = fmaxf(fmaf(pr2, cst[S_QW + 7], fmaf(pr1, cst[S_QW + 4], fmaf(pr0, cst[S_QW + 1], cst[S_QB + 1]))), 0.f);
  const float qn2 = fmaxf(fmaf(pr2, cst[S_QW + 8], fmaf(pr1, cst[S_QW + 5], fmaf(pr0, cst[S_QW + 2], cst[S_QB + 2]))), 0.f);

  // fused k-softmax: logits from bn2'(h2), softmax over 16-lane group (k dim)
  float4 ha = *(const float4*)(h2 + g * 8);
  float4 hb = *(const float4*)(h2 + g * 8 + 4);
  float hn[8];
  hn[0] = fmaxf(fmaf(ha.x, s2sh[0], h2ssh[0]), 0.f);
  hn[1] = fmaxf(fmaf(ha.y, s2sh[1], h2ssh[1]), 0.f);
  hn[2] = fmaxf(fmaf(ha.z, s2sh[2], h2ssh[2]), 0.f);
  hn[3] = fmaxf(fmaf(ha.w, s2sh[3], h2ssh[3]), 0.f);
  hn[4] = fmaxf(fmaf(hb.x, s2sh[4], h2ssh[4]), 0.f);
  hn[5] = fmaxf(fmaf(hb.y, s2sh[5], h2ssh[5]), 0.f);
  hn[6] = fmaxf(fmaf(hb.z, s2sh[6], h2ssh[6]), 0.f);
  hn[7] = fmaxf(fmaf(hb.w, s2sh[7], h2ssh[7]), 0.f);
  float wk[8];
  #pragma unroll
  for (int t = 0; t < 8; ++t) {
    float a = b3sh[t];
    #pragma unroll
    for (int u = 0; u < 8; ++u) a = fmaf(hn[u], w3sh[u * 8 + t], a);
    wk[t] = a;
  }
  #pragma unroll
  for (int t = 0; t < 8; ++t) {
    float m = wk[t];
    m = fmaxf(m, __shfl_xor(m, 1));
    m = fmaxf(m, __shfl_xor(m, 2));
    m = fmaxf(m, __shfl_xor(m, 4));
    m = fmaxf(m, __shfl_xor(m, 8));
    float ex = __expf(wk[t] - m);
    float s = ex;
    s += __shfl_xor(s, 1);
    s += __shfl_xor(s, 2);
    s += __shfl_xor(s, 4);
    s += __shfl_xor(s, 8);
    wk[t] = ex / s;
  }

  float sacc[8], vacc[8];
  #pragma unroll
  for (int t = 0; t < 8; ++t) { sacc[t] = ibsh[t]; vacc[t] = ixbsh[t]; }
  float4 o = make_float4(0.f, 0.f, 0.f, 0.f);
  const float* zr = z + (size_t)j * 64;
  for (int c = 0; c < 64; c += 4) {
    float4 zv = *(const float4*)(zr + c);
    float4 l0 = *(const float4*)(lpw2sh + c);
    float4 l1 = *(const float4*)(lpw2sh + 64 + c);
    float4 l2 = *(const float4*)(lpw2sh + 128 + c);
    float4 lb = *(const float4*)(lpb2sh + c);
    float xkv[4];
    xkv[0] = (zv.x + fmaf(qn2, l2.x, fmaf(qn1, l1.x, fmaf(qn0, l0.x, lb.x)))) * wk[(c + 0) & 7];
    xkv[1] = (zv.y + fmaf(qn2, l2.y, fmaf(qn1, l1.y, fmaf(qn0, l0.y, lb.y)))) * wk[(c + 1) & 7];
    xkv[2] = (zv.z + fmaf(qn2, l2.z, fmaf(qn1, l1.z, fmaf(qn0, l0.z, lb.z)))) * wk[(c + 2) & 7];
    xkv[3] = (zv.w + fmaf(qn2, l2.w, fmaf(qn1, l1.w, fmaf(qn0, l0.w, lb.w)))) * wk[(c + 3) & 7];
    float r0 = xkv[0], r1 = xkv[1], r2 = xkv[2], r3 = xkv[3];
    #pragma unroll
    for (int m = 1; m < 16; m <<= 1) {
      r0 += __shfl_xor(r0, m);
      r1 += __shfl_xor(r1, m);
      r2 += __shfl_xor(r2, m);
      r3 += __shfl_xor(r3, m);
    }
    if (own == (c >> 2)) o = make_float4(r0, r1, r2, r3);
    #pragma unroll
    for (int d = 0; d < 4; ++d) {
      const float xk = xkv[d];
      const float* iwc = iwsh + (c + d) * 8;
      const float* ixwc = ixwsh + (c + d) * 8;
      float4 a0 = *(const float4*)(iwc);
      float4 a1 = *(const float4*)(iwc + 4);
      float4 b0 = *(const float4*)(ixwc);
      float4 b1 = *(const float4*)(ixwc + 4);
      sacc[0] = fmaf(xk, a0.x, sacc[0]); sacc[1] = fmaf(xk, a0.y, sacc[1]); sacc[2] = fmaf(xk, a0.z, sacc[2]); sacc[3] = fmaf(xk, a0.w, sacc[3]);
      sacc[4] = fmaf(xk, a1.x, sacc[4]); sacc[5] = fmaf(xk, a1.y, sacc[5]); sacc[6] = fmaf(xk, a1.z, sacc[6]); sacc[7] = fmaf(xk, a1.w, sacc[7]);
      vacc[0] = fmaf(xk, b0.x, vacc[0]); vacc[1] = fmaf(xk, b0.y, vacc[1]); vacc[2] = fmaf(xk, b0.z, vacc[2]); vacc[3] = fmaf(xk, b0.w, vacc[3]);
      vacc[4] = fmaf(xk, b1.x, vacc[4]); vacc[5] = fmaf(xk, b1.y, vacc[5]); vacc[6] = fmaf(xk, b1.z, vacc[6]); vacc[7] = fmaf(xk, b1.w, vacc[7]);
    }
  }
  float ex[8];
  #pragma unroll
  for (int t = 0; t < 8; ++t) ex[t] = __expf(sacc[t]);
  *(float4*)(exv + g * 16)      = make_float4(ex[0], ex[1], ex[2], ex[3]);
  *(float4*)(exv + g * 16 + 4)  = make_float4(ex[4], ex[5], ex[6], ex[7]);
  *(float4*)(exv + g * 16 + 8)  = make_float4(ex[0] * vacc[0], ex[1] * vacc[1], ex[2] * vacc[2], ex[3] * vacc[3]);
  *(float4*)(exv + g * 16 + 12) = make_float4(ex[4] * vacc[4], ex[5] * vacc[5], ex[6] * vacc[6], ex[7] * vacc[7]);

  const size_t i = g >> 4;
  *(float4*)(x_intra + i * 64 + own * 4) = o;
}

// ---------------- K5: CSR segment reduce -> resid ----------------
__global__ __launch_bounds__(256) void k_inter(
    const int* __restrict__ rowstart, const int* __restrict__ bucket,
    const float* __restrict__ exv, float* __restrict__ resid)
{
  const int tid = threadIdx.x;
  const int t = tid & 15;
  const int j = blockIdx.x * 16 + (tid >> 4);
  const int start = rowstart[j];
  const int end = rowstart[j + 1];
  float acc = 0.f;
  for (int e = start; e < end; ++e) {
    const int gg = bucket[e];
    acc += exv[(size_t)gg * 16 + t];
  }
  const float other = __shfl_xor(acc, 8);
  if (t < 8) {
    resid[(size_t)j * 8 + t] = (acc > 0.f) ? (other / acc) : 0.f;
  }
}

// ---------------- K6: x2 = x_intra + tile(resid), bn2 partials ----------------
__global__ __launch_bounds__(256) void k_x2_stats(
    float* __restrict__ xi, const float* __restrict__ resid,
    float* __restrict__ partial, int n)
{
  __shared__ float bsum[64], bsq[64];
  const int tid = threadIdx.x;
  const int lane = tid & 63;
  const int wave = tid >> 6;
  if (tid < 64) { bsum[tid] = 0.f; bsq[tid] = 0.f; }
  __syncthreads();
  float ls = 0.f, lq = 0.f;
  const int row0 = (blockIdx.x * 4 + wave) * 16;
  for (int r = 0; r < 16; ++r) {
    const int row = row0 + r;
    float v = xi[(size_t)row * 64 + lane] + resid[(size_t)row * 8 + (lane & 7)];
    xi[(size_t)row * 64 + lane] = v;
    ls += v;
    lq = fmaf(v, v, lq);
  }
  atomicAdd(&bsum[lane], ls);
  atomicAdd(&bsq[lane], lq);
  __syncthreads();
  if (tid < 64) {
    partial[(size_t)tid * gridDim.x + blockIdx.x] = bsum[tid];
    partial[(size_t)(tid + 64) * gridDim.x + blockIdx.x] = bsq[tid];
  }
}

// ---------------- K7: final bn3 + residual + relu ----------------
__global__ __launch_bounds__(256) void k_out(
    const float* __restrict__ y3, const float* __restrict__ x0,
    const float* __restrict__ cst, float* __restrict__ out)
{
  __shared__ float scsh[64], shsh[64];
  const int tid = threadIdx.x;
  if (tid < 64) { scsh[tid] = cst[S_SC3 + tid]; shsh[tid] = cst[S_SH3 + tid]; }
  __syncthreads();
  const size_t i = ((size_t)blockIdx.x * 256 + tid) * 4;
  float4 y = *(const float4*)(y3 + i);
  float4 x = *(const float4*)(x0 + i);
  const int c = (int)(i & 63);
  float4 o;
  o.x = fmaxf(fmaf(y.x, scsh[c + 0], shsh[c + 0]) + x.x, 0.f);
  o.y = fmaxf(fmaf(y.y, scsh[c + 1], shsh[c + 1]) + x.y, 0.f);
  o.z = fmaxf(fmaf(y.z, scsh[c + 2], shsh[c + 2]) + x.z, 0.f);
  o.w = fmaxf(fmaf(y.w, scsh[c + 3], shsh[c + 3]) + x.w, 0.f);
  *(float4*)(out + i) = o;
}

// ---------------- launch ----------------
extern "C" void kernel_launch(void* const* d_in, const int* in_sizes, int n_in,
                              void* d_out, int out_size, void* d_ws, size_t ws_size,
                              hipStream_t stream)
{
  (void)n_in; (void)out_size; (void)ws_size;
  const float* p    = (const float*)d_in[0];
  const float* x    = (const float*)d_in[1];
  const int*   knn  = (const int*)d_in[2];
  const float* w1   = (const float*)d_in[3];
  const float* g1   = (const float*)d_in[4];
  const float* b1   = (const float*)d_in[5];
  const float* m1w1 = (const float*)d_in[6];
  const float* m1b1 = (const float*)d_in[7];
  const float* m1w2 = (const float*)d_in[8];
  const float* m1b2 = (const float*)d_in[9];
  const float* lpw1 = (const float*)d_in[10];
  const float* lpb1 = (const float*)d_in[11];
  const float* lpg  = (const float*)d_in[12];
  const float* lpbt = (const float*)d_in[13];
  const float* lpw2 = (const float*)d_in[14];
  const float* lpb2 = (const float*)d_in[15];
  const float* m2w1 = (const float*)d_in[16];
  const float* m2g1 = (const float*)d_in[17];
  const float* m2bt1= (const float*)d_in[18];
  const float* m2w2 = (const float*)d_in[19];
  const float* m2g2 = (const float*)d_in[20];
  const float* m2bt2= (const float*)d_in[21];
  const float* m2w3 = (const float*)d_in[22];
  const float* m2b3 = (const float*)d_in[23];
  const float* m3w  = (const float*)d_in[24];
  const float* m3b  = (const float*)d_in[25];
  const float* iw   = (const float*)d_in[26];
  const float* ib   = (const float*)d_in[27];
  const float* ixw  = (const float*)d_in[28];
  const float* ixb  = (const float*)d_in[29];
  const float* g2   = (const float*)d_in[30];
  const float* b2   = (const float*)d_in[31];
  const float* w3   = (const float*)d_in[32];
  const float* g3   = (const float*)d_in[33];
  const float* b3   = (const float*)d_in[34];
  float* out = (float*)d_out;
  float* ws  = (float*)d_ws;

  const int n = in_sizes[1] / 64;                // 32768
  const long long nk = (long long)n * 16;        // 524288

  float* cst  = ws;
  int* cnt      = (int*)(ws + CONST_FLOATS);    // n ints (zeroed with cst)
  int* rowstart = cnt + n;                      // n+1 ints
  int* cursor   = rowstart + n + 1;             // n ints
  int* bucket   = cursor + n;                   // nk ints
  float* resid = (float*)(bucket + nk);         // n*8
  float* y1 = resid + 8LL * n;                  // N*64, reused as y3
  float* z  = y1 + 64LL * n;                    // N*64
  float* xi = z + 64LL * n;                     // N*64 (x_intra -> x2)
  float* pr = xi + 64LL * n;                    // N*K*3
  float* y16 = pr + 48LL * n;                   // N*16
  float* h2 = y16 + 16LL * n;                   // N*K*8
  float* exv = h2 + 128LL * n;                  // N*K*16

  const int gB   = n / 64;            // 512
  const int nkB  = (int)(nk / 256);   // 2048
  const int nkB2 = (int)(nk / 512);   // 1024
  const int nkBi = (int)(nk / 128);   // 4096

  // partial-sum scratch (channel-major)
  float* pbn1  = exv + 256LL * n;                // 128 * gB
  float* plp   = pbn1 + 128LL * gB;              // 8 * nkB
  float* pm2b1 = plp + 8LL * nkB;                // 128 * nkB
  float* pm2b2 = pm2b1 + 128LL * nkB;            // 16 * nkB2
  float* pbn2  = pm2b2 + 16LL * nkB2;            // 128 * gB
  float* pbn3  = pbn2 + 128LL * gB;              // 128 * gB

  // zero const area + histogram counts
  hipMemsetAsync(d_ws, 0, (size_t)CONST_FLOATS * sizeof(float) + (size_t)n * sizeof(int), stream);

  // p_r + lp partials + histogram (independent of GEMM chain)
  k_prhist<<<nkB, 256, 0, stream>>>(p, knn, lpw1, lpb1, pr, plp, cnt);
  k_scan<<<1, 1024, 0, stream>>>(cnt, rowstart, cursor, n);
  k_fill<<<nkB, 256, 0, stream>>>(knn, cursor, bucket);
  k_f2_lp<<<1, 256, 0, stream>>>(plp, nkB, lpg, lpbt, lpw1, lpb1, lpw2, lpb2,
                                 cst, 1.f / (float)nk);

  // 1) y1 = x @ w1, bn1
  k_gemm64<<<gB, 256, 0, stream>>>(x, w1, nullptr, nullptr, nullptr, y1, pbn1, n);
  k_rbn<<<64, 256, 0, stream>>>(pbn1, gB, 64, g1, b1, cst + S_SC1, cst + S_SH1, 1.f / (float)n);
  // 2) z = relu(bn1(y1)) @ m3w + m3b ; Y16 = relu(bn1(y1)) @ m1w1[3:]
  k_gemm64<<<gB, 256, 0, stream>>>(y1, m3w, m3b, cst + S_SC1, cst + S_SH1, z, nullptr, n);
  k_gemm16<<<n / 16, 256, 0, stream>>>(y1, m1w1 + 48, cst + S_SC1, cst + S_SH1, y16);
  // 3) h1 BN stats (e recomputed from y16 + pr)
  k_e_stats<<<nkB, 256, 0, stream>>>(y16, pr, knn, m1w1, m1b1, m1w2, m1b2, cst, m2w1, pm2b1);
  k_rbn<<<64, 256, 0, stream>>>(pm2b1, nkB, 64, m2g1, m2bt1, cst + S_M2S1, cst + S_M2H1, 1.f / (float)nk);
  // 4) h2 + stats
  k_h2<<<nkB2, 256, 0, stream>>>(y16, pr, knn, m1w1, m1b1, m1w2, m1b2, cst, m2w1, m2w2, h2, pm2b2);
  k_rbn<<<8, 256, 0, stream>>>(pm2b2, nkB2, 8, m2g2, m2bt2, cst + S_M2S2, cst + S_M2H2, 1.f / (float)nk);
  // 5) fused softmax + xk + x_intra + exv
  k_intra<<<nkBi, 128, 0, stream>>>(z, pr, knn, cst, lpw2, lpb2, iw, ib, ixw, ixb,
                                    h2, m2w3, m2b3, xi, exv);
  // 6) CSR segment reduce -> resid
  k_inter<<<n / 16, 256, 0, stream>>>(rowstart, bucket, exv, resid);
  // 7) x2 = x_intra + tile(resid), bn2
  k_x2_stats<<<gB, 256, 0, stream>>>(xi, resid, pbn2, n);
  k_rbn<<<64, 256, 0, stream>>>(pbn2, gB, 64, g2, b2, cst + S_SC2, cst + S_SH2, 1.f / (float)n);
  // 8) y3 = relu(bn2(x2)) @ w3, bn3
  k_gemm64<<<gB, 256, 0, stream>>>(xi, w3, nullptr, cst + S_SC2, cst + S_SH2, y1, pbn3, n);
  k_rbn<<<64, 256, 0, stream>>>(pbn3, gB, 64, g3, b3, cst + S_SC3, cst + S_SH3, 1.f / (float)n);
  // 9) out = relu(bn3(y3) + x)
  k_out<<<(int)((long long)n * 64 / 1024), 256, 0, stream>>>(y1, x, cst, out);
}

// Round 6
// 427.784 us; speedup vs baseline: 3.7498x; 1.0965x over previous
//
#include <hip/hip_runtime.h>

// N = 32768 (runtime), C = 64, K = 16, CS = 8, SHARE = 8

enum {
  S_SC1 = 0,    S_SH1 = 64,
  S_LPSC = 128, S_LPSH = 132,
  S_M2S1 = 136, S_M2H1 = 200,
  S_M2S2 = 264, S_M2H2 = 272,
  S_SC2 = 280,  S_SH2 = 344,
  S_SC3 = 408,  S_SH3 = 472,
  S_LPW2S = 536, S_LPB2S = 584,
  S_QW = 600, S_QB = 612,
  S_G = 640,        // 64x16 c-major: G[c*16+u]
  S_HC = 1664,      // 64x4 c-major: H[c*4+r], r<3
  S_HB = 1920,      // 64
  CONST_FLOATS = 2048
};

// ---------------- fused partial-reduce + BN finalize: one block per channel ----------------
__global__ __launch_bounds__(256) void k_rbn(
    const float* __restrict__ partial, int nb, int nch,
    const float* __restrict__ g, const float* __restrict__ b,
    float* __restrict__ scale, float* __restrict__ shift, float inv_count)
{
  const int c = blockIdx.x;
  const int tid = threadIdx.x;
  float s = 0.f, q = 0.f;
  for (int i = tid; i < nb; i += 256) {
    s += partial[(size_t)c * nb + i];
    q += partial[(size_t)(c + nch) * nb + i];
  }
  #pragma unroll
  for (int m = 1; m < 64; m <<= 1) { s += __shfl_xor(s, m); q += __shfl_xor(q, m); }
  __shared__ float ws[4], wq[4];
  if ((tid & 63) == 0) { ws[tid >> 6] = s; wq[tid >> 6] = q; }
  __syncthreads();
  if (tid == 0) {
    float S = ws[0] + ws[1] + ws[2] + ws[3];
    float Q = wq[0] + wq[1] + wq[2] + wq[3];
    float m = S * inv_count;
    float v = Q * inv_count - m * m;
    float rs = rsqrtf(v + 1e-5f);
    float sc = g[c] * rs;
    scale[c] = sc;
    shift[c] = fmaf(-m, sc, b[c]);
  }
}

// ---------------- generic 64x64 GEMM ----------------
__global__ __launch_bounds__(256) void k_gemm64(
    const float* __restrict__ in, const float* __restrict__ w,
    const float* __restrict__ bias,
    const float* __restrict__ sc, const float* __restrict__ sh,
    float* __restrict__ out,
    float* __restrict__ partial,   // [128 * gridDim.x] channel-major, or null
    int n)
{
  __shared__ float scsh[64], shsh[64];
  __shared__ float bsum[64], bsq[64];
  const int tid = threadIdx.x;
  const int lane = tid & 63;
  const int wave = tid >> 6;
  if (sc != nullptr && tid < 64) { scsh[tid] = sc[tid]; shsh[tid] = sh[tid]; }
  if (tid < 64) { bsum[tid] = 0.f; bsq[tid] = 0.f; }
  __syncthreads();

  float wreg[64];
  #pragma unroll
  for (int k = 0; k < 64; ++k) wreg[k] = w[k * 64 + lane];
  const float bz = bias ? bias[lane] : 0.f;

  float lsum = 0.f, lsq = 0.f;
  const int row0 = (blockIdx.x * 4 + wave) * 16;
  for (int r = 0; r < 16; ++r) {
    const int row = row0 + r;
    const float* xr = in + (size_t)row * 64;
    float acc = bz;
    if (sc != nullptr) {
      #pragma unroll
      for (int k = 0; k < 64; k += 4) {
        float4 xv = *(const float4*)(xr + k);
        float x0 = fmaxf(fmaf(xv.x, scsh[k + 0], shsh[k + 0]), 0.f);
        float x1 = fmaxf(fmaf(xv.y, scsh[k + 1], shsh[k + 1]), 0.f);
        float x2 = fmaxf(fmaf(xv.z, scsh[k + 2], shsh[k + 2]), 0.f);
        float x3 = fmaxf(fmaf(xv.w, scsh[k + 3], shsh[k + 3]), 0.f);
        acc = fmaf(x0, wreg[k + 0], acc);
        acc = fmaf(x1, wreg[k + 1], acc);
        acc = fmaf(x2, wreg[k + 2], acc);
        acc = fmaf(x3, wreg[k + 3], acc);
      }
    } else {
      #pragma unroll
      for (int k = 0; k < 64; k += 4) {
        float4 xv = *(const float4*)(xr + k);
        acc = fmaf(xv.x, wreg[k + 0], acc);
        acc = fmaf(xv.y, wreg[k + 1], acc);
        acc = fmaf(xv.z, wreg[k + 2], acc);
        acc = fmaf(xv.w, wreg[k + 3], acc);
      }
    }
    out[(size_t)row * 64 + lane] = acc;
    lsum += acc;
    lsq = fmaf(acc, acc, lsq);
  }
  if (partial != nullptr) {
    atomicAdd(&bsum[lane], lsum);
    atomicAdd(&bsq[lane], lsq);
    __syncthreads();
    if (tid < 64) {
      partial[(size_t)tid * gridDim.x + blockIdx.x] = bsum[tid];
      partial[(size_t)(tid + 64) * gridDim.x + blockIdx.x] = bsq[tid];
    }
  }
}

// ---------------- Y16 = normrelu(y1) @ m1w1[3:67] ----------------
__global__ __launch_bounds__(256) void k_gemm16(
    const float* __restrict__ in, const float* __restrict__ w,
    const float* __restrict__ sc, const float* __restrict__ sh,
    float* __restrict__ out16)
{
  __shared__ float xn[16][65];
  __shared__ float wsh[1024];
  __shared__ float scsh[64], shsh[64];
  const int tid = threadIdx.x;
  if (tid < 64) { scsh[tid] = sc[tid]; shsh[tid] = sh[tid]; }
  for (int idx = tid; idx < 1024; idx += 256) wsh[idx] = w[idx];
  __syncthreads();
  const int base = blockIdx.x * 16;
  for (int idx = tid; idx < 1024; idx += 256) {
    int r = idx >> 6, c = idx & 63;
    float v = in[(size_t)(base + r) * 64 + c];
    xn[r][c] = fmaxf(fmaf(v, scsh[c], shsh[c]), 0.f);
  }
  __syncthreads();
  const int r = tid >> 4, t = tid & 15;
  float acc = 0.f;
  #pragma unroll
  for (int c = 0; c < 64; ++c) acc = fmaf(xn[r][c], wsh[c * 16 + t], acc);
  out16[(size_t)(base + r) * 16 + t] = acc;
}

// ---------------- lp finalize + weight folding (with built-in reduce) ----------------
__global__ __launch_bounds__(256) void k_f2_lp(
    const float* __restrict__ plp, int nb,
    const float* __restrict__ lpg, const float* __restrict__ lpbt,
    const float* __restrict__ lpw1, const float* __restrict__ lpb1,
    const float* __restrict__ lpw2, const float* __restrict__ lpb2,
    float* __restrict__ cst, float inv_count)
{
  __shared__ float S[8];
  const int tid = threadIdx.x;
  const int row = tid >> 5, l32 = tid & 31;
  float s = 0.f;
  for (int i = l32; i < nb; i += 32) s += plp[(size_t)row * nb + i];
  #pragma unroll
  for (int m = 1; m < 32; m <<= 1) s += __shfl_xor(s, m);
  if (l32 == 0) S[row] = s;
  __syncthreads();
  const int t = tid;
  if (t < 3) {
    float m = S[t] * inv_count;
    float v = S[4 + t] * inv_count - m * m;
    float rs = rsqrtf(v + 1e-5f);
    float sc = lpg[t] * rs;
    cst[S_LPSC + t] = sc;
    cst[S_LPSH + t] = fmaf(-m, sc, lpbt[t]);
  }
  __syncthreads();
  if (t < 9)  cst[S_QW + t] = lpw1[t] * cst[S_LPSC + (t % 3)];
  if (t < 3)  cst[S_QB + t] = fmaf(lpb1[t], cst[S_LPSC + t], cst[S_LPSH + t]);
  if (t < 16) {
    float b = 0.f;
    for (int c2 = 0; c2 < 4; ++c2) b += lpb2[c2 * 16 + t];
    cst[S_LPB2S + t] = b;
    for (int r = 0; r < 3; ++r) {
      float w = 0.f;
      for (int c2 = 0; c2 < 4; ++c2) w += lpw2[r * 64 + c2 * 16 + t];
      cst[S_LPW2S + r * 16 + t] = w;
    }
  }
}

// ---------------- fold G = m1w2 @ m2w1_top, H = lpshrink @ m2w1_bot, hbias ----------------
__global__ __launch_bounds__(256) void k_fold(
    const float* __restrict__ m1w2, const float* __restrict__ m2w1,
    const float* __restrict__ m1b2, float* __restrict__ cst)
{
  const int tid = threadIdx.x;
  #pragma unroll
  for (int q = 0; q < 4; ++q) {
    int ee = tid * 4 + q;
    int c = ee >> 4, u = ee & 15;
    float s = 0.f;
    #pragma unroll
    for (int t = 0; t < 16; ++t) s = fmaf(m1w2[u * 16 + t], m2w1[t * 64 + c], s);
    cst[S_G + c * 16 + u] = s;
  }
  if (tid < 192) {
    int c = tid / 3, r = tid - c * 3;
    float s = 0.f;
    #pragma unroll
    for (int t = 0; t < 16; ++t) s = fmaf(cst[S_LPW2S + r * 16 + t], m2w1[(16 + t) * 64 + c], s);
    cst[S_HC + c * 4 + r] = s;
  }
  if (tid < 64) {
    cst[S_HC + tid * 4 + 3] = 0.f;
    float s = 0.f;
    #pragma unroll
    for (int t = 0; t < 16; ++t) {
      s = fmaf(m1b2[t], m2w1[t * 64 + tid], s);
      s = fmaf(cst[S_LPB2S + t], m2w1[(16 + t) * 64 + tid], s);
    }
    cst[S_HB + tid] = s;
  }
}

// ---------------- K1: p_r, lp partials, knn histogram ----------------
__global__ __launch_bounds__(256) void k_prhist(
    const float* __restrict__ p, const int* __restrict__ knn,
    const float* __restrict__ lpw1, const float* __restrict__ lpb1,
    float* __restrict__ p_r, float* __restrict__ plp, int* __restrict__ cnt)
{
  __shared__ float lpw1sh[9], lpb1sh[3];
  __shared__ float lpsh[4][8];
  const int tid = threadIdx.x;
  if (tid < 9) lpw1sh[tid] = lpw1[tid];
  if (tid < 3) lpb1sh[tid] = lpb1[tid];
  __syncthreads();

  const size_t g = (size_t)blockIdx.x * 256 + tid;
  const int i = (int)(g >> 4);
  const int j = knn[g];
  const float pr0 = p[j * 3 + 0] - p[i * 3 + 0];
  const float pr1 = p[j * 3 + 1] - p[i * 3 + 1];
  const float pr2 = p[j * 3 + 2] - p[i * 3 + 2];
  p_r[g * 3 + 0] = pr0; p_r[g * 3 + 1] = pr1; p_r[g * 3 + 2] = pr2;
  atomicAdd(&cnt[j], 1);

  float q0 = fmaf(pr2, lpw1sh[6], fmaf(pr1, lpw1sh[3], fmaf(pr0, lpw1sh[0], lpb1sh[0])));
  float q1 = fmaf(pr2, lpw1sh[7], fmaf(pr1, lpw1sh[4], fmaf(pr0, lpw1sh[1], lpb1sh[1])));
  float q2 = fmaf(pr2, lpw1sh[8], fmaf(pr1, lpw1sh[5], fmaf(pr0, lpw1sh[2], lpb1sh[2])));
  float s0 = q0, s1 = q1, s2 = q2, qq0 = q0 * q0, qq1 = q1 * q1, qq2 = q2 * q2;
  #pragma unroll
  for (int m = 1; m < 64; m <<= 1) {
    s0 += __shfl_xor(s0, m); s1 += __shfl_xor(s1, m); s2 += __shfl_xor(s2, m);
    qq0 += __shfl_xor(qq0, m); qq1 += __shfl_xor(qq1, m); qq2 += __shfl_xor(qq2, m);
  }
  if ((tid & 63) == 0) {
    const int w = tid >> 6;
    lpsh[w][0] = s0; lpsh[w][1] = s1; lpsh[w][2] = s2; lpsh[w][3] = 0.f;
    lpsh[w][4] = qq0; lpsh[w][5] = qq1; lpsh[w][6] = qq2; lpsh[w][7] = 0.f;
  }
  __syncthreads();
  if (tid < 8) {
    float v = lpsh[0][tid] + lpsh[1][tid] + lpsh[2][tid] + lpsh[3][tid];
    plp[(size_t)tid * gridDim.x + blockIdx.x] = v;
  }
}

// ---------------- CSR build: scan ----------------
__global__ __launch_bounds__(1024) void k_scan(
    const int* __restrict__ cnt, int* __restrict__ rowstart,
    int* __restrict__ cursor, int n)
{
  __shared__ int tsum[1024];
  const int tid = threadIdx.x;
  const int per = n >> 10;
  const int base = tid * per;
  int local[32];
  int s = 0;
  for (int u = 0; u < per; ++u) { local[u] = cnt[base + u]; s += local[u]; }
  tsum[tid] = s;
  __syncthreads();
  for (int off = 1; off < 1024; off <<= 1) {
    int v = (tid >= off) ? tsum[tid - off] : 0;
    __syncthreads();
    tsum[tid] += v;
    __syncthreads();
  }
  int run = tsum[tid] - s;
  for (int u = 0; u < per; ++u) {
    rowstart[base + u] = run;
    cursor[base + u] = run;
    run += local[u];
  }
  if (tid == 1023) rowstart[n] = run;
}

// ---------------- CSR build: fill buckets ----------------
__global__ __launch_bounds__(256) void k_fill(
    const int* __restrict__ knn, int* __restrict__ cursor, int* __restrict__ bucket)
{
  const size_t g = (size_t)blockIdx.x * 256 + threadIdx.x;
  const int j = knn[g];
  const int pos = atomicAdd(&cursor[j], 1);
  bucket[pos] = (int)g;
}

// ---------------- K2: h1 BN stats via folded G/H (no e materialization) ----------------
__global__ __launch_bounds__(256) void k_h1_stats(
    const float* __restrict__ y16, const float* __restrict__ p_r,
    const int* __restrict__ knn, const float* __restrict__ m1w1,
    const float* __restrict__ m1b1, const float* __restrict__ cst,
    float* __restrict__ partial)   // [128 * gridDim.x]
{
  __shared__ float tq[256 * 20];
  __shared__ float bsum[64], bsq[64];
  const int tid = threadIdx.x;
  if (tid < 64) { bsum[tid] = 0.f; bsq[tid] = 0.f; }

  const size_t g = (size_t)blockIdx.x * 256 + tid;
  const int j = knn[g];
  const float pr0 = p_r[g * 3 + 0], pr1 = p_r[g * 3 + 1], pr2 = p_r[g * 3 + 2];
  const float* yj = y16 + (size_t)j * 16;
  float4 ya = *(const float4*)(yj);
  float4 yb = *(const float4*)(yj + 4);
  float4 yc = *(const float4*)(yj + 8);
  float4 yd = *(const float4*)(yj + 12);
  float t1[16] = {ya.x, ya.y, ya.z, ya.w, yb.x, yb.y, yb.z, yb.w,
                  yc.x, yc.y, yc.z, yc.w, yd.x, yd.y, yd.z, yd.w};
  #pragma unroll
  for (int u = 0; u < 16; ++u)
    t1[u] = fmaxf(fmaf(pr2, m1w1[32 + u], fmaf(pr1, m1w1[16 + u],
                  fmaf(pr0, m1w1[u], t1[u] + m1b1[u]))), 0.f);
  const float qn0 = fmaxf(fmaf(pr2, cst[S_QW + 6], fmaf(pr1, cst[S_QW + 3], fmaf(pr0, cst[S_QW + 0], cst[S_QB + 0]))), 0.f);
  const float qn1 = fmaxf(fmaf(pr2, cst[S_QW + 7], fmaf(pr1, cst[S_QW + 4], fmaf(pr0, cst[S_QW + 1], cst[S_QB + 1]))), 0.f);
  const float qn2 = fmaxf(fmaf(pr2, cst[S_QW + 8], fmaf(pr1, cst[S_QW + 5], fmaf(pr0, cst[S_QW + 2], cst[S_QB + 2]))), 0.f);
  float* tr = tq + tid * 20;
  *(float4*)(tr)      = make_float4(t1[0], t1[1], t1[2], t1[3]);
  *(float4*)(tr + 4)  = make_float4(t1[4], t1[5], t1[6], t1[7]);
  *(float4*)(tr + 8)  = make_float4(t1[8], t1[9], t1[10], t1[11]);
  *(float4*)(tr + 12) = make_float4(t1[12], t1[13], t1[14], t1[15]);
  *(float4*)(tr + 16) = make_float4(qn0, qn1, qn2, 0.f);
  __syncthreads();

  const int c = tid & 63, q = tid >> 6;
  float Greg[16];
  #pragma unroll
  for (int u = 0; u < 16; ++u) Greg[u] = cst[S_G + c * 16 + u];
  const float4 Hv = *(const float4*)(cst + S_HC + c * 4);
  const float hb = cst[S_HB + c];
  float ls = 0.f, lq = 0.f;
  for (int gg = q * 64; gg < q * 64 + 64; ++gg) {
    const float* t4 = tq + gg * 20;
    float4 a = *(const float4*)(t4);
    float4 b = *(const float4*)(t4 + 4);
    float4 cc = *(const float4*)(t4 + 8);
    float4 d = *(const float4*)(t4 + 12);
    float4 e4 = *(const float4*)(t4 + 16);
    float h = hb;
    h = fmaf(a.x, Greg[0], h);  h = fmaf(a.y, Greg[1], h);  h = fmaf(a.z, Greg[2], h);  h = fmaf(a.w, Greg[3], h);
    h = fmaf(b.x, Greg[4], h);  h = fmaf(b.y, Greg[5], h);  h = fmaf(b.z, Greg[6], h);  h = fmaf(b.w, Greg[7], h);
    h = fmaf(cc.x, Greg[8], h); h = fmaf(cc.y, Greg[9], h); h = fmaf(cc.z, Greg[10], h); h = fmaf(cc.w, Greg[11], h);
    h = fmaf(d.x, Greg[12], h); h = fmaf(d.y, Greg[13], h); h = fmaf(d.z, Greg[14], h); h = fmaf(d.w, Greg[15], h);
    h = fmaf(e4.x, Hv.x, fmaf(e4.y, Hv.y, fmaf(e4.z, Hv.z, h)));
    ls += h;
    lq = fmaf(h, h, lq);
  }
  atomicAdd(&bsum[c], ls);
  atomicAdd(&bsq[c], lq);
  __syncthreads();
  if (tid < 64) {
    partial[(size_t)tid * gridDim.x + blockIdx.x] = bsum[tid];
    partial[(size_t)(tid + 64) * gridDim.x + blockIdx.x] = bsq[tid];
  }
}

// ---------------- K3: h2 = relu(bn(h1)) @ m2w2 via folded G/H ----------------
__global__ __launch_bounds__(256) void k_h2(
    const float* __restrict__ y16, const float* __restrict__ p_r,
    const int* __restrict__ knn, const float* __restrict__ m1w1,
    const float* __restrict__ m1b1, const float* __restrict__ cst,
    const float* __restrict__ m2w2,
    float* __restrict__ h2out,
    float* __restrict__ partial)   // [16 * gridDim.x]
{
  __shared__ float Gsh[1024], Hsh[256], hbsh[64];
  __shared__ float w2m[512];
  __shared__ float scsh[64], shsh[64];
  __shared__ float redsh[4][16];
  const int tid = threadIdx.x;
  for (int i = tid; i < 1024; i += 256) Gsh[i] = cst[S_G + i];
  Hsh[tid] = cst[S_HC + tid];
  for (int i = tid; i < 512; i += 256) w2m[i] = m2w2[i];
  if (tid < 64) { hbsh[tid] = cst[S_HB + tid]; scsh[tid] = cst[S_M2S1 + tid]; shsh[tid] = cst[S_M2H1 + tid]; }
  __syncthreads();

  const size_t g0 = ((size_t)blockIdx.x * 256 + tid) * 2;
  float t1[2][16], qn[2][3];
  #pragma unroll
  for (int gg = 0; gg < 2; ++gg) {
    const size_t g = g0 + gg;
    const int j = knn[g];
    const float pr0 = p_r[g * 3 + 0], pr1 = p_r[g * 3 + 1], pr2 = p_r[g * 3 + 2];
    const float* yj = y16 + (size_t)j * 16;
    float4 ya = *(const float4*)(yj);
    float4 yb = *(const float4*)(yj + 4);
    float4 yc = *(const float4*)(yj + 8);
    float4 yd = *(const float4*)(yj + 12);
    float tt[16] = {ya.x, ya.y, ya.z, ya.w, yb.x, yb.y, yb.z, yb.w,
                    yc.x, yc.y, yc.z, yc.w, yd.x, yd.y, yd.z, yd.w};
    #pragma unroll
    for (int u = 0; u < 16; ++u)
      t1[gg][u] = fmaxf(fmaf(pr2, m1w1[32 + u], fmaf(pr1, m1w1[16 + u],
                    fmaf(pr0, m1w1[u], tt[u] + m1b1[u]))), 0.f);
    qn[gg][0] = fmaxf(fmaf(pr2, cst[S_QW + 6], fmaf(pr1, cst[S_QW + 3], fmaf(pr0, cst[S_QW + 0], cst[S_QB + 0]))), 0.f);
    qn[gg][1] = fmaxf(fmaf(pr2, cst[S_QW + 7], fmaf(pr1, cst[S_QW + 4], fmaf(pr0, cst[S_QW + 1], cst[S_QB + 1]))), 0.f);
    qn[gg][2] = fmaxf(fmaf(pr2, cst[S_QW + 8], fmaf(pr1, cst[S_QW + 5], fmaf(pr0, cst[S_QW + 2], cst[S_QB + 2]))), 0.f);
  }

  float a0[8], a1[8];
  #pragma unroll
  for (int t = 0; t < 8; ++t) { a0[t] = 0.f; a1[t] = 0.f; }
  for (int c = 0; c < 64; ++c) {
    float4 g0v = *(const float4*)(Gsh + c * 16);
    float4 g1v = *(const float4*)(Gsh + c * 16 + 4);
    float4 g2v = *(const float4*)(Gsh + c * 16 + 8);
    float4 g3v = *(const float4*)(Gsh + c * 16 + 12);
    float4 hv = *(const float4*)(Hsh + c * 4);
    float h_0 = hbsh[c], h_1 = hbsh[c];
    h_0 = fmaf(t1[0][0], g0v.x, h_0); h_0 = fmaf(t1[0][1], g0v.y, h_0); h_0 = fmaf(t1[0][2], g0v.z, h_0); h_0 = fmaf(t1[0][3], g0v.w, h_0);
    h_0 = fmaf(t1[0][4], g1v.x, h_0); h_0 = fmaf(t1[0][5], g1v.y, h_0); h_0 = fmaf(t1[0][6], g1v.z, h_0); h_0 = fmaf(t1[0][7], g1v.w, h_0);
    h_0 = fmaf(t1[0][8], g2v.x, h_0); h_0 = fmaf(t1[0][9], g2v.y, h_0); h_0 = fmaf(t1[0][10], g2v.z, h_0); h_0 = fmaf(t1[0][11], g2v.w, h_0);
    h_0 = fmaf(t1[0][12], g3v.x, h_0); h_0 = fmaf(t1[0][13], g3v.y, h_0); h_0 = fmaf(t1[0][14], g3v.z, h_0); h_0 = fmaf(t1[0][15], g3v.w, h_0);
    h_0 = fmaf(qn[0][0], hv.x, fmaf(qn[0][1], hv.y, fmaf(qn[0][2], hv.z, h_0)));
    h_1 = fmaf(t1[1][0], g0v.x, h_1); h_1 = fmaf(t1[1][1], g0v.y, h_1); h_1 = fmaf(t1[1][2], g0v.z, h_1); h_1 = fmaf(t1[1][3], g0v.w, h_1);
    h_1 = fmaf(t1[1][4], g1v.x, h_1); h_1 = fmaf(t1[1][5], g1v.y, h_1); h_1 = fmaf(t1[1][6], g1v.z, h_1); h_1 = fmaf(t1[1][7], g1v.w, h_1);
    h_1 = fmaf(t1[1][8], g2v.x, h_1); h_1 = fmaf(t1[1][9], g2v.y, h_1); h_1 = fmaf(t1[1][10], g2v.z, h_1); h_1 = fmaf(t1[1][11], g2v.w, h_1);
    h_1 = fmaf(t1[1][12], g3v.x, h_1); h_1 = fmaf(t1[1][13], g3v.y, h_1); h_1 = fmaf(t1[1][14], g3v.z, h_1); h_1 = fmaf(t1[1][15], g3v.w, h_1);
    h_1 = fmaf(qn[1][0], hv.x, fmaf(qn[1][1], hv.y, fmaf(qn[1][2], hv.z, h_1)));
    float x0 = fmaxf(fmaf(h_0, scsh[c], shsh[c]), 0.f);
    float x1 = fmaxf(fmaf(h_1, scsh[c], shsh[c]), 0.f);
    float4 wa = *(const float4*)(w2m + c * 8);
    float4 wb = *(const float4*)(w2m + c * 8 + 4);
    a0[0] = fmaf(x0, wa.x, a0[0]); a0[1] = fmaf(x0, wa.y, a0[1]); a0[2] = fmaf(x0, wa.z, a0[2]); a0[3] = fmaf(x0, wa.w, a0[3]);
    a0[4] = fmaf(x0, wb.x, a0[4]); a0[5] = fmaf(x0, wb.y, a0[5]); a0[6] = fmaf(x0, wb.z, a0[6]); a0[7] = fmaf(x0, wb.w, a0[7]);
    a1[0] = fmaf(x1, wa.x, a1[0]); a1[1] = fmaf(x1, wa.y, a1[1]); a1[2] = fmaf(x1, wa.z, a1[2]); a1[3] = fmaf(x1, wa.w, a1[3]);
    a1[4] = fmaf(x1, wb.x, a1[4]); a1[5] = fmaf(x1, wb.y, a1[5]); a1[6] = fmaf(x1, wb.z, a1[6]); a1[7] = fmaf(x1, wb.w, a1[7]);
  }
  *(float4*)(h2out + g0 * 8)      = make_float4(a0[0], a0[1], a0[2], a0[3]);
  *(float4*)(h2out + g0 * 8 + 4)  = make_float4(a0[4], a0[5], a0[6], a0[7]);
  *(float4*)(h2out + g0 * 8 + 8)  = make_float4(a1[0], a1[1], a1[2], a1[3]);
  *(float4*)(h2out + g0 * 8 + 12) = make_float4(a1[4], a1[5], a1[6], a1[7]);

  float st[8], sq[8];
  #pragma unroll
  for (int t = 0; t < 8; ++t) {
    st[t] = a0[t] + a1[t];
    sq[t] = fmaf(a0[t], a0[t], a1[t] * a1[t]);
  }
  #pragma unroll
  for (int m = 1; m < 64; m <<= 1) {
    #pragma unroll
    for (int t = 0; t < 8; ++t) { st[t] += __shfl_xor(st[t], m); sq[t] += __shfl_xor(sq[t], m); }
  }
  if ((tid & 63) == 0) {
    const int w = tid >> 6;
    #pragma unroll
    for (int t = 0; t < 8; ++t) { redsh[w][t] = st[t]; redsh[w][8 + t] = sq[t]; }
  }
  __syncthreads();
  if (tid < 16) {
    float v = redsh[0][tid] + redsh[1][tid] + redsh[2][tid] + redsh[3][tid];
    partial[(size_t)tid * gridDim.x + blockIdx.x] = v;
  }
}

// ---------------- K4: fused softmax + xk + x_intra + exv (z-row prefetch) ----------------
__global__ __launch_bounds__(256) void k_intra(
    const float* __restrict__ z, const float* __restrict__ p_r,
    const int* __restrict__ knn, const float* __restrict__ cst,
    const float* __restrict__ lpw2, const float* __restrict__ lpb2,
    const float* __restrict__ iw, const float* __restrict__ ib,
    const float* __restrict__ ixw, const float* __restrict__ ixb,
    const float* __restrict__ h2, const float* __restrict__ m2w3,
    const float* __restrict__ m2b3,
    float* __restrict__ x_intra, float* __restrict__ exv)
{
  __shared__ float lpw2sh[192], lpb2sh[64];
  __shared__ float iwsh[512], ixwsh[512];
  __shared__ float ibsh[8], ixbsh[8];
  __shared__ float w3sh[64], b3sh[8], s2sh[8], h2ssh[8];
  const int tid = threadIdx.x;
  if (tid < 192) lpw2sh[tid] = lpw2[tid];
  if (tid < 64) { lpb2sh[tid] = lpb2[tid]; w3sh[tid] = m2w3[tid]; }
  for (int idx = tid; idx < 512; idx += 256) { iwsh[idx] = iw[idx]; ixwsh[idx] = ixw[idx]; }
  if (tid < 8) {
    ibsh[tid] = ib[tid]; ixbsh[tid] = ixb[tid];
    b3sh[tid] = m2b3[tid]; s2sh[tid] = cst[S_M2S2 + tid]; h2ssh[tid] = cst[S_M2H2 + tid];
  }
  __syncthreads();

  const size_t g = (size_t)blockIdx.x * 256 + tid;
  const int j = knn[g];
  const int own = tid & 15;

  // issue the full z-row load early (16 outstanding float4s)
  const float* zr = z + (size_t)j * 64;
  float4 zv[16];
  #pragma unroll
  for (int q4 = 0; q4 < 16; ++q4) zv[q4] = *(const float4*)(zr + q4 * 4);

  const float pr0 = p_r[g * 3 + 0], pr1 = p_r[g * 3 + 1], pr2 = p_r[g * 3 + 2];
  const float qn0 = fmaxf(fmaf(pr2, cst[S_QW + 6], fmaf(pr1, cst[S_QW + 3], fmaf(pr0, cst[S_QW + 0], cst[S_QB + 0]))), 0.f);
  const float qn1 = fmaxf(fmaf(pr2, cst[S_QW + 7], fmaf(pr1, cst[S_QW + 4], fmaf(pr0, cst[S_QW + 1], cst[S_QB + 1]))), 0.f);
  const float qn2 = fmaxf(fmaf(pr2, cst[S_QW + 8], fmaf(pr1, cst[S_QW + 5], fmaf(pr0, cst[S_QW + 2], cst[S_QB + 2]))), 0.f);

  // fused k-softmax
  float4 ha = *(const float4*)(h2 + g * 8);
  float4 hb = *(const float4*)(h2 + g * 8 + 4);
  float hn[8];
  hn[0] = fmaxf(fmaf(ha.x, s2sh[0], h2ssh[0]), 0.f);
  hn[1] = fmaxf(fmaf(ha.y, s2sh[1], h2ssh[1]), 0.f);
  hn[2] = fmaxf(fmaf(ha.z, s2sh[2], h2ssh[2]), 0.f);
  hn[3] = fmaxf(fmaf(ha.w, s2sh[3], h2ssh[3]), 0.f);
  hn[4] = fmaxf(fmaf(hb.x, s2sh[4], h2ssh[4]), 0.f);
  hn[5] = fmaxf(fmaf(hb.y, s2sh[5], h2ssh[5]), 0.f);
  hn[6] = fmaxf(fmaf(hb.z, s2sh[6], h2ssh[6]), 0.f);
  hn[7] = fmaxf(fmaf(hb.w, s2sh[7], h2ssh[7]), 0.f);
  float wk[8];
  #pragma unroll
  for (int t = 0; t < 8; ++t) {
    float a = b3sh[t];
    #pragma unroll
    for (int u = 0; u < 8; ++u) a = fmaf(hn[u], w3sh[u * 8 + t], a);
    wk[t] = a;
  }
  #pragma unroll
  for (int t = 0; t < 8; ++t) {
    float m = wk[t];
    m = fmaxf(m, __shfl_xor(m, 1));
    m = fmaxf(m, __shfl_xor(m, 2));
    m = fmaxf(m, __shfl_xor(m, 4));
    m = fmaxf(m, __shfl_xor(m, 8));
    float ex = __expf(wk[t] - m);
    float s = ex;
    s += __shfl_xor(s, 1);
    s += __shfl_xor(s, 2);
    s += __shfl_xor(s, 4);
    s += __shfl_xor(s, 8);
    wk[t] = ex / s;
  }

  float sacc[8], vacc[8];
  #pragma unroll
  for (int t = 0; t < 8; ++t) { sacc[t] = ibsh[t]; vacc[t] = ixbsh[t]; }
  float4 o = make_float4(0.f, 0.f, 0.f, 0.f);
  #pragma unroll
  for (int c = 0; c < 64; c += 4) {
    float4 zq = zv[c >> 2];
    float4 l0 = *(const float4*)(lpw2sh + c);
    float4 l1 = *(const float4*)(lpw2sh + 64 + c);
    float4 l2 = *(const float4*)(lpw2sh + 128 + c);
    float4 lb = *(const float4*)(lpb2sh + c);
    float xkv[4];
    xkv[0] = (zq.x + fmaf(qn2, l2.x, fmaf(qn1, l1.x, fmaf(qn0, l0.x, lb.x)))) * wk[(c + 0) & 7];
    xkv[1] = (zq.y + fmaf(qn2, l2.y, fmaf(qn1, l1.y, fmaf(qn0, l0.y, lb.y)))) * wk[(c + 1) & 7];
    xkv[2] = (zq.z + fmaf(qn2, l2.z, fmaf(qn1, l1.z, fmaf(qn0, l0.z, lb.z)))) * wk[(c + 2) & 7];
    xkv[3] = (zq.w + fmaf(qn2, l2.w, fmaf(qn1, l1.w, fmaf(qn0, l0.w, lb.w)))) * wk[(c + 3) & 7];
    float r0 = xkv[0], r1 = xkv[1], r2 = xkv[2], r3 = xkv[3];
    #pragma unroll
    for (int m = 1; m < 16; m <<= 1) {
      r0 += __shfl_xor(r0, m);
      r1 += __shfl_xor(r1, m);
      r2 += __shfl_xor(r2, m);
      r3 += __shfl_xor(r3, m);
    }
    if (own == (c >> 2)) o = make_float4(r0, r1, r2, r3);
    #pragma unroll
    for (int d = 0; d < 4; ++d) {
      const float xk = xkv[d];
      const float* iwc = iwsh + (c + d) * 8;
      const float* ixwc = ixwsh + (c + d) * 8;
      float4 a0 = *(const float4*)(iwc);
      float4 a1 = *(const float4*)(iwc + 4);
      float4 b0 = *(const float4*)(ixwc);
      float4 b1 = *(const float4*)(ixwc + 4);
      sacc[0] = fmaf(xk, a0.x, sacc[0]); sacc[1] = fmaf(xk, a0.y, sacc[1]); sacc[2] = fmaf(xk, a0.z, sacc[2]); sacc[3] = fmaf(xk, a0.w, sacc[3]);
      sacc[4] = fmaf(xk, a1.x, sacc[4]); sacc[5] = fmaf(xk, a1.y, sacc[5]); sacc[6] = fmaf(xk, a1.z, sacc[6]); sacc[7] = fmaf(xk, a1.w, sacc[7]);
      vacc[0] = fmaf(xk, b0.x, vacc[0]); vacc[1] = fmaf(xk, b0.y, vacc[1]); vacc[2] = fmaf(xk, b0.z, vacc[2]); vacc[3] = fmaf(xk, b0.w, vacc[3]);
      vacc[4] = fmaf(xk, b1.x, vacc[4]); vacc[5] = fmaf(xk, b1.y, vacc[5]); vacc[6] = fmaf(xk, b1.z, vacc[6]); vacc[7] = fmaf(xk, b1.w, vacc[7]);
    }
  }
  float ex[8];
  #pragma unroll
  for (int t = 0; t < 8; ++t) ex[t] = __expf(sacc[t]);
  *(float4*)(exv + g * 16)      = make_float4(ex[0], ex[1], ex[2], ex[3]);
  *(float4*)(exv + g * 16 + 4)  = make_float4(ex[4], ex[5], ex[6], ex[7]);
  *(float4*)(exv + g * 16 + 8)  = make_float4(ex[0] * vacc[0], ex[1] * vacc[1], ex[2] * vacc[2], ex[3] * vacc[3]);
  *(float4*)(exv + g * 16 + 12) = make_float4(ex[4] * vacc[4], ex[5] * vacc[5], ex[6] * vacc[6], ex[7] * vacc[7]);

  const size_t i = g >> 4;
  *(float4*)(x_intra + i * 64 + own * 4) = o;
}

// ---------------- K5: CSR segment reduce + x2 = x_intra + tile(resid) + bn2 partials ----------------
__global__ __launch_bounds__(256) void k_inter_x2(
    const int* __restrict__ rowstart, const int* __restrict__ bucket,
    const float* __restrict__ exv,
    float* __restrict__ xi, float* __restrict__ partial)
{
  __shared__ float bsum[64], bsq[64];
  const int tid = threadIdx.x;
  if (tid < 64) { bsum[tid] = 0.f; bsq[tid] = 0.f; }
  __syncthreads();
  const int t = tid & 15;
  const int j = blockIdx.x * 16 + (tid >> 4);
  const int s0 = rowstart[j];
  const int e0 = rowstart[j + 1];
  float acc = 0.f;
  for (int e = s0; e < e0; ++e) {
    const int gg = bucket[e];
    acc += exv[(size_t)gg * 16 + t];
  }
  const float other = __shfl_xor(acc, 8);
  // lane t<8: acc=sum(ex), other=sum(ex*v); lane t>=8: swapped
  float r = (t < 8) ? ((acc > 0.f) ? other / acc : 0.f)
                    : ((other > 0.f) ? acc / other : 0.f);
  float4 xv = *(const float4*)(xi + (size_t)j * 64 + t * 4);
  float v0 = xv.x + __shfl(r, (4 * t + 0) & 7, 16);
  float v1 = xv.y + __shfl(r, (4 * t + 1) & 7, 16);
  float v2 = xv.z + __shfl(r, (4 * t + 2) & 7, 16);
  float v3 = xv.w + __shfl(r, (4 * t + 3) & 7, 16);
  *(float4*)(xi + (size_t)j * 64 + t * 4) = make_float4(v0, v1, v2, v3);
  float s_[4] = {v0, v1, v2, v3};
  float q_[4] = {v0 * v0, v1 * v1, v2 * v2, v3 * v3};
  #pragma unroll
  for (int d = 0; d < 4; ++d) {
    s_[d] += __shfl_xor(s_[d], 16); s_[d] += __shfl_xor(s_[d], 32);
    q_[d] += __shfl_xor(q_[d], 16); q_[d] += __shfl_xor(q_[d], 32);
  }
  if ((tid & 63) < 16) {
    #pragma unroll
    for (int d = 0; d < 4; ++d) {
      atomicAdd(&bsum[4 * t + d], s_[d]);
      atomicAdd(&bsq[4 * t + d], q_[d]);
    }
  }
  __syncthreads();
  if (tid < 64) {
    partial[(size_t)tid * gridDim.x + blockIdx.x] = bsum[tid];
    partial[(size_t)(tid + 64) * gridDim.x + blockIdx.x] = bsq[tid];
  }
}

// ---------------- K6: final bn3 + residual + relu ----------------
__global__ __launch_bounds__(256) void k_out(
    const float* __restrict__ y3, const float* __restrict__ x0,
    const float* __restrict__ cst, float* __restrict__ out)
{
  __shared__ float scsh[64], shsh[64];
  const int tid = threadIdx.x;
  if (tid < 64) { scsh[tid] = cst[S_SC3 + tid]; shsh[tid] = cst[S_SH3 + tid]; }
  __syncthreads();
  const size_t i = ((size_t)blockIdx.x * 256 + tid) * 4;
  float4 y = *(const float4*)(y3 + i);
  float4 x = *(const float4*)(x0 + i);
  const int c = (int)(i & 63);
  float4 o;
  o.x = fmaxf(fmaf(y.x, scsh[c + 0], shsh[c + 0]) + x.x, 0.f);
  o.y = fmaxf(fmaf(y.y, scsh[c + 1], shsh[c + 1]) + x.y, 0.f);
  o.z = fmaxf(fmaf(y.z, scsh[c + 2], shsh[c + 2]) + x.z, 0.f);
  o.w = fmaxf(fmaf(y.w, scsh[c + 3], shsh[c + 3]) + x.w, 0.f);
  *(float4*)(out + i) = o;
}

// ---------------- launch ----------------
extern "C" void kernel_launch(void* const* d_in, const int* in_sizes, int n_in,
                              void* d_out, int out_size, void* d_ws, size_t ws_size,
                              hipStream_t stream)
{
  (void)n_in; (void)out_size; (void)ws_size;
  const float* p    = (const float*)d_in[0];
  const float* x    = (const float*)d_in[1];
  const int*   knn  = (const int*)d_in[2];
  const float* w1   = (const float*)d_in[3];
  const float* g1   = (const float*)d_in[4];
  const float* b1   = (const float*)d_in[5];
  const float* m1w1 = (const float*)d_in[6];
  const float* m1b1 = (const float*)d_in[7];
  const float* m1w2 = (const float*)d_in[8];
  const float* m1b2 = (const float*)d_in[9];
  const float* lpw1 = (const float*)d_in[10];
  const float* lpb1 = (const float*)d_in[11];
  const float* lpg  = (const float*)d_in[12];
  const float* lpbt = (const float*)d_in[13];
  const float* lpw2 = (const float*)d_in[14];
  const float* lpb2 = (const float*)d_in[15];
  const float* m2w1 = (const float*)d_in[16];
  const float* m2g1 = (const float*)d_in[17];
  const float* m2bt1= (const float*)d_in[18];
  const float* m2w2 = (const float*)d_in[19];
  const float* m2g2 = (const float*)d_in[20];
  const float* m2bt2= (const float*)d_in[21];
  const float* m2w3 = (const float*)d_in[22];
  const float* m2b3 = (const float*)d_in[23];
  const float* m3w  = (const float*)d_in[24];
  const float* m3b  = (const float*)d_in[25];
  const float* iw   = (const float*)d_in[26];
  const float* ib   = (const float*)d_in[27];
  const float* ixw  = (const float*)d_in[28];
  const float* ixb  = (const float*)d_in[29];
  const float* g2   = (const float*)d_in[30];
  const float* b2   = (const float*)d_in[31];
  const float* w3   = (const float*)d_in[32];
  const float* g3   = (const float*)d_in[33];
  const float* b3   = (const float*)d_in[34];
  float* out = (float*)d_out;
  float* ws  = (float*)d_ws;

  const int n = in_sizes[1] / 64;                // 32768
  const long long nk = (long long)n * 16;        // 524288

  float* cst  = ws;
  int* cnt      = (int*)(ws + CONST_FLOATS);    // n ints (zeroed with cst)
  int* rowstart = cnt + n;                      // n+1 ints
  int* cursor   = rowstart + n + 1;             // n ints
  int* bucket   = cursor + n;                   // nk ints
  float* y1 = (float*)(bucket + nk);            // N*64, reused as y3
  float* z  = y1 + 64LL * n;                    // N*64
  float* xi = z + 64LL * n;                     // N*64 (x_intra -> x2)
  float* pr = xi + 64LL * n;                    // N*K*3
  float* y16 = pr + 48LL * n;                   // N*16
  float* h2 = y16 + 16LL * n;                   // N*K*8
  float* exv = h2 + 128LL * n;                  // N*K*16

  const int gB   = n / 64;            // 512
  const int nkB  = (int)(nk / 256);   // 2048
  const int nkB2 = (int)(nk / 512);   // 1024
  const int jB   = n / 16;            // 2048

  // partial-sum scratch (channel-major)
  float* pbn1  = exv + 256LL * n;                // 128 * gB
  float* plp   = pbn1 + 128LL * gB;              // 8 * nkB
  float* pm2b1 = plp + 8LL * nkB;                // 128 * nkB
  float* pm2b2 = pm2b1 + 128LL * nkB;            // 16 * nkB2
  float* pbn2  = pm2b2 + 16LL * nkB2;            // 128 * jB
  float* pbn3  = pbn2 + 128LL * jB;              // 128 * gB

  // zero const area + histogram counts
  hipMemsetAsync(d_ws, 0, (size_t)CONST_FLOATS * sizeof(float) + (size_t)n * sizeof(int), stream);

  // p_r + lp partials + histogram, CSR, weight folding
  k_prhist<<<nkB, 256, 0, stream>>>(p, knn, lpw1, lpb1, pr, plp, cnt);
  k_scan<<<1, 1024, 0, stream>>>(cnt, rowstart, cursor, n);
  k_fill<<<nkB, 256, 0, stream>>>(knn, cursor, bucket);
  k_f2_lp<<<1, 256, 0, stream>>>(plp, nkB, lpg, lpbt, lpw1, lpb1, lpw2, lpb2,
                                 cst, 1.f / (float)nk);
  k_fold<<<1, 256, 0, stream>>>(m1w2, m2w1, m1b2, cst);

  // 1) y1 = x @ w1, bn1
  k_gemm64<<<gB, 256, 0, stream>>>(x, w1, nullptr, nullptr, nullptr, y1, pbn1, n);
  k_rbn<<<64, 256, 0, stream>>>(pbn1, gB, 64, g1, b1, cst + S_SC1, cst + S_SH1, 1.f / (float)n);
  // 2) z = relu(bn1(y1)) @ m3w + m3b ; Y16 = relu(bn1(y1)) @ m1w1[3:]
  k_gemm64<<<gB, 256, 0, stream>>>(y1, m3w, m3b, cst + S_SC1, cst + S_SH1, z, nullptr, n);
  k_gemm16<<<n / 16, 256, 0, stream>>>(y1, m1w1 + 48, cst + S_SC1, cst + S_SH1, y16);
  // 3) h1 BN stats via folded G/H
  k_h1_stats<<<nkB, 256, 0, stream>>>(y16, pr, knn, m1w1, m1b1, cst, pm2b1);
  k_rbn<<<64, 256, 0, stream>>>(pm2b1, nkB, 64, m2g1, m2bt1, cst + S_M2S1, cst + S_M2H1, 1.f / (float)nk);
  // 4) h2 + stats
  k_h2<<<nkB2, 256, 0, stream>>>(y16, pr, knn, m1w1, m1b1, cst, m2w2, h2, pm2b2);
  k_rbn<<<8, 256, 0, stream>>>(pm2b2, nkB2, 8, m2g2, m2bt2, cst + S_M2S2, cst + S_M2H2, 1.f / (float)nk);
  // 5) fused softmax + xk + x_intra + exv
  k_intra<<<nkB, 256, 0, stream>>>(z, pr, knn, cst, lpw2, lpb2, iw, ib, ixw, ixb,
                                   h2, m2w3, m2b3, xi, exv);
  // 6) CSR segment reduce + x2 + bn2 partials
  k_inter_x2<<<jB, 256, 0, stream>>>(rowstart, bucket, exv, xi, pbn2);
  k_rbn<<<64, 256, 0, stream>>>(pbn2, jB, 64, g2, b2, cst + S_SC2, cst + S_SH2, 1.f / (float)n);
  // 7) y3 = relu(bn2(x2)) @ w3, bn3
  k_gemm64<<<gB, 256, 0, stream>>>(xi, w3, nullptr, cst + S_SC2, cst + S_SH2, y1, pbn3, n);
  k_rbn<<<64, 256, 0, stream>>>(pbn3, gB, 64, g3, b3, cst + S_SC3, cst + S_SH3, 1.f / (float)n);
  // 8) out = relu(bn3(y3) + x)
  k_out<<<(int)((long long)n * 64 / 1024), 256, 0, stream>>>(y1, x, cst, out);
}